// Round 9
// baseline (399.906 us; speedup 1.0000x reference)
//
#include <hip/hip_runtime.h>
#include <math.h>

// OSS / VMamba-style block. B=4, C=64, H=W=64, L=4096, d_inner=512, D_STATE=16.
// R3: gemm_xz MFMA. R4: scan v3. R5: dt/BC/res MFMA. R6: merged gemm_proj, blocked z/y.
// R7: dt/xi bf16 + packed-uint LDS. R8: B/C bf16 through LDS (b64 reads), D folded
// into pl (emit reads 4x float2, no pk re-read), uint2 pk writes, p2 LDS 11.5KB,
// unroll 4; FFN g/gm bf16.

#define DEV static __device__ __forceinline__

DEV float silu_f(float x){ return x / (1.f + __expf(-x)); }

DEV ushort f2bf(float f){
  uint u = __float_as_uint(f);
  uint r = (u + 0x7FFF + ((u>>16)&1)) >> 16;
  return (ushort)r;
}
DEV uint f2bf2(float lo, float hi){
  return (uint)f2bf(lo) | ((uint)f2bf(hi)<<16);
}
DEV float bf2f(ushort u){ return __uint_as_float(((uint)u)<<16); }
DEV float bflo(uint u){ return __uint_as_float(u<<16); }
DEV float bfhi(uint u){ return __uint_as_float(u&0xffff0000u); }

typedef __attribute__((ext_vector_type(8))) short bf8_t;
typedef __attribute__((ext_vector_type(4))) float f4_t;

DEV float quad_sum4(float v){
  v += __int_as_float(__builtin_amdgcn_update_dpp(0, __float_as_int(v), 0xB1, 0xF, 0xF, false));
  v += __int_as_float(__builtin_amdgcn_update_dpp(0, __float_as_int(v), 0x4E, 0xF, 0xF, false));
  return v;
}

// ---------------- LayerNorm stats, two-stage ----------------
__global__ __launch_bounds__(256) void ln_part(const float* __restrict__ x,
                                               float2* __restrict__ part){
  int blk = blockIdx.x; int b = blk>>6, pc = blk&63;
  const float* p = x + (size_t)b*262144 + (size_t)pc*4096;
  float s=0.f, s2=0.f;
  #pragma unroll
  for(int it=0; it<4; ++it){
    int i = threadIdx.x + it*256;
    float4 v = *(const float4*)(p + i*4);
    s  += v.x+v.y+v.z+v.w;
    s2 += v.x*v.x+v.y*v.y+v.z*v.z+v.w*v.w;
  }
  __shared__ float ls[256], ls2[256];
  ls[threadIdx.x]=s; ls2[threadIdx.x]=s2; __syncthreads();
  for(int st=128;st>0;st>>=1){
    if(threadIdx.x<st){ ls[threadIdx.x]+=ls[threadIdx.x+st]; ls2[threadIdx.x]+=ls2[threadIdx.x+st]; }
    __syncthreads();
  }
  if(threadIdx.x==0) part[blk]=make_float2(ls[0],ls2[0]);
}
__global__ __launch_bounds__(64) void ln_fin(const float2* __restrict__ part,
                                             float* __restrict__ mu, float* __restrict__ rstd){
  int b = blockIdx.x;
  float2 v = part[b*64+threadIdx.x];
  __shared__ double ds_[64], ds2_[64];
  ds_[threadIdx.x]=v.x; ds2_[threadIdx.x]=v.y; __syncthreads();
  for(int st=32;st>0;st>>=1){
    if(threadIdx.x<st){ ds_[threadIdx.x]+=ds_[threadIdx.x+st]; ds2_[threadIdx.x]+=ds2_[threadIdx.x+st]; }
    __syncthreads();
  }
  if(threadIdx.x==0){
    double m = ds_[0]*(1.0/262144.0);
    double var = ds2_[0]*(1.0/262144.0) - m*m;
    mu[b]=(float)m; rstd[b]=(float)(1.0/sqrt(var+1e-5));
  }
}

// ---------------- LN1 apply + inproj (64->128) + split, silu on fo2 ----------------
__global__ __launch_bounds__(256) void ln1_inproj(const float* __restrict__ x,
    const float* __restrict__ n1w, const float* __restrict__ n1b,
    const float* __restrict__ ipw, const float* __restrict__ ipb,
    const float* __restrict__ mu, const float* __restrict__ rstd,
    float* __restrict__ fo1_raw, float* __restrict__ fo2s){
  int bh = blockIdx.x; int b = bh>>6, h = bh&63;
  __shared__ float xn[64][64];
  __shared__ float wl[128*64];
  float m = mu[b], rs = rstd[b];
  for(int i=threadIdx.x;i<4096;i+=256){
    int c=i>>6, w=i&63;
    size_t sp=(size_t)c*4096 + h*64 + w;
    float v = x[(size_t)b*262144 + sp];
    xn[c][w] = (v-m)*rs*n1w[sp] + n1b[sp];
  }
  for(int i=threadIdx.x;i<8192;i+=256) wl[i]=ipw[i];
  __syncthreads();
  int px = threadIdx.x & 63, ob = (threadIdx.x>>6)*32;
  float acc[32];
  #pragma unroll
  for(int j=0;j<32;j++) acc[j]=0.f;
  for(int c=0;c<64;c++){
    float xv = xn[c][px];
    #pragma unroll
    for(int j=0;j<32;j++) acc[j] = fmaf(wl[(ob+j)*64+c], xv, acc[j]);
  }
  for(int j=0;j<32;j++){
    int o = ob+j;
    float v = acc[j] + ipb[o];
    if(o<64) fo1_raw[((size_t)(b*64+o))*4096 + h*64 + px] = v;
    else     fo2s  [((size_t)(b*64+o-64))*4096 + h*64 + px] = silu_f(v);
  }
}

// ---------------- depthwise 3x3 + silu, writes normal + transposed spatial ----------------
__global__ __launch_bounds__(256) void dwconv_silu_tr(const float* __restrict__ src_,
    const float* __restrict__ dww, const float* __restrict__ dwb,
    float* __restrict__ fo1s, float* __restrict__ fo1t){
  int bc = blockIdx.x; int c = bc & 63;
  const float* src = src_ + (size_t)bc*4096;
  float wk[9];
  #pragma unroll
  for(int k=0;k<9;k++) wk[k]=dww[c*9+k];
  float bias = dwb[c];
  __shared__ float tl[64][65];
  for(int i=threadIdx.x;i<4096;i+=256){
    int h=i>>6, w=i&63;
    float acc=bias;
    #pragma unroll
    for(int kh=0;kh<3;kh++){
      int ih=h+kh-1; if(ih<0||ih>63) continue;
      #pragma unroll
      for(int kw=0;kw<3;kw++){
        int iw=w+kw-1; if(iw<0||iw>63) continue;
        acc += wk[kh*3+kw]*src[ih*64+iw];
      }
    }
    tl[h][w] = silu_f(acc);
  }
  __syncthreads();
  float* ps = fo1s + (size_t)bc*4096;
  float* pt = fo1t + (size_t)bc*4096;
  for(int i=threadIdx.x;i<4096;i+=256){
    ps[i] = tl[i>>6][i&63];
    pt[i] = tl[i&63][i>>6];
  }
}

// ---------------- weight preps ----------------
__global__ __launch_bounds__(256) void cvt_w_bf(const float* __restrict__ w, uint* __restrict__ wb){
  int i = blockIdx.x*256 + threadIdx.x;   // 131072 pairs
  float2 v = *(const float2*)(w + 2*i);
  wb[i] = f2bf2(v.x, v.y);
}
__global__ __launch_bounds__(256) void wdt_make(const float* __restrict__ dtw,
    const float* __restrict__ xpw, ushort* __restrict__ wcomb){
  int d = blockIdx.x;
  float wr[16];
  #pragma unroll
  for(int r=0;r<16;r++) wr[r]=dtw[d*16+r];
  for(int k=threadIdx.x;k<512;k+=256){
    float acc=0.f;
    #pragma unroll
    for(int r=0;r<16;r++) acc = fmaf(wr[r], xpw[r*512+k], acc);
    wcomb[(size_t)d*512+k]=f2bf(acc);
  }
}
__global__ __launch_bounds__(256) void cvt_bc_pad(const float* __restrict__ xpw, ushort* __restrict__ wcomb){
  int i = blockIdx.x*256 + threadIdx.x;   // 32768
  int row = i>>9, k = i&511;
  float v = (row<32) ? xpw[8192 + row*512 + k] : 0.f;
  wcomb[(size_t)(512+row)*512 + k] = f2bf(v);
}
__global__ __launch_bounds__(256) void fold_w_bf(const float* __restrict__ ow, ushort* __restrict__ wf){
  int i = blockIdx.x*256 + threadIdx.x;   // 32768
  int c = i>>9, d2 = i&511;
  wf[i] = f2bf(ow[c*512+d2] + ow[(64+c)*512+d2] + ow[(128+c)*512+d2] + ow[(192+c)*512+d2]);
}

// ---------------- gather u transposed: (B, L=4096, 256) bf16 ----------------
__global__ __launch_bounds__(256) void gather_u_t(const float* __restrict__ fo1s,
    const float* __restrict__ fo1t, uint* __restrict__ u_bf){
  int blk = blockIdx.x;
  int lt = blk&63, part = (blk>>6)&3, b = blk>>8;
  int l0 = lt<<6;
  const float* s = (part<2)? fo1s : fo1t;
  bool rev = part&1;
  __shared__ float tl[64][65];
  for(int i=threadIdx.x;i<4096;i+=256){
    int c=i>>6, j=i&63;
    int l = l0 + j;
    int idx = rev ? (4095-l) : l;
    tl[c][j] = s[((size_t)(b*64+c))*4096 + idx];
  }
  __syncthreads();
  for(int i=threadIdx.x;i<2048;i+=256){
    int j = i>>5, cp = i&31;
    int l = l0 + j;
    u_bf[((size_t)(b*4096)+l)*128 + part*32 + cp] = f2bf2(tl[2*cp][j], tl[2*cp+1][j]);
  }
}

// ---------------- MFMA GEMM: xz = W(1024,256) x U^T ----------------
__global__ __launch_bounds__(256) void gemm_xz_mfma(const ushort* __restrict__ u_bf,
    const ushort* __restrict__ w_bf, float* __restrict__ xi0, ushort* __restrict__ z_bf){
  int blk = blockIdx.x; int b = blk>>5; int l0 = (blk&31)<<7;
  int o0 = blockIdx.y<<7;
  __shared__ __align__(16) ushort Al[2][5120];
  __shared__ __align__(16) ushort Bl[2][5120];
  int t = threadIdx.x, lane = t&63, wid = t>>6;
  int wr = wid>>1, wc = wid&1;
  int rl = lane&15, kseg = (lane>>4)*8;
  f4_t acc[4][4];
  #pragma unroll
  for(int m=0;m<4;m++)
    #pragma unroll
    for(int n=0;n<4;n++) acc[m][n]=(f4_t){0.f,0.f,0.f,0.f};

  int r0 = t>>2, r1 = 64+(t>>2), seg = t&3;
  uint4 rA0,rA1,rB0,rB1;
  auto issue=[&](int kc){
    rA0 = *(const uint4*)&w_bf[(size_t)(o0+r0)*256 + kc*32 + seg*8];
    rA1 = *(const uint4*)&w_bf[(size_t)(o0+r1)*256 + kc*32 + seg*8];
    rB0 = *(const uint4*)&u_bf[((size_t)(b*4096)+l0+r0)*256 + kc*32 + seg*8];
    rB1 = *(const uint4*)&u_bf[((size_t)(b*4096)+l0+r1)*256 + kc*32 + seg*8];
  };
  auto store=[&](int buf){
    *(uint4*)&Al[buf][r0*40 + seg*8] = rA0;
    *(uint4*)&Al[buf][r1*40 + seg*8] = rA1;
    *(uint4*)&Bl[buf][r0*40 + seg*8] = rB0;
    *(uint4*)&Bl[buf][r1*40 + seg*8] = rB1;
  };
  issue(0); store(0); __syncthreads();
  int buf=0;
  for(int kc=0;kc<8;kc++){
    bool more = kc<7;
    if(more) issue(kc+1);
    bf8_t af[4], bfr[4];
    #pragma unroll
    for(int m=0;m<4;m++) af[m] = *(const bf8_t*)&Al[buf][(wr*64+m*16+rl)*40 + kseg];
    #pragma unroll
    for(int n=0;n<4;n++) bfr[n] = *(const bf8_t*)&Bl[buf][(wc*64+n*16+rl)*40 + kseg];
    #pragma unroll
    for(int m=0;m<4;m++)
      #pragma unroll
      for(int n=0;n<4;n++)
        acc[m][n] = __builtin_amdgcn_mfma_f32_16x16x32_bf16(af[m], bfr[n], acc[m][n], 0,0,0);
    __syncthreads();
    if(more){ store(buf^1); __syncthreads(); }
    buf^=1;
  }
  int orow = (lane>>4)*4;
  if(o0 < 512){
    #pragma unroll
    for(int m=0;m<4;m++)
      #pragma unroll
      for(int n=0;n<4;n++){
        int l = l0 + wc*64 + n*16 + rl;
        #pragma unroll
        for(int r=0;r<4;r++){
          int o = o0 + wr*64 + m*16 + orow + r;
          xi0[((size_t)(b*512)+o)*4096 + l] = acc[m][n][r];
        }
      }
  } else {
    #pragma unroll
    for(int m=0;m<4;m++)
      #pragma unroll
      for(int n=0;n<4;n++){
        int l = l0 + wc*64 + n*16 + rl;
        int gz = (o0 - 512 + wr*64 + m*16) >> 4;
        uint2 pkz;
        pkz.x = f2bf2(acc[m][n][0], acc[m][n][1]);
        pkz.y = f2bf2(acc[m][n][2], acc[m][n][3]);
        *(uint2*)&z_bf[(((size_t)(b*32)+gz)*4096 + l)*16 + orow] = pkz;
      }
  }
}

// ---------------- conv1d (k=4 causal) + silu: xi bf16 c-major + bf16 l-major ----------------
__global__ __launch_bounds__(256) void conv1d_silu2(const float* __restrict__ xi0,
    const float* __restrict__ cw, const float* __restrict__ cb,
    ushort* __restrict__ xi_c, ushort* __restrict__ xi_l){
  int blk = blockIdx.x;          // 2048: lt(64) | dt8(8) | b(4)
  int lt = blk&63, dt8 = (blk>>6)&7, b = blk>>9;
  int d0 = dt8*64, l0 = lt*64;
  __shared__ float T[64][65];
  int t = threadIdx.x, lloc = t&63, dq = t>>6;
  #pragma unroll 4
  for(int i=0;i<16;i++){
    int dloc = dq + i*4;
    int d = d0 + dloc;
    int l = l0 + lloc;
    size_t rowb = ((size_t)(b*512)+d)*4096;
    float acc = cb[d];
    #pragma unroll
    for(int k=0;k<4;k++){
      int ls = l-3+k;
      if(ls>=0) acc += cw[d*4+k]*xi0[rowb+ls];
    }
    acc = silu_f(acc);
    xi_c[rowb + l] = f2bf(acc);
    T[lloc][dloc] = acc;
  }
  __syncthreads();
  int dl = t&63;
  #pragma unroll 4
  for(int i=0;i<16;i++){
    int lloc2 = dq + i*4;
    xi_l[((size_t)(b*4096)+l0+lloc2)*512 + d0 + dl] = f2bf(T[lloc2][dl]);
  }
}

// ---------------- merged MFMA GEMM: [dt(512); bc(32)] = Wcomb(576,512) x xi^T ----------------
__global__ __launch_bounds__(256) void gemm_proj_mfma(const ushort* __restrict__ xi_bf,
    const ushort* __restrict__ wcomb, const float* __restrict__ dtb,
    ushort* __restrict__ dt_bf, ushort* __restrict__ bc_out){
  int blk = blockIdx.x; int b = blk>>6; int l0 = (blk&63)<<6;
  int o0 = blockIdx.y<<6;
  __shared__ __align__(16) ushort Al[2][2560];
  __shared__ __align__(16) ushort Bl[2][2560];
  int t = threadIdx.x, lane = t&63, wid = t>>6;
  int wo = wid>>1, wl = wid&1;
  int rl = lane&15, kseg = (lane>>4)*8;
  f4_t acc[2][2];
  #pragma unroll
  for(int m=0;m<2;m++)
    #pragma unroll
    for(int n=0;n<2;n++) acc[m][n]=(f4_t){0.f,0.f,0.f,0.f};
  int r = t>>2, seg = t&3;
  uint4 rA,rB;
  auto issue=[&](int kc){
    rA = *(const uint4*)&wcomb[(size_t)(o0+r)*512 + kc*32 + seg*8];
    rB = *(const uint4*)&xi_bf[((size_t)(b*4096)+l0+r)*512 + kc*32 + seg*8];
  };
  auto store=[&](int buf){
    *(uint4*)&Al[buf][r*40 + seg*8] = rA;
    *(uint4*)&Bl[buf][r*40 + seg*8] = rB;
  };
  issue(0); store(0); __syncthreads();
  int buf=0;
  for(int kc=0;kc<16;kc++){
    bool more = kc<15;
    if(more) issue(kc+1);
    bf8_t af[2], bfr[2];
    #pragma unroll
    for(int m=0;m<2;m++) af[m] = *(const bf8_t*)&Al[buf][(wo*32+m*16+rl)*40 + kseg];
    #pragma unroll
    for(int n=0;n<2;n++) bfr[n] = *(const bf8_t*)&Bl[buf][(wl*32+n*16+rl)*40 + kseg];
    #pragma unroll
    for(int m=0;m<2;m++)
      #pragma unroll
      for(int n=0;n<2;n++)
        acc[m][n] = __builtin_amdgcn_mfma_f32_16x16x32_bf16(af[m], bfr[n], acc[m][n], 0,0,0);
    __syncthreads();
    if(more){ store(buf^1); __syncthreads(); }
    buf^=1;
  }
  int orow = (lane>>4)*4;
  #pragma unroll
  for(int m=0;m<2;m++)
    #pragma unroll
    for(int n=0;n<2;n++){
      int l = l0 + wl*32 + n*16 + rl;
      #pragma unroll
      for(int rr=0;rr<4;rr++){
        int o = o0 + wo*32 + m*16 + orow + rr;
        float v = acc[m][n][rr];
        if(o<512){
          v += dtb[o];
          float sp = (v>20.f)? v : 0.69314718056f*__log2f(1.f+exp2f(1.44269504089f*v));
          dt_bf[((size_t)(b*512)+o)*4096 + l] = f2bf(sp);
        } else if(o<544){
          bc_out[((size_t)(b*4096)+l)*32 + (o-512)] = f2bf(v);
        }
      }
    }
}

// ================= scan v3: 32 chunks of 128; wave = 16 ch x 4 states =================
// dt/xi bf16 c-major; B/C bf16 (B,L,32). LDS: packed (dt|xi) uints + bf16 B/C.
__global__ __launch_bounds__(64) void scan3_p1(
    const ushort* __restrict__ dtx, const ushort* __restrict__ xix,
    const ushort* __restrict__ bc, const float* __restrict__ Alog,
    float4* __restrict__ Pbuf, float4* __restrict__ qbuf){
  int blk=blockIdx.x;
  int c=blk&31, g=(blk>>5)&31, b=blk>>10;
  int lane=threadIdx.x, ch=lane>>2, sq=lane&3;
  int d=g*16+ch;
  float4 Ar = *(const float4*)(Alog + d*16 + sq*4);
  float A2[4];
  A2[0]=-__expf(Ar.x)*1.44269504088896f;
  A2[1]=-__expf(Ar.y)*1.44269504088896f;
  A2[2]=-__expf(Ar.z)*1.44269504088896f;
  A2[3]=-__expf(Ar.w)*1.44269504088896f;
  __shared__ __align__(16) uint   pk[2][16][36];
  __shared__ __align__(16) ushort blh[2][32][20];
  const int l0c = c*128;
  const size_t dtrow = ((size_t)(b*512)+d)*4096;
  const ushort* xb = bc + (size_t)b*4096*32;
  uint4 rdt, rxi; uint2 rb[2];
  auto issue=[&](int t){
    int l0 = l0c + t*32;
    rdt = *(const uint4*)(dtx + dtrow + l0 + sq*8);
    rxi = *(const uint4*)(xix + dtrow + l0 + sq*8);
    #pragma unroll
    for(int k=0;k<2;k++){
      int j=ch+k*16;
      rb[k]=*(const uint2*)(xb + (size_t)(l0+j)*32 + sq*4);
    }
  };
  auto store=[&](int buf){
    const uint* dp=(const uint*)&rdt; const uint* xp=(const uint*)&rxi;
    #pragma unroll
    for(int k=0;k<4;k++){
      uint ud=dp[k], ux=xp[k];
      uint2 w;
      w.x = (ud&0xffffu)|(ux<<16);
      w.y = (ud>>16)|(ux&0xffff0000u);
      *(uint2*)&pk[buf][ch][sq*8+2*k] = w;
    }
    #pragma unroll
    for(int k=0;k<2;k++)
      *(uint2*)&blh[buf][ch+k*16][sq*4] = rb[k];
  };
  float P[4]={1.f,1.f,1.f,1.f}, q[4]={0.f,0.f,0.f,0.f};
  issue(0); store(0);
  for(int t=0;t<4;t++){
    int buf=t&1;
    if(t<3) issue(t+1);
    #pragma unroll 4
    for(int jp=0;jp<16;jp++){
      uint2 pp = *(const uint2*)&pk[buf][ch][jp*2];
      uint2 bu0 = *(const uint2*)&blh[buf][2*jp][sq*4];
      uint2 bu1 = *(const uint2*)&blh[buf][2*jp+1][sq*4];
      {
        float dtv=bflo(pp.x), xiv=bfhi(pp.x);
        float u=dtv*xiv;
        float Bv[4]={bflo(bu0.x),bfhi(bu0.x),bflo(bu0.y),bfhi(bu0.y)};
        #pragma unroll
        for(int i=0;i<4;i++){ float dA=exp2f(dtv*A2[i]); P[i]*=dA; q[i]=fmaf(dA,q[i],u*Bv[i]); }
      }
      {
        float dtv=bflo(pp.y), xiv=bfhi(pp.y);
        float u=dtv*xiv;
        float Bv[4]={bflo(bu1.x),bfhi(bu1.x),bflo(bu1.y),bfhi(bu1.y)};
        #pragma unroll
        for(int i=0;i<4;i++){ float dA=exp2f(dtv*A2[i]); P[i]*=dA; q[i]=fmaf(dA,q[i],u*Bv[i]); }
      }
    }
    if(t<3) store(buf^1);
  }
  int idx = blk*64 + lane;
  Pbuf[idx]=make_float4(P[0],P[1],P[2],P[3]);
  qbuf[idx]=make_float4(q[0],q[1],q[2],q[3]);
}

__global__ __launch_bounds__(256) void scan3_mid(const float4* __restrict__ Pbuf,
    const float4* __restrict__ qbuf, float4* __restrict__ hstart){
  int tid = blockIdx.x*256+threadIdx.x;  // 8192
  int lane = tid&63, sg = tid>>6;
  float4 h = make_float4(0.f,0.f,0.f,0.f);
  #pragma unroll
  for(int c=0;c<32;c++){
    int idx = (sg*32+c)*64 + lane;
    hstart[idx]=h;
    float4 P=Pbuf[idx], q=qbuf[idx];
    h.x = fmaf(P.x,h.x,q.x);
    h.y = fmaf(P.y,h.y,q.y);
    h.z = fmaf(P.z,h.z,q.z);
    h.w = fmaf(P.w,h.w,q.w);
  }
}

__global__ __launch_bounds__(64) void scan3_p2(
    const ushort* __restrict__ dtx, const ushort* __restrict__ xix,
    const ushort* __restrict__ z_bf, const ushort* __restrict__ bc,
    const float* __restrict__ Alog, const float* __restrict__ Dp,
    const float4* __restrict__ hstart, ushort* __restrict__ y_bf){
  int blk=blockIdx.x;
  int c=blk&31, g=(blk>>5)&31, b=blk>>10;
  int lane=threadIdx.x, ch=lane>>2, sq=lane&3;
  int d=g*16+ch;
  float4 Ar = *(const float4*)(Alog + d*16 + sq*4);
  float A2[4];
  A2[0]=-__expf(Ar.x)*1.44269504088896f;
  A2[1]=-__expf(Ar.y)*1.44269504088896f;
  A2[2]=-__expf(Ar.z)*1.44269504088896f;
  A2[3]=-__expf(Ar.w)*1.44269504088896f;
  float Dv = Dp[d];
  int je = lane>>1, halfe = lane&1;
  __shared__ __align__(16) uint   pk[2][16][36];
  __shared__ __align__(16) ushort bclh[2][32][36];
  __shared__ __align__(16) float  pl[32][18];
  const int l0c = c*128;
  const size_t dtrow = ((size_t)(b*512)+d)*4096;
  const ushort* xb = bc + (size_t)b*4096*32;
  const size_t zybase = (((size_t)(b*32)+g)*4096);
  uint4 rdt, rxi; uint2 rbc[4];
  uint4 rzb[2];
  auto issue=[&](int t){
    int l0 = l0c + t*32;
    rdt = *(const uint4*)(dtx + dtrow + l0 + sq*8);
    rxi = *(const uint4*)(xix + dtrow + l0 + sq*8);
    #pragma unroll
    for(int k=0;k<4;k++){
      int j=(lane>>3)+k*8, seg=lane&7;
      rbc[k]=*(const uint2*)(xb + (size_t)(l0+j)*32 + seg*4);
    }
    rzb[t&1] = *(const uint4*)&z_bf[(zybase + l0 + je)*16 + halfe*8];
  };
  auto store=[&](int buf){
    const uint* dp=(const uint*)&rdt; const uint* xp=(const uint*)&rxi;
    #pragma unroll
    for(int k=0;k<4;k++){
      uint ud=dp[k], ux=xp[k];
      uint2 w;
      w.x = (ud&0xffffu)|(ux<<16);
      w.y = (ud>>16)|(ux&0xffff0000u);
      *(uint2*)&pk[buf][ch][sq*8+2*k] = w;
    }
    #pragma unroll
    for(int k=0;k<4;k++)
      *(uint2*)&bclh[buf][(lane>>3)+k*8][(lane&7)*4] = rbc[k];
  };
  float h[4];
  {
    float4 h0 = hstart[blk*64 + lane];
    h[0]=h0.x; h[1]=h0.y; h[2]=h0.z; h[3]=h0.w;
  }
  issue(0); store(0);
  for(int t=0;t<4;t++){
    int buf=t&1;
    if(t<3) issue(t+1);
    #pragma unroll 4
    for(int jp=0;jp<16;jp++){
      uint2 pp = *(const uint2*)&pk[buf][ch][jp*2];
      {
        int j=2*jp;
        uint2 bu = *(const uint2*)&bclh[buf][j][sq*4];
        uint2 cu = *(const uint2*)&bclh[buf][j][16+sq*4];
        float dtv=bflo(pp.x), xiv=bfhi(pp.x);
        float u=dtv*xiv;
        float Bv[4]={bflo(bu.x),bfhi(bu.x),bflo(bu.y),bfhi(bu.y)};
        float Cv[4]={bflo(cu.x),bfhi(cu.x),bflo(cu.y),bfhi(cu.y)};
        float p;
        #pragma unroll
        for(int i=0;i<4;i++){ float dA=exp2f(dtv*A2[i]); h[i]=fmaf(dA,h[i],u*Bv[i]); }
        p = h[0]*Cv[0]; p=fmaf(h[1],Cv[1],p); p=fmaf(h[2],Cv[2],p); p=fmaf(h[3],Cv[3],p);
        p = quad_sum4(p);
        if(sq==0) pl[j][ch] = p + xiv*Dv;
      }
      {
        int j=2*jp+1;
        uint2 bu = *(const uint2*)&bclh[buf][j][sq*4];
        uint2 cu = *(const uint2*)&bclh[buf][j][16+sq*4];
        float dtv=bflo(pp.y), xiv=bfhi(pp.y);
        float u=dtv*xiv;
        float Bv[4]={bflo(bu.x),bfhi(bu.x),bflo(bu.y),bfhi(bu.y)};
        float Cv[4]={bflo(cu.x),bfhi(cu.x),bflo(cu.y),bfhi(cu.y)};
        float p;
        #pragma unroll
        for(int i=0;i<4;i++){ float dA=exp2f(dtv*A2[i]); h[i]=fmaf(dA,h[i],u*Bv[i]); }
        p = h[0]*Cv[0]; p=fmaf(h[1],Cv[1],p); p=fmaf(h[2],Cv[2],p); p=fmaf(h[3],Cv[3],p);
        p = quad_sum4(p);
        if(sq==0) pl[j][ch] = p + xiv*Dv;
      }
    }
    {
      int l = l0c + t*32 + je;
      uint4 zr = rzb[t&1];
      const ushort* zp = (const ushort*)&zr;
      float pv[8];
      #pragma unroll
      for(int k=0;k<4;k++){
        float2 v2 = *(const float2*)&pl[je][halfe*8+2*k];
        pv[2*k]=v2.x; pv[2*k+1]=v2.y;
      }
      float yv[8];
      #pragma unroll
      for(int k=0;k<8;k++) yv[k] = pv[k] * silu_f(bf2f(zp[k]));
      uint4 yo;
      uint* yp=(uint*)&yo;
      yp[0]=f2bf2(yv[0],yv[1]); yp[1]=f2bf2(yv[2],yv[3]);
      yp[2]=f2bf2(yv[4],yv[5]); yp[3]=f2bf2(yv[6],yv[7]);
      *(uint4*)&y_bf[((size_t)zybase + l)*16 + halfe*8] = yo;
    }
    if(t<3) store(buf^1);
  }
}

// ---------------- MFMA GEMM: res = (W'(64,512) x Y^T) * fo2s, out (B,64,L) c-major ----------------
__global__ __launch_bounds__(256) void gemm_res_mfma(const ushort* __restrict__ y_bf,
    const ushort* __restrict__ wf_bf, const float* __restrict__ fo2s, float* __restrict__ res){
  int blk = blockIdx.x; int b = blk>>5; int l0 = (blk&31)<<7;
  __shared__ __align__(16) ushort Wl[2][2560];
  __shared__ __align__(16) ushort Yl[2][5120];
  int t = threadIdx.x, lane = t&63, wid = t>>6;
  int rl = lane&15, kseg = (lane>>4)*8;
  f4_t acc[4][2];
  #pragma unroll
  for(int m=0;m<4;m++)
    #pragma unroll
    for(int n=0;n<2;n++) acc[m][n]=(f4_t){0.f,0.f,0.f,0.f};
  int ry = t>>1;
  int rw = t>>2, sgw = t&3;
  uint4 rY0, rY1, rW;
  auto issue=[&](int kc){
    int gg = 2*kc + (t&1);
    const ushort* yrow = &y_bf[(((size_t)(b*32)+gg)*4096 + l0+ry)*16];
    rY0 = *(const uint4*)&yrow[0];
    rY1 = *(const uint4*)&yrow[8];
    rW  = *(const uint4*)&wf_bf[(size_t)rw*512 + kc*32 + sgw*8];
  };
  auto store=[&](int buf){
    *(uint4*)&Yl[buf][ry*40 + (t&1)*16]     = rY0;
    *(uint4*)&Yl[buf][ry*40 + (t&1)*16 + 8] = rY1;
    *(uint4*)&Wl[buf][rw*40 + sgw*8]        = rW;
  };
  issue(0); store(0); __syncthreads();
  int buf=0;
  for(int kc=0;kc<16;kc++){
    bool more = kc<15;
    if(more) issue(kc+1);
    bf8_t aw[4], by[2];
    #pragma unroll
    for(int m=0;m<4;m++) aw[m] = *(const bf8_t*)&Wl[buf][(m*16+rl)*40 + kseg];
    #pragma unroll
    for(int n=0;n<2;n++) by[n] = *(const bf8_t*)&Yl[buf][(wid*32+n*16+rl)*40 + kseg];
    #pragma unroll
    for(int m=0;m<4;m++)
      #pragma unroll
      for(int n=0;n<2;n++)
        acc[m][n] = __builtin_amdgcn_mfma_f32_16x16x32_bf16(aw[m], by[n], acc[m][n], 0,0,0);
    __syncthreads();
    if(more){ store(buf^1); __syncthreads(); }
    buf^=1;
  }
  int orow = (lane>>4)*4;
  #pragma unroll
  for(int m=0;m<4;m++)
    #pragma unroll
    for(int n=0;n<2;n++){
      int l = l0 + wid*32 + n*16 + rl;
      #pragma unroll
      for(int r=0;r<4;r++){
        int o = m*16 + orow + r;
        size_t idx = ((size_t)(b*64+o))*4096 + l;
        res[idx] = acc[m][n][r]*fo2s[idx];
      }
    }
}

// ---------------- per (b,c) spatial mean ----------------
__global__ __launch_bounds__(256) void colmean(const float* __restrict__ res, float* __restrict__ fm){
  int bc = blockIdx.x;
  const float* p = res + (size_t)bc*4096;
  float s=0;
  for(int i=threadIdx.x;i<4096;i+=256) s+=p[i];
  __shared__ float ls[256];
  ls[threadIdx.x]=s; __syncthreads();
  for(int st=128;st>0;st>>=1){ if(threadIdx.x<st) ls[threadIdx.x]+=ls[threadIdx.x+st]; __syncthreads(); }
  if(threadIdx.x==0) fm[bc]=ls[0]*(1.f/4096.f);
}

// ---------------- tiny mamba2 over channel sequence ----------------
__global__ __launch_bounds__(64) void mamba2_kernel(const float* __restrict__ fm,
    const float* __restrict__ in_w, const float* __restrict__ cw, const float* __restrict__ cb,
    const float* __restrict__ xp, const float* __restrict__ dtw, const float* __restrict__ dtb,
    const float* __restrict__ Alog, const float* __restrict__ Dp, const float* __restrict__ ow,
    float* __restrict__ fsum){
  int b = blockIdx.x; int t = threadIdx.x;
  __shared__ float xi0m[64][4], xim[64][4], dtm[64][4], xbl[64][33], ym[64][4];
  float a0 = fm[b*64+t], a1 = fm[b*64 + 63-t];
  float zreg[4];
  #pragma unroll
  for(int d2=0;d2<4;d2++){
    xi0m[t][d2] = in_w[d2*2+0]*a0 + in_w[d2*2+1]*a1;
    zreg[d2]    = in_w[(4+d2)*2+0]*a0 + in_w[(4+d2)*2+1]*a1;
  }
  __syncthreads();
  float xir[4];
  #pragma unroll
  for(int d2=0;d2<4;d2++){
    float acc=cb[d2];
    #pragma unroll
    for(int k=0;k<4;k++){
      int srow=t-3+k;
      if(srow>=0) acc += cw[d2*4+k]*xi0m[srow][d2];
    }
    xir[d2]=silu_f(acc);
    xim[t][d2]=xir[d2];
  }
  for(int j=0;j<33;j++){
    float acc=0;
    #pragma unroll
    for(int d2=0;d2<4;d2++) acc += xp[j*4+d2]*xir[d2];
    xbl[t][j]=acc;
  }
  #pragma unroll
  for(int d2=0;d2<4;d2++){
    float v = xbl[t][0]*dtw[d2] + dtb[d2];
    dtm[t][d2] = (v>20.f)? v : log1pf(__expf(v));
  }
  __syncthreads();
  int dd=t>>4, s=t&15;
  float A2 = -__expf(Alog[dd*16+s]) * 1.44269504088896f;
  float h=0.f;
  for(int c=0;c<64;c++){
    float dtv=dtm[c][dd];
    float dA=exp2f(dtv*A2);
    h = fmaf(dA, h, dtv*xim[c][dd]*xbl[c][1+s]);
    float p = h*xbl[c][17+s];
    p += __shfl_xor(p,1,16);
    p += __shfl_xor(p,2,16);
    p += __shfl_xor(p,4,16);
    p += __shfl_xor(p,8,16);
    if(s==0) ym[c][dd]=p;
  }
  __syncthreads();
  float os=0.f;
  #pragma unroll
  for(int d2=0;d2<4;d2++){
    float yv = (ym[t][d2] + xim[t][d2]*Dp[d2]) * silu_f(zreg[d2]);
    os += yv * (ow[d2] + ow[4+d2]);
  }
  fsum[b*64+t]=os;
}

// ---------------- foss = res*(1+foc) ; x2 = outproj(foss) + x ----------------
__global__ __launch_bounds__(256) void outproj_kernel(const float* __restrict__ res,
    const float* __restrict__ fsum, const float* __restrict__ opw, const float* __restrict__ opb,
    const float* __restrict__ x, float* __restrict__ x2){
  int bh=blockIdx.x; int b=bh>>6,h=bh&63;
  __shared__ float tile[64][64];
  __shared__ float wl[4096];
  for(int i=threadIdx.x;i<4096;i+=256) wl[i]=opw[i];
  for(int i=threadIdx.x;i<4096;i+=256){
    int c=i>>6,w=i&63;
    tile[c][w]=res[((size_t)(b*64+c))*4096 + h*64 + w]*(1.f+fsum[b*64+c]);
  }
  __syncthreads();
  int px=threadIdx.x&63, og=threadIdx.x>>6;
  float acc[16];
  #pragma unroll
  for(int j=0;j<16;j++) acc[j]=0.f;
  for(int c=0;c<64;c++){
    float v=tile[c][px];
    #pragma unroll
    for(int j=0;j<16;j++) acc[j]=fmaf(wl[(og*16+j)*64+c],v,acc[j]);
  }
  for(int j=0;j<16;j++){
    int o=og*16+j;
    size_t idx=((size_t)(b*64+o))*4096 + h*64 + px;
    x2[idx]=acc[j]+opb[o]+x[idx];
  }
}

// ---------------- LN2 apply + ffn_in (64->256), grid (256,4), g bf16 ----------------
__global__ __launch_bounds__(256) void ffn_in_kernel(const float* __restrict__ x2,
    const float* __restrict__ n2w, const float* __restrict__ n2b,
    const float* __restrict__ fiw, const float* __restrict__ fib,
    const float* __restrict__ mu2, const float* __restrict__ rstd2,
    ushort* __restrict__ g){
  int bh=blockIdx.x; int b=bh>>6,h=bh&63;
  int oq=blockIdx.y;             // 0..3, 64 outputs each
  __shared__ float tile[64][64];
  __shared__ float wl[64*64];
  float m=mu2[b], rs=rstd2[b];
  for(int i=threadIdx.x;i<4096;i+=256){
    int c=i>>6,w=i&63;
    size_t sp=(size_t)c*4096 + h*64 + w;
    tile[c][w]=(x2[(size_t)b*262144+sp]-m)*rs*n2w[sp]+n2b[sp];
  }
  for(int i=threadIdx.x;i<4096;i+=256) wl[i]=fiw[(size_t)(oq*64)*64 + i];
  __syncthreads();
  int px=threadIdx.x&63, og=threadIdx.x>>6;
  float acc[16];
  #pragma unroll
  for(int j=0;j<16;j++) acc[j]=0.f;
  int ob = og*16;
  for(int c=0;c<64;c++){
    float v=tile[c][px];
    #pragma unroll
    for(int j=0;j<16;j++) acc[j]=fmaf(wl[(ob+j)*64+c],v,acc[j]);
  }
  for(int j=0;j<16;j++){
    int o = oq*64 + ob + j;
    g[((size_t)(b*256+o))*4096 + h*64 + px]=f2bf(acc[j]+fib[o]);
  }
}

// ---------------- ffn depthwise 3x3 + gelu-gate (bf16 in/out) ----------------
__global__ __launch_bounds__(256) void ffn_dw_gate(const ushort* __restrict__ g,
    const float* __restrict__ dww, const float* __restrict__ dwb, ushort* __restrict__ gm){
  int e = blockIdx.x*256 + threadIdx.x;   // 4*128*4096
  int sp = e & 4095, j = (e>>12)&127, b = e>>19;
  int h = sp>>6, w = sp&63;
  float v[2];
  #pragma unroll
  for(int half=0;half<2;half++){
    int ch = j + half*128;
    const ushort* gp = g + ((size_t)(b*256+ch))*4096;
    float acc = dwb[ch];
    #pragma unroll
    for(int kh=0;kh<3;kh++){
      int ih=h+kh-1; if(ih<0||ih>63) continue;
      #pragma unroll
      for(int kw=0;kw<3;kw++){
        int iw=w+kw-1; if(iw<0||iw>63) continue;
        acc += dww[ch*9+kh*3+kw]*bf2f(gp[ih*64+iw]);
      }
    }
    v[half]=acc;
  }
  float ge = 0.5f*v[0]*(1.f+erff(v[0]*0.70710678f));
  gm[((size_t)(b*128+j))*4096 + sp] = f2bf(ge*v[1]);
}

// ---------------- ffn_out (128->64) + bias + residual add -> d_out ----------------
__global__ __launch_bounds__(256) void ffn_out_kernel(const ushort* __restrict__ gm,
    const float* __restrict__ fow, const float* __restrict__ fob,
    const float* __restrict__ x2, float* __restrict__ out){
  int bh=blockIdx.x; int b=bh>>6,h=bh&63;
  __shared__ float tile[128][64];
  __shared__ float wl[64*128];
  for(int i=threadIdx.x;i<8192;i+=256){
    int c=i>>6,w=i&63;
    tile[c][w]=bf2f(gm[((size_t)(b*128+c))*4096 + h*64 + w]);
  }
  for(int i=threadIdx.x;i<8192;i+=256) wl[i]=fow[i];
  __syncthreads();
  int px=threadIdx.x&63, og=threadIdx.x>>6;
  float acc[16];
  #pragma unroll
  for(int j=0;j<16;j++) acc[j]=0.f;
  for(int c=0;c<128;c++){
    float v=tile[c][px];
    #pragma unroll
    for(int j=0;j<16;j++) acc[j]=fmaf(wl[(og*16+j)*128+c],v,acc[j]);
  }
  for(int j=0;j<16;j++){
    int o=og*16+j;
    size_t idx=((size_t)(b*64+o))*4096 + h*64 + px;
    out[idx]=acc[j]+fob[o]+x2[idx];
  }
}

extern "C" void kernel_launch(void* const* d_in, const int* in_sizes, int n_in,
                              void* d_out, int out_size, void* d_ws, size_t ws_size,
                              hipStream_t stream){
  const float* x      = (const float*)d_in[0];
  const float* n1w    = (const float*)d_in[1];
  const float* n1b    = (const float*)d_in[2];
  const float* n2w    = (const float*)d_in[3];
  const float* n2b    = (const float*)d_in[4];
  const float* ipw    = (const float*)d_in[5];
  const float* ipb    = (const float*)d_in[6];
  const float* dww    = (const float*)d_in[7];
  const float* dwb    = (const float*)d_in[8];
  const float* opw    = (const float*)d_in[9];
  const float* opb    = (const float*)d_in[10];
  const float* m1_inw = (const float*)d_in[11];
  const float* m1_cw  = (const float*)d_in[12];
  const float* m1_cb  = (const float*)d_in[13];
  const float* m1_xp  = (const float*)d_in[14];
  const float* m1_dtw = (const float*)d_in[15];
  const float* m1_dtb = (const float*)d_in[16];
  const float* m1_Al  = (const float*)d_in[17];
  const float* m1_D   = (const float*)d_in[18];
  const float* m1_ow  = (const float*)d_in[19];
  const float* m2_inw = (const float*)d_in[20];
  const float* m2_cw  = (const float*)d_in[21];
  const float* m2_cb  = (const float*)d_in[22];
  const float* m2_xp  = (const float*)d_in[23];
  const float* m2_dtw = (const float*)d_in[24];
  const float* m2_dtb = (const float*)d_in[25];
  const float* m2_Al  = (const float*)d_in[26];
  const float* m2_D   = (const float*)d_in[27];
  const float* m2_ow  = (const float*)d_in[28];
  const float* fiw    = (const float*)d_in[29];
  const float* fib    = (const float*)d_in[30];
  const float* fdw    = (const float*)d_in[31];
  const float* fdb    = (const float*)d_in[32];
  const float* fow    = (const float*)d_in[33];
  const float* fob    = (const float*)d_in[34];
  float* out = (float*)d_out;
  float* ws  = (float*)d_ws;

  const size_t M1 = 1048576;
  float* mu1   = ws + 0;  float* rstd1 = ws + 4;
  float* mu2   = ws + 8;  float* rstd2 = ws + 12;
  float* fmean = ws + 64;
  float* fsum  = ws + 320;
  float* lnpart= ws + 33792;
  float* base0 = ws + 36864;
  float* fo1raw= base0;                 // 1M [-> hstart -> res]
  float* fo2s  = base0 + M1;            // 1M
  float* fo1s  = base0 + 2*M1;          // 1M [-> Pbuf]
  float* fo1t  = base0 + 3*M1;          // 1M [-> qbuf]
  float* big0  = base0 + 4*M1;          // 8M: u_bf -> dt_bf(4M) -> g_bf(2M)
  float* big1  = base0 + 12*M1;         // 8M: xi0 -> y_bf(4M) + gm_bf(1M @ +4M)
  float* big2  = base0 + 20*M1;         // 8M: z_bf(4M) + xi_l(4M @ +4M)
  float* big3  = base0 + 28*M1;         // 8M: xi_c bf16 c-major (4M used)
  float* bcslot= base0 + 36*M1;         // 512K floats slot: bc_bf (256K used)
  float* x2    = base0 + 36*M1 + 524288;// 1M
  float* tail  = x2 + M1;
  ushort* w_bf    = (ushort*)tail;                    // 1024x256 bf16 (512KB)
  ushort* wcomb   = (ushort*)(tail + 131072);         // 576x512 bf16 (576KB)
  ushort* wf_bf   = (ushort*)(tail + 131072 + 147456);// 64x512 bf16 (64KB)

  uint*   u_bf  = (uint*)big0;
  ushort* dt_bf = (ushort*)big0;
  ushort* g_bf  = (ushort*)big0;
  float*  xi0   = big1;
  ushort* y_bf  = (ushort*)big1;
  ushort* gm_bf = (ushort*)(big1 + 4*M1);
  ushort* z_bf  = (ushort*)big2;
  ushort* xi_l  = (ushort*)(big2 + 4*M1);
  ushort* xi_c  = (ushort*)big3;
  ushort* bc_bf = (ushort*)bcslot;
  float*  Pbuf  = fo1s;
  float*  qbuf  = fo1t;
  float*  hstart= fo1raw;
  float*  res   = fo1raw;

  hipLaunchKernelGGL(ln_part, dim3(256), dim3(256), 0, stream, x, (float2*)lnpart);
  hipLaunchKernelGGL(ln_fin, dim3(4), dim3(64), 0, stream, (const float2*)lnpart, mu1, rstd1);
  hipLaunchKernelGGL(cvt_w_bf, dim3(512), dim3(256), 0, stream, m1_inw, (uint*)w_bf);
  hipLaunchKernelGGL(wdt_make, dim3(512), dim3(256), 0, stream, m1_dtw, m1_xp, wcomb);
  hipLaunchKernelGGL(cvt_bc_pad, dim3(128), dim3(256), 0, stream, m1_xp, wcomb);
  hipLaunchKernelGGL(fold_w_bf, dim3(128), dim3(256), 0, stream, m1_ow, wf_bf);
  hipLaunchKernelGGL(ln1_inproj, dim3(256), dim3(256), 0, stream,
                     x, n1w, n1b, ipw, ipb, mu1, rstd1, fo1raw, fo2s);
  hipLaunchKernelGGL(dwconv_silu_tr, dim3(256), dim3(256), 0, stream,
                     fo1raw, dww, dwb, fo1s, fo1t);
  hipLaunchKernelGGL(gather_u_t, dim3(1024), dim3(256), 0, stream, fo1s, fo1t, u_bf);
  hipLaunchKernelGGL(gemm_xz_mfma, dim3(128, 8), dim3(256), 0, stream,
                     (const ushort*)u_bf, w_bf, xi0, z_bf);
  hipLaunchKernelGGL(conv1d_silu2, dim3(2048), dim3(256), 0, stream,
                     xi0, m1_cw, m1_cb, xi_c, xi_l);
  hipLaunchKernelGGL(gemm_proj_mfma, dim3(256, 9), dim3(256), 0, stream,
                     xi_l, wcomb, m1_dtb, dt_bf, bc_bf);
  hipLaunchKernelGGL(scan3_p1, dim3(4096), dim3(64), 0, stream,
                     dt_bf, xi_c, bc_bf, m1_Al, (float4*)Pbuf, (float4*)qbuf);
  hipLaunchKernelGGL(scan3_mid, dim3(32), dim3(256), 0, stream,
                     (const float4*)Pbuf, (const float4*)qbuf, (float4*)hstart);
  hipLaunchKernelGGL(scan3_p2, dim3(4096), dim3(64), 0, stream,
                     dt_bf, xi_c, z_bf, bc_bf, m1_Al, m1_D, (const float4*)hstart, y_bf);
  hipLaunchKernelGGL(gemm_res_mfma, dim3(128), dim3(256), 0, stream,
                     y_bf, wf_bf, fo2s, res);
  hipLaunchKernelGGL(colmean, dim3(256), dim3(256), 0, stream, res, fmean);
  hipLaunchKernelGGL(mamba2_kernel, dim3(4), dim3(64), 0, stream,
                     fmean, m2_inw, m2_cw, m2_cb, m2_xp, m2_dtw, m2_dtb, m2_Al, m2_D, m2_ow, fsum);
  hipLaunchKernelGGL(outproj_kernel, dim3(256), dim3(256), 0, stream,
                     res, fsum, opw, opb, x, x2);
  hipLaunchKernelGGL(ln_part, dim3(256), dim3(256), 0, stream, x2, (float2*)lnpart);
  hipLaunchKernelGGL(ln_fin, dim3(4), dim3(64), 0, stream, (const float2*)lnpart, mu2, rstd2);
  hipLaunchKernelGGL(ffn_in_kernel, dim3(256, 4), dim3(256), 0, stream,
                     x2, n2w, n2b, fiw, fib, mu2, rstd2, g_bf);
  hipLaunchKernelGGL(ffn_dw_gate, dim3(8192), dim3(256), 0, stream, g_bf, fdw, fdb, gm_bf);
  hipLaunchKernelGGL(ffn_out_kernel, dim3(256), dim3(256), 0, stream, gm_bf, fow, fob, x2, out);
}

// Round 10
// 385.639 us; speedup vs baseline: 1.0370x; 1.0370x over previous
//
#include <hip/hip_runtime.h>
#include <math.h>

// OSS / VMamba-style block. B=4, C=64, H=W=64, L=4096, d_inner=512, D_STATE=16.
// R3: gemm_xz MFMA. R4: scan v3. R5: dt/BC/res MFMA. R6: merged gemm_proj, blocked z/y.
// R7: dt/xi bf16 + packed-uint LDS. R8: D folded into pl, uint2 pk, bf16 FFN chain.
// R9: B/C stay bf16 in GLOBAL but are converted to f32 at LDS staging (unpack once
// per tile, not per use); scan inner loop back to b128 f32 B/C reads (R7 form).

#define DEV static __device__ __forceinline__

DEV float silu_f(float x){ return x / (1.f + __expf(-x)); }

DEV ushort f2bf(float f){
  uint u = __float_as_uint(f);
  uint r = (u + 0x7FFF + ((u>>16)&1)) >> 16;
  return (ushort)r;
}
DEV uint f2bf2(float lo, float hi){
  return (uint)f2bf(lo) | ((uint)f2bf(hi)<<16);
}
DEV float bf2f(ushort u){ return __uint_as_float(((uint)u)<<16); }
DEV float bflo(uint u){ return __uint_as_float(u<<16); }
DEV float bfhi(uint u){ return __uint_as_float(u&0xffff0000u); }

typedef __attribute__((ext_vector_type(8))) short bf8_t;
typedef __attribute__((ext_vector_type(4))) float f4_t;

DEV float quad_sum4(float v){
  v += __int_as_float(__builtin_amdgcn_update_dpp(0, __float_as_int(v), 0xB1, 0xF, 0xF, false));
  v += __int_as_float(__builtin_amdgcn_update_dpp(0, __float_as_int(v), 0x4E, 0xF, 0xF, false));
  return v;
}

// ---------------- LayerNorm stats, two-stage ----------------
__global__ __launch_bounds__(256) void ln_part(const float* __restrict__ x,
                                               float2* __restrict__ part){
  int blk = blockIdx.x; int b = blk>>6, pc = blk&63;
  const float* p = x + (size_t)b*262144 + (size_t)pc*4096;
  float s=0.f, s2=0.f;
  #pragma unroll
  for(int it=0; it<4; ++it){
    int i = threadIdx.x + it*256;
    float4 v = *(const float4*)(p + i*4);
    s  += v.x+v.y+v.z+v.w;
    s2 += v.x*v.x+v.y*v.y+v.z*v.z+v.w*v.w;
  }
  __shared__ float ls[256], ls2[256];
  ls[threadIdx.x]=s; ls2[threadIdx.x]=s2; __syncthreads();
  for(int st=128;st>0;st>>=1){
    if(threadIdx.x<st){ ls[threadIdx.x]+=ls[threadIdx.x+st]; ls2[threadIdx.x]+=ls2[threadIdx.x+st]; }
    __syncthreads();
  }
  if(threadIdx.x==0) part[blk]=make_float2(ls[0],ls2[0]);
}
__global__ __launch_bounds__(64) void ln_fin(const float2* __restrict__ part,
                                             float* __restrict__ mu, float* __restrict__ rstd){
  int b = blockIdx.x;
  float2 v = part[b*64+threadIdx.x];
  __shared__ double ds_[64], ds2_[64];
  ds_[threadIdx.x]=v.x; ds2_[threadIdx.x]=v.y; __syncthreads();
  for(int st=32;st>0;st>>=1){
    if(threadIdx.x<st){ ds_[threadIdx.x]+=ds_[threadIdx.x+st]; ds2_[threadIdx.x]+=ds2_[threadIdx.x+st]; }
    __syncthreads();
  }
  if(threadIdx.x==0){
    double m = ds_[0]*(1.0/262144.0);
    double var = ds2_[0]*(1.0/262144.0) - m*m;
    mu[b]=(float)m; rstd[b]=(float)(1.0/sqrt(var+1e-5));
  }
}

// ---------------- LN1 apply + inproj (64->128) + split, silu on fo2 ----------------
__global__ __launch_bounds__(256) void ln1_inproj(const float* __restrict__ x,
    const float* __restrict__ n1w, const float* __restrict__ n1b,
    const float* __restrict__ ipw, const float* __restrict__ ipb,
    const float* __restrict__ mu, const float* __restrict__ rstd,
    float* __restrict__ fo1_raw, float* __restrict__ fo2s){
  int bh = blockIdx.x; int b = bh>>6, h = bh&63;
  __shared__ float xn[64][64];
  __shared__ float wl[128*64];
  float m = mu[b], rs = rstd[b];
  for(int i=threadIdx.x;i<4096;i+=256){
    int c=i>>6, w=i&63;
    size_t sp=(size_t)c*4096 + h*64 + w;
    float v = x[(size_t)b*262144 + sp];
    xn[c][w] = (v-m)*rs*n1w[sp] + n1b[sp];
  }
  for(int i=threadIdx.x;i<8192;i+=256) wl[i]=ipw[i];
  __syncthreads();
  int px = threadIdx.x & 63, ob = (threadIdx.x>>6)*32;
  float acc[32];
  #pragma unroll
  for(int j=0;j<32;j++) acc[j]=0.f;
  for(int c=0;c<64;c++){
    float xv = xn[c][px];
    #pragma unroll
    for(int j=0;j<32;j++) acc[j] = fmaf(wl[(ob+j)*64+c], xv, acc[j]);
  }
  for(int j=0;j<32;j++){
    int o = ob+j;
    float v = acc[j] + ipb[o];
    if(o<64) fo1_raw[((size_t)(b*64+o))*4096 + h*64 + px] = v;
    else     fo2s  [((size_t)(b*64+o-64))*4096 + h*64 + px] = silu_f(v);
  }
}

// ---------------- depthwise 3x3 + silu, writes normal + transposed spatial ----------------
__global__ __launch_bounds__(256) void dwconv_silu_tr(const float* __restrict__ src_,
    const float* __restrict__ dww, const float* __restrict__ dwb,
    float* __restrict__ fo1s, float* __restrict__ fo1t){
  int bc = blockIdx.x; int c = bc & 63;
  const float* src = src_ + (size_t)bc*4096;
  float wk[9];
  #pragma unroll
  for(int k=0;k<9;k++) wk[k]=dww[c*9+k];
  float bias = dwb[c];
  __shared__ float tl[64][65];
  for(int i=threadIdx.x;i<4096;i+=256){
    int h=i>>6, w=i&63;
    float acc=bias;
    #pragma unroll
    for(int kh=0;kh<3;kh++){
      int ih=h+kh-1; if(ih<0||ih>63) continue;
      #pragma unroll
      for(int kw=0;kw<3;kw++){
        int iw=w+kw-1; if(iw<0||iw>63) continue;
        acc += wk[kh*3+kw]*src[ih*64+iw];
      }
    }
    tl[h][w] = silu_f(acc);
  }
  __syncthreads();
  float* ps = fo1s + (size_t)bc*4096;
  float* pt = fo1t + (size_t)bc*4096;
  for(int i=threadIdx.x;i<4096;i+=256){
    ps[i] = tl[i>>6][i&63];
    pt[i] = tl[i&63][i>>6];
  }
}

// ---------------- weight preps ----------------
__global__ __launch_bounds__(256) void cvt_w_bf(const float* __restrict__ w, uint* __restrict__ wb){
  int i = blockIdx.x*256 + threadIdx.x;   // 131072 pairs
  float2 v = *(const float2*)(w + 2*i);
  wb[i] = f2bf2(v.x, v.y);
}
__global__ __launch_bounds__(256) void wdt_make(const float* __restrict__ dtw,
    const float* __restrict__ xpw, ushort* __restrict__ wcomb){
  int d = blockIdx.x;
  float wr[16];
  #pragma unroll
  for(int r=0;r<16;r++) wr[r]=dtw[d*16+r];
  for(int k=threadIdx.x;k<512;k+=256){
    float acc=0.f;
    #pragma unroll
    for(int r=0;r<16;r++) acc = fmaf(wr[r], xpw[r*512+k], acc);
    wcomb[(size_t)d*512+k]=f2bf(acc);
  }
}
__global__ __launch_bounds__(256) void cvt_bc_pad(const float* __restrict__ xpw, ushort* __restrict__ wcomb){
  int i = blockIdx.x*256 + threadIdx.x;   // 32768
  int row = i>>9, k = i&511;
  float v = (row<32) ? xpw[8192 + row*512 + k] : 0.f;
  wcomb[(size_t)(512+row)*512 + k] = f2bf(v);
}
__global__ __launch_bounds__(256) void fold_w_bf(const float* __restrict__ ow, ushort* __restrict__ wf){
  int i = blockIdx.x*256 + threadIdx.x;   // 32768
  int c = i>>9, d2 = i&511;
  wf[i] = f2bf(ow[c*512+d2] + ow[(64+c)*512+d2] + ow[(128+c)*512+d2] + ow[(192+c)*512+d2]);
}

// ---------------- gather u transposed: (B, L=4096, 256) bf16 ----------------
__global__ __launch_bounds__(256) void gather_u_t(const float* __restrict__ fo1s,
    const float* __restrict__ fo1t, uint* __restrict__ u_bf){
  int blk = blockIdx.x;
  int lt = blk&63, part = (blk>>6)&3, b = blk>>8;
  int l0 = lt<<6;
  const float* s = (part<2)? fo1s : fo1t;
  bool rev = part&1;
  __shared__ float tl[64][65];
  for(int i=threadIdx.x;i<4096;i+=256){
    int c=i>>6, j=i&63;
    int l = l0 + j;
    int idx = rev ? (4095-l) : l;
    tl[c][j] = s[((size_t)(b*64+c))*4096 + idx];
  }
  __syncthreads();
  for(int i=threadIdx.x;i<2048;i+=256){
    int j = i>>5, cp = i&31;
    int l = l0 + j;
    u_bf[((size_t)(b*4096)+l)*128 + part*32 + cp] = f2bf2(tl[2*cp][j], tl[2*cp+1][j]);
  }
}

// ---------------- MFMA GEMM: xz = W(1024,256) x U^T ----------------
__global__ __launch_bounds__(256) void gemm_xz_mfma(const ushort* __restrict__ u_bf,
    const ushort* __restrict__ w_bf, float* __restrict__ xi0, ushort* __restrict__ z_bf){
  int blk = blockIdx.x; int b = blk>>5; int l0 = (blk&31)<<7;
  int o0 = blockIdx.y<<7;
  __shared__ __align__(16) ushort Al[2][5120];
  __shared__ __align__(16) ushort Bl[2][5120];
  int t = threadIdx.x, lane = t&63, wid = t>>6;
  int wr = wid>>1, wc = wid&1;
  int rl = lane&15, kseg = (lane>>4)*8;
  f4_t acc[4][4];
  #pragma unroll
  for(int m=0;m<4;m++)
    #pragma unroll
    for(int n=0;n<4;n++) acc[m][n]=(f4_t){0.f,0.f,0.f,0.f};

  int r0 = t>>2, r1 = 64+(t>>2), seg = t&3;
  uint4 rA0,rA1,rB0,rB1;
  auto issue=[&](int kc){
    rA0 = *(const uint4*)&w_bf[(size_t)(o0+r0)*256 + kc*32 + seg*8];
    rA1 = *(const uint4*)&w_bf[(size_t)(o0+r1)*256 + kc*32 + seg*8];
    rB0 = *(const uint4*)&u_bf[((size_t)(b*4096)+l0+r0)*256 + kc*32 + seg*8];
    rB1 = *(const uint4*)&u_bf[((size_t)(b*4096)+l0+r1)*256 + kc*32 + seg*8];
  };
  auto store=[&](int buf){
    *(uint4*)&Al[buf][r0*40 + seg*8] = rA0;
    *(uint4*)&Al[buf][r1*40 + seg*8] = rA1;
    *(uint4*)&Bl[buf][r0*40 + seg*8] = rB0;
    *(uint4*)&Bl[buf][r1*40 + seg*8] = rB1;
  };
  issue(0); store(0); __syncthreads();
  int buf=0;
  for(int kc=0;kc<8;kc++){
    bool more = kc<7;
    if(more) issue(kc+1);
    bf8_t af[4], bfr[4];
    #pragma unroll
    for(int m=0;m<4;m++) af[m] = *(const bf8_t*)&Al[buf][(wr*64+m*16+rl)*40 + kseg];
    #pragma unroll
    for(int n=0;n<4;n++) bfr[n] = *(const bf8_t*)&Bl[buf][(wc*64+n*16+rl)*40 + kseg];
    #pragma unroll
    for(int m=0;m<4;m++)
      #pragma unroll
      for(int n=0;n<4;n++)
        acc[m][n] = __builtin_amdgcn_mfma_f32_16x16x32_bf16(af[m], bfr[n], acc[m][n], 0,0,0);
    __syncthreads();
    if(more){ store(buf^1); __syncthreads(); }
    buf^=1;
  }
  int orow = (lane>>4)*4;
  if(o0 < 512){
    #pragma unroll
    for(int m=0;m<4;m++)
      #pragma unroll
      for(int n=0;n<4;n++){
        int l = l0 + wc*64 + n*16 + rl;
        #pragma unroll
        for(int r=0;r<4;r++){
          int o = o0 + wr*64 + m*16 + orow + r;
          xi0[((size_t)(b*512)+o)*4096 + l] = acc[m][n][r];
        }
      }
  } else {
    #pragma unroll
    for(int m=0;m<4;m++)
      #pragma unroll
      for(int n=0;n<4;n++){
        int l = l0 + wc*64 + n*16 + rl;
        int gz = (o0 - 512 + wr*64 + m*16) >> 4;
        uint2 pkz;
        pkz.x = f2bf2(acc[m][n][0], acc[m][n][1]);
        pkz.y = f2bf2(acc[m][n][2], acc[m][n][3]);
        *(uint2*)&z_bf[(((size_t)(b*32)+gz)*4096 + l)*16 + orow] = pkz;
      }
  }
}

// ---------------- conv1d (k=4 causal) + silu: xi bf16 c-major + bf16 l-major ----------------
__global__ __launch_bounds__(256) void conv1d_silu2(const float* __restrict__ xi0,
    const float* __restrict__ cw, const float* __restrict__ cb,
    ushort* __restrict__ xi_c, ushort* __restrict__ xi_l){
  int blk = blockIdx.x;          // 2048: lt(64) | dt8(8) | b(4)
  int lt = blk&63, dt8 = (blk>>6)&7, b = blk>>9;
  int d0 = dt8*64, l0 = lt*64;
  __shared__ float T[64][65];
  int t = threadIdx.x, lloc = t&63, dq = t>>6;
  #pragma unroll 4
  for(int i=0;i<16;i++){
    int dloc = dq + i*4;
    int d = d0 + dloc;
    int l = l0 + lloc;
    size_t rowb = ((size_t)(b*512)+d)*4096;
    float acc = cb[d];
    #pragma unroll
    for(int k=0;k<4;k++){
      int ls = l-3+k;
      if(ls>=0) acc += cw[d*4+k]*xi0[rowb+ls];
    }
    acc = silu_f(acc);
    xi_c[rowb + l] = f2bf(acc);
    T[lloc][dloc] = acc;
  }
  __syncthreads();
  int dl = t&63;
  #pragma unroll 4
  for(int i=0;i<16;i++){
    int lloc2 = dq + i*4;
    xi_l[((size_t)(b*4096)+l0+lloc2)*512 + d0 + dl] = f2bf(T[lloc2][dl]);
  }
}

// ---------------- merged MFMA GEMM: [dt(512); bc(32)] = Wcomb(576,512) x xi^T ----------------
__global__ __launch_bounds__(256) void gemm_proj_mfma(const ushort* __restrict__ xi_bf,
    const ushort* __restrict__ wcomb, const float* __restrict__ dtb,
    ushort* __restrict__ dt_bf, ushort* __restrict__ bc_out){
  int blk = blockIdx.x; int b = blk>>6; int l0 = (blk&63)<<6;
  int o0 = blockIdx.y<<6;
  __shared__ __align__(16) ushort Al[2][2560];
  __shared__ __align__(16) ushort Bl[2][2560];
  int t = threadIdx.x, lane = t&63, wid = t>>6;
  int wo = wid>>1, wl = wid&1;
  int rl = lane&15, kseg = (lane>>4)*8;
  f4_t acc[2][2];
  #pragma unroll
  for(int m=0;m<2;m++)
    #pragma unroll
    for(int n=0;n<2;n++) acc[m][n]=(f4_t){0.f,0.f,0.f,0.f};
  int r = t>>2, seg = t&3;
  uint4 rA,rB;
  auto issue=[&](int kc){
    rA = *(const uint4*)&wcomb[(size_t)(o0+r)*512 + kc*32 + seg*8];
    rB = *(const uint4*)&xi_bf[((size_t)(b*4096)+l0+r)*512 + kc*32 + seg*8];
  };
  auto store=[&](int buf){
    *(uint4*)&Al[buf][r*40 + seg*8] = rA;
    *(uint4*)&Bl[buf][r*40 + seg*8] = rB;
  };
  issue(0); store(0); __syncthreads();
  int buf=0;
  for(int kc=0;kc<16;kc++){
    bool more = kc<15;
    if(more) issue(kc+1);
    bf8_t af[2], bfr[2];
    #pragma unroll
    for(int m=0;m<2;m++) af[m] = *(const bf8_t*)&Al[buf][(wo*32+m*16+rl)*40 + kseg];
    #pragma unroll
    for(int n=0;n<2;n++) bfr[n] = *(const bf8_t*)&Bl[buf][(wl*32+n*16+rl)*40 + kseg];
    #pragma unroll
    for(int m=0;m<2;m++)
      #pragma unroll
      for(int n=0;n<2;n++)
        acc[m][n] = __builtin_amdgcn_mfma_f32_16x16x32_bf16(af[m], bfr[n], acc[m][n], 0,0,0);
    __syncthreads();
    if(more){ store(buf^1); __syncthreads(); }
    buf^=1;
  }
  int orow = (lane>>4)*4;
  #pragma unroll
  for(int m=0;m<2;m++)
    #pragma unroll
    for(int n=0;n<2;n++){
      int l = l0 + wl*32 + n*16 + rl;
      #pragma unroll
      for(int rr=0;rr<4;rr++){
        int o = o0 + wo*32 + m*16 + orow + rr;
        float v = acc[m][n][rr];
        if(o<512){
          v += dtb[o];
          float sp = (v>20.f)? v : 0.69314718056f*__log2f(1.f+exp2f(1.44269504089f*v));
          dt_bf[((size_t)(b*512)+o)*4096 + l] = f2bf(sp);
        } else if(o<544){
          bc_out[((size_t)(b*4096)+l)*32 + (o-512)] = f2bf(v);
        }
      }
    }
}

// ================= scan v3: 32 chunks of 128; wave = 16 ch x 4 states =================
// dt/xi bf16 c-major; B/C bf16 global but f32 in LDS (converted at staging).
__global__ __launch_bounds__(64) void scan3_p1(
    const ushort* __restrict__ dtx, const ushort* __restrict__ xix,
    const ushort* __restrict__ bc, const float* __restrict__ Alog,
    float4* __restrict__ Pbuf, float4* __restrict__ qbuf){
  int blk=blockIdx.x;
  int c=blk&31, g=(blk>>5)&31, b=blk>>10;
  int lane=threadIdx.x, ch=lane>>2, sq=lane&3;
  int d=g*16+ch;
  float4 Ar = *(const float4*)(Alog + d*16 + sq*4);
  float A2[4];
  A2[0]=-__expf(Ar.x)*1.44269504088896f;
  A2[1]=-__expf(Ar.y)*1.44269504088896f;
  A2[2]=-__expf(Ar.z)*1.44269504088896f;
  A2[3]=-__expf(Ar.w)*1.44269504088896f;
  __shared__ __align__(16) uint  pk[2][16][36];
  __shared__ __align__(16) float bl[2][32][20];
  const int l0c = c*128;
  const size_t dtrow = ((size_t)(b*512)+d)*4096;
  const ushort* xb = bc + (size_t)b*4096*32;
  uint4 rdt, rxi; uint2 rb[2];
  auto issue=[&](int t){
    int l0 = l0c + t*32;
    rdt = *(const uint4*)(dtx + dtrow + l0 + sq*8);
    rxi = *(const uint4*)(xix + dtrow + l0 + sq*8);
    #pragma unroll
    for(int k=0;k<2;k++){
      int j=ch+k*16;
      rb[k]=*(const uint2*)(xb + (size_t)(l0+j)*32 + sq*4);
    }
  };
  auto store=[&](int buf){
    const uint* dp=(const uint*)&rdt; const uint* xp=(const uint*)&rxi;
    #pragma unroll
    for(int k=0;k<4;k++){
      uint ud=dp[k], ux=xp[k];
      uint2 w;
      w.x = (ud&0xffffu)|(ux<<16);
      w.y = (ud>>16)|(ux&0xffff0000u);
      *(uint2*)&pk[buf][ch][sq*8+2*k] = w;
    }
    #pragma unroll
    for(int k=0;k<2;k++){
      float4 bv = make_float4(bflo(rb[k].x), bfhi(rb[k].x), bflo(rb[k].y), bfhi(rb[k].y));
      *(float4*)&bl[buf][ch+k*16][sq*4] = bv;
    }
  };
  float P[4]={1.f,1.f,1.f,1.f}, q[4]={0.f,0.f,0.f,0.f};
  issue(0); store(0);
  for(int t=0;t<4;t++){
    int buf=t&1;
    if(t<3) issue(t+1);
    #pragma unroll 4
    for(int jp=0;jp<16;jp++){
      uint2 pp = *(const uint2*)&pk[buf][ch][jp*2];
      float4 B0 = *(const float4*)&bl[buf][2*jp][sq*4];
      float4 B1 = *(const float4*)&bl[buf][2*jp+1][sq*4];
      {
        float dtv=bflo(pp.x), xiv=bfhi(pp.x);
        float u=dtv*xiv;
        float Bv[4]={B0.x,B0.y,B0.z,B0.w};
        #pragma unroll
        for(int i=0;i<4;i++){ float dA=exp2f(dtv*A2[i]); P[i]*=dA; q[i]=fmaf(dA,q[i],u*Bv[i]); }
      }
      {
        float dtv=bflo(pp.y), xiv=bfhi(pp.y);
        float u=dtv*xiv;
        float Bv[4]={B1.x,B1.y,B1.z,B1.w};
        #pragma unroll
        for(int i=0;i<4;i++){ float dA=exp2f(dtv*A2[i]); P[i]*=dA; q[i]=fmaf(dA,q[i],u*Bv[i]); }
      }
    }
    if(t<3) store(buf^1);
  }
  int idx = blk*64 + lane;
  Pbuf[idx]=make_float4(P[0],P[1],P[2],P[3]);
  qbuf[idx]=make_float4(q[0],q[1],q[2],q[3]);
}

__global__ __launch_bounds__(256) void scan3_mid(const float4* __restrict__ Pbuf,
    const float4* __restrict__ qbuf, float4* __restrict__ hstart){
  int tid = blockIdx.x*256+threadIdx.x;  // 8192
  int lane = tid&63, sg = tid>>6;
  float4 h = make_float4(0.f,0.f,0.f,0.f);
  #pragma unroll
  for(int c=0;c<32;c++){
    int idx = (sg*32+c)*64 + lane;
    hstart[idx]=h;
    float4 P=Pbuf[idx], q=qbuf[idx];
    h.x = fmaf(P.x,h.x,q.x);
    h.y = fmaf(P.y,h.y,q.y);
    h.z = fmaf(P.z,h.z,q.z);
    h.w = fmaf(P.w,h.w,q.w);
  }
}

__global__ __launch_bounds__(64) void scan3_p2(
    const ushort* __restrict__ dtx, const ushort* __restrict__ xix,
    const ushort* __restrict__ z_bf, const ushort* __restrict__ bc,
    const float* __restrict__ Alog, const float* __restrict__ Dp,
    const float4* __restrict__ hstart, ushort* __restrict__ y_bf){
  int blk=blockIdx.x;
  int c=blk&31, g=(blk>>5)&31, b=blk>>10;
  int lane=threadIdx.x, ch=lane>>2, sq=lane&3;
  int d=g*16+ch;
  float4 Ar = *(const float4*)(Alog + d*16 + sq*4);
  float A2[4];
  A2[0]=-__expf(Ar.x)*1.44269504088896f;
  A2[1]=-__expf(Ar.y)*1.44269504088896f;
  A2[2]=-__expf(Ar.z)*1.44269504088896f;
  A2[3]=-__expf(Ar.w)*1.44269504088896f;
  float Dv = Dp[d];
  int je = lane>>1, halfe = lane&1;
  __shared__ __align__(16) uint  pk[2][16][36];
  __shared__ __align__(16) float bcl[2][32][36];
  __shared__ __align__(16) float pl[32][18];
  const int l0c = c*128;
  const size_t dtrow = ((size_t)(b*512)+d)*4096;
  const ushort* xb = bc + (size_t)b*4096*32;
  const size_t zybase = (((size_t)(b*32)+g)*4096);
  uint4 rdt, rxi; uint2 rbc[4];
  uint4 rzb[2];
  auto issue=[&](int t){
    int l0 = l0c + t*32;
    rdt = *(const uint4*)(dtx + dtrow + l0 + sq*8);
    rxi = *(const uint4*)(xix + dtrow + l0 + sq*8);
    #pragma unroll
    for(int k=0;k<4;k++){
      int j=(lane>>3)+k*8, seg=lane&7;
      rbc[k]=*(const uint2*)(xb + (size_t)(l0+j)*32 + seg*4);
    }
    rzb[t&1] = *(const uint4*)&z_bf[(zybase + l0 + je)*16 + halfe*8];
  };
  auto store=[&](int buf){
    const uint* dp=(const uint*)&rdt; const uint* xp=(const uint*)&rxi;
    #pragma unroll
    for(int k=0;k<4;k++){
      uint ud=dp[k], ux=xp[k];
      uint2 w;
      w.x = (ud&0xffffu)|(ux<<16);
      w.y = (ud>>16)|(ux&0xffff0000u);
      *(uint2*)&pk[buf][ch][sq*8+2*k] = w;
    }
    #pragma unroll
    for(int k=0;k<4;k++){
      float4 v = make_float4(bflo(rbc[k].x), bfhi(rbc[k].x), bflo(rbc[k].y), bfhi(rbc[k].y));
      *(float4*)&bcl[buf][(lane>>3)+k*8][(lane&7)*4] = v;
    }
  };
  float h[4];
  {
    float4 h0 = hstart[blk*64 + lane];
    h[0]=h0.x; h[1]=h0.y; h[2]=h0.z; h[3]=h0.w;
  }
  issue(0); store(0);
  for(int t=0;t<4;t++){
    int buf=t&1;
    if(t<3) issue(t+1);
    #pragma unroll 4
    for(int jp=0;jp<16;jp++){
      uint2 pp = *(const uint2*)&pk[buf][ch][jp*2];
      {
        int j=2*jp;
        float4 B4 = *(const float4*)&bcl[buf][j][sq*4];
        float4 C4 = *(const float4*)&bcl[buf][j][16+sq*4];
        float dtv=bflo(pp.x), xiv=bfhi(pp.x);
        float u=dtv*xiv;
        float p;
        #pragma unroll
        for(int i=0;i<4;i++){ float dA=exp2f(dtv*A2[i]); h[i]=fmaf(dA,h[i],u*((const float*)&B4)[i]); }
        p = h[0]*C4.x; p=fmaf(h[1],C4.y,p); p=fmaf(h[2],C4.z,p); p=fmaf(h[3],C4.w,p);
        p = quad_sum4(p);
        if(sq==0) pl[j][ch] = p + xiv*Dv;
      }
      {
        int j=2*jp+1;
        float4 B4 = *(const float4*)&bcl[buf][j][sq*4];
        float4 C4 = *(const float4*)&bcl[buf][j][16+sq*4];
        float dtv=bflo(pp.y), xiv=bfhi(pp.y);
        float u=dtv*xiv;
        float p;
        #pragma unroll
        for(int i=0;i<4;i++){ float dA=exp2f(dtv*A2[i]); h[i]=fmaf(dA,h[i],u*((const float*)&B4)[i]); }
        p = h[0]*C4.x; p=fmaf(h[1],C4.y,p); p=fmaf(h[2],C4.z,p); p=fmaf(h[3],C4.w,p);
        p = quad_sum4(p);
        if(sq==0) pl[j][ch] = p + xiv*Dv;
      }
    }
    {
      int l = l0c + t*32 + je;
      uint4 zr = rzb[t&1];
      const ushort* zp = (const ushort*)&zr;
      float pv[8];
      #pragma unroll
      for(int k=0;k<4;k++){
        float2 v2 = *(const float2*)&pl[je][halfe*8+2*k];
        pv[2*k]=v2.x; pv[2*k+1]=v2.y;
      }
      float yv[8];
      #pragma unroll
      for(int k=0;k<8;k++) yv[k] = pv[k] * silu_f(bf2f(zp[k]));
      uint4 yo;
      uint* yp=(uint*)&yo;
      yp[0]=f2bf2(yv[0],yv[1]); yp[1]=f2bf2(yv[2],yv[3]);
      yp[2]=f2bf2(yv[4],yv[5]); yp[3]=f2bf2(yv[6],yv[7]);
      *(uint4*)&y_bf[((size_t)zybase + l)*16 + halfe*8] = yo;
    }
    if(t<3) store(buf^1);
  }
}

// ---------------- MFMA GEMM: res = (W'(64,512) x Y^T) * fo2s, out (B,64,L) c-major ----------------
__global__ __launch_bounds__(256) void gemm_res_mfma(const ushort* __restrict__ y_bf,
    const ushort* __restrict__ wf_bf, const float* __restrict__ fo2s, float* __restrict__ res){
  int blk = blockIdx.x; int b = blk>>5; int l0 = (blk&31)<<7;
  __shared__ __align__(16) ushort Wl[2][2560];
  __shared__ __align__(16) ushort Yl[2][5120];
  int t = threadIdx.x, lane = t&63, wid = t>>6;
  int rl = lane&15, kseg = (lane>>4)*8;
  f4_t acc[4][2];
  #pragma unroll
  for(int m=0;m<4;m++)
    #pragma unroll
    for(int n=0;n<2;n++) acc[m][n]=(f4_t){0.f,0.f,0.f,0.f};
  int ry = t>>1;
  int rw = t>>2, sgw = t&3;
  uint4 rY0, rY1, rW;
  auto issue=[&](int kc){
    int gg = 2*kc + (t&1);
    const ushort* yrow = &y_bf[(((size_t)(b*32)+gg)*4096 + l0+ry)*16];
    rY0 = *(const uint4*)&yrow[0];
    rY1 = *(const uint4*)&yrow[8];
    rW  = *(const uint4*)&wf_bf[(size_t)rw*512 + kc*32 + sgw*8];
  };
  auto store=[&](int buf){
    *(uint4*)&Yl[buf][ry*40 + (t&1)*16]     = rY0;
    *(uint4*)&Yl[buf][ry*40 + (t&1)*16 + 8] = rY1;
    *(uint4*)&Wl[buf][rw*40 + sgw*8]        = rW;
  };
  issue(0); store(0); __syncthreads();
  int buf=0;
  for(int kc=0;kc<16;kc++){
    bool more = kc<15;
    if(more) issue(kc+1);
    bf8_t aw[4], by[2];
    #pragma unroll
    for(int m=0;m<4;m++) aw[m] = *(const bf8_t*)&Wl[buf][(m*16+rl)*40 + kseg];
    #pragma unroll
    for(int n=0;n<2;n++) by[n] = *(const bf8_t*)&Yl[buf][(wid*32+n*16+rl)*40 + kseg];
    #pragma unroll
    for(int m=0;m<4;m++)
      #pragma unroll
      for(int n=0;n<2;n++)
        acc[m][n] = __builtin_amdgcn_mfma_f32_16x16x32_bf16(aw[m], by[n], acc[m][n], 0,0,0);
    __syncthreads();
    if(more){ store(buf^1); __syncthreads(); }
    buf^=1;
  }
  int orow = (lane>>4)*4;
  #pragma unroll
  for(int m=0;m<4;m++)
    #pragma unroll
    for(int n=0;n<2;n++){
      int l = l0 + wid*32 + n*16 + rl;
      #pragma unroll
      for(int r=0;r<4;r++){
        int o = m*16 + orow + r;
        size_t idx = ((size_t)(b*64+o))*4096 + l;
        res[idx] = acc[m][n][r]*fo2s[idx];
      }
    }
}

// ---------------- per (b,c) spatial mean ----------------
__global__ __launch_bounds__(256) void colmean(const float* __restrict__ res, float* __restrict__ fm){
  int bc = blockIdx.x;
  const float* p = res + (size_t)bc*4096;
  float s=0;
  for(int i=threadIdx.x;i<4096;i+=256) s+=p[i];
  __shared__ float ls[256];
  ls[threadIdx.x]=s; __syncthreads();
  for(int st=128;st>0;st>>=1){ if(threadIdx.x<st) ls[threadIdx.x]+=ls[threadIdx.x+st]; __syncthreads(); }
  if(threadIdx.x==0) fm[bc]=ls[0]*(1.f/4096.f);
}

// ---------------- tiny mamba2 over channel sequence ----------------
__global__ __launch_bounds__(64) void mamba2_kernel(const float* __restrict__ fm,
    const float* __restrict__ in_w, const float* __restrict__ cw, const float* __restrict__ cb,
    const float* __restrict__ xp, const float* __restrict__ dtw, const float* __restrict__ dtb,
    const float* __restrict__ Alog, const float* __restrict__ Dp, const float* __restrict__ ow,
    float* __restrict__ fsum){
  int b = blockIdx.x; int t = threadIdx.x;
  __shared__ float xi0m[64][4], xim[64][4], dtm[64][4], xbl[64][33], ym[64][4];
  float a0 = fm[b*64+t], a1 = fm[b*64 + 63-t];
  float zreg[4];
  #pragma unroll
  for(int d2=0;d2<4;d2++){
    xi0m[t][d2] = in_w[d2*2+0]*a0 + in_w[d2*2+1]*a1;
    zreg[d2]    = in_w[(4+d2)*2+0]*a0 + in_w[(4+d2)*2+1]*a1;
  }
  __syncthreads();
  float xir[4];
  #pragma unroll
  for(int d2=0;d2<4;d2++){
    float acc=cb[d2];
    #pragma unroll
    for(int k=0;k<4;k++){
      int srow=t-3+k;
      if(srow>=0) acc += cw[d2*4+k]*xi0m[srow][d2];
    }
    xir[d2]=silu_f(acc);
    xim[t][d2]=xir[d2];
  }
  for(int j=0;j<33;j++){
    float acc=0;
    #pragma unroll
    for(int d2=0;d2<4;d2++) acc += xp[j*4+d2]*xir[d2];
    xbl[t][j]=acc;
  }
  #pragma unroll
  for(int d2=0;d2<4;d2++){
    float v = xbl[t][0]*dtw[d2] + dtb[d2];
    dtm[t][d2] = (v>20.f)? v : log1pf(__expf(v));
  }
  __syncthreads();
  int dd=t>>4, s=t&15;
  float A2 = -__expf(Alog[dd*16+s]) * 1.44269504088896f;
  float h=0.f;
  for(int c=0;c<64;c++){
    float dtv=dtm[c][dd];
    float dA=exp2f(dtv*A2);
    h = fmaf(dA, h, dtv*xim[c][dd]*xbl[c][1+s]);
    float p = h*xbl[c][17+s];
    p += __shfl_xor(p,1,16);
    p += __shfl_xor(p,2,16);
    p += __shfl_xor(p,4,16);
    p += __shfl_xor(p,8,16);
    if(s==0) ym[c][dd]=p;
  }
  __syncthreads();
  float os=0.f;
  #pragma unroll
  for(int d2=0;d2<4;d2++){
    float yv = (ym[t][d2] + xim[t][d2]*Dp[d2]) * silu_f(zreg[d2]);
    os += yv * (ow[d2] + ow[4+d2]);
  }
  fsum[b*64+t]=os;
}

// ---------------- foss = res*(1+foc) ; x2 = outproj(foss) + x ----------------
__global__ __launch_bounds__(256) void outproj_kernel(const float* __restrict__ res,
    const float* __restrict__ fsum, const float* __restrict__ opw, const float* __restrict__ opb,
    const float* __restrict__ x, float* __restrict__ x2){
  int bh=blockIdx.x; int b=bh>>6,h=bh&63;
  __shared__ float tile[64][64];
  __shared__ float wl[4096];
  for(int i=threadIdx.x;i<4096;i+=256) wl[i]=opw[i];
  for(int i=threadIdx.x;i<4096;i+=256){
    int c=i>>6,w=i&63;
    tile[c][w]=res[((size_t)(b*64+c))*4096 + h*64 + w]*(1.f+fsum[b*64+c]);
  }
  __syncthreads();
  int px=threadIdx.x&63, og=threadIdx.x>>6;
  float acc[16];
  #pragma unroll
  for(int j=0;j<16;j++) acc[j]=0.f;
  for(int c=0;c<64;c++){
    float v=tile[c][px];
    #pragma unroll
    for(int j=0;j<16;j++) acc[j]=fmaf(wl[(og*16+j)*64+c],v,acc[j]);
  }
  for(int j=0;j<16;j++){
    int o=og*16+j;
    size_t idx=((size_t)(b*64+o))*4096 + h*64 + px;
    x2[idx]=acc[j]+opb[o]+x[idx];
  }
}

// ---------------- LN2 apply + ffn_in (64->256), grid (256,4), g bf16 ----------------
__global__ __launch_bounds__(256) void ffn_in_kernel(const float* __restrict__ x2,
    const float* __restrict__ n2w, const float* __restrict__ n2b,
    const float* __restrict__ fiw, const float* __restrict__ fib,
    const float* __restrict__ mu2, const float* __restrict__ rstd2,
    ushort* __restrict__ g){
  int bh=blockIdx.x; int b=bh>>6,h=bh&63;
  int oq=blockIdx.y;             // 0..3, 64 outputs each
  __shared__ float tile[64][64];
  __shared__ float wl[64*64];
  float m=mu2[b], rs=rstd2[b];
  for(int i=threadIdx.x;i<4096;i+=256){
    int c=i>>6,w=i&63;
    size_t sp=(size_t)c*4096 + h*64 + w;
    tile[c][w]=(x2[(size_t)b*262144+sp]-m)*rs*n2w[sp]+n2b[sp];
  }
  for(int i=threadIdx.x;i<4096;i+=256) wl[i]=fiw[(size_t)(oq*64)*64 + i];
  __syncthreads();
  int px=threadIdx.x&63, og=threadIdx.x>>6;
  float acc[16];
  #pragma unroll
  for(int j=0;j<16;j++) acc[j]=0.f;
  int ob = og*16;
  for(int c=0;c<64;c++){
    float v=tile[c][px];
    #pragma unroll
    for(int j=0;j<16;j++) acc[j]=fmaf(wl[(ob+j)*64+c],v,acc[j]);
  }
  for(int j=0;j<16;j++){
    int o = oq*64 + ob + j;
    g[((size_t)(b*256+o))*4096 + h*64 + px]=f2bf(acc[j]+fib[o]);
  }
}

// ---------------- ffn depthwise 3x3 + gelu-gate (bf16 in/out) ----------------
__global__ __launch_bounds__(256) void ffn_dw_gate(const ushort* __restrict__ g,
    const float* __restrict__ dww, const float* __restrict__ dwb, ushort* __restrict__ gm){
  int e = blockIdx.x*256 + threadIdx.x;   // 4*128*4096
  int sp = e & 4095, j = (e>>12)&127, b = e>>19;
  int h = sp>>6, w = sp&63;
  float v[2];
  #pragma unroll
  for(int half=0;half<2;half++){
    int ch = j + half*128;
    const ushort* gp = g + ((size_t)(b*256+ch))*4096;
    float acc = dwb[ch];
    #pragma unroll
    for(int kh=0;kh<3;kh++){
      int ih=h+kh-1; if(ih<0||ih>63) continue;
      #pragma unroll
      for(int kw=0;kw<3;kw++){
        int iw=w+kw-1; if(iw<0||iw>63) continue;
        acc += dww[ch*9+kh*3+kw]*bf2f(gp[ih*64+iw]);
      }
    }
    v[half]=acc;
  }
  float ge = 0.5f*v[0]*(1.f+erff(v[0]*0.70710678f));
  gm[((size_t)(b*128+j))*4096 + sp] = f2bf(ge*v[1]);
}

// ---------------- ffn_out (128->64) + bias + residual add -> d_out ----------------
__global__ __launch_bounds__(256) void ffn_out_kernel(const ushort* __restrict__ gm,
    const float* __restrict__ fow, const float* __restrict__ fob,
    const float* __restrict__ x2, float* __restrict__ out){
  int bh=blockIdx.x; int b=bh>>6,h=bh&63;
  __shared__ float tile[128][64];
  __shared__ float wl[64*128];
  for(int i=threadIdx.x;i<8192;i+=256){
    int c=i>>6,w=i&63;
    tile[c][w]=bf2f(gm[((size_t)(b*128+c))*4096 + h*64 + w]);
  }
  for(int i=threadIdx.x;i<8192;i+=256) wl[i]=fow[i];
  __syncthreads();
  int px=threadIdx.x&63, og=threadIdx.x>>6;
  float acc[16];
  #pragma unroll
  for(int j=0;j<16;j++) acc[j]=0.f;
  for(int c=0;c<128;c++){
    float v=tile[c][px];
    #pragma unroll
    for(int j=0;j<16;j++) acc[j]=fmaf(wl[(og*16+j)*128+c],v,acc[j]);
  }
  for(int j=0;j<16;j++){
    int o=og*16+j;
    size_t idx=((size_t)(b*64+o))*4096 + h*64 + px;
    out[idx]=acc[j]+fob[o]+x2[idx];
  }
}

extern "C" void kernel_launch(void* const* d_in, const int* in_sizes, int n_in,
                              void* d_out, int out_size, void* d_ws, size_t ws_size,
                              hipStream_t stream){
  const float* x      = (const float*)d_in[0];
  const float* n1w    = (const float*)d_in[1];
  const float* n1b    = (const float*)d_in[2];
  const float* n2w    = (const float*)d_in[3];
  const float* n2b    = (const float*)d_in[4];
  const float* ipw    = (const float*)d_in[5];
  const float* ipb    = (const float*)d_in[6];
  const float* dww    = (const float*)d_in[7];
  const float* dwb    = (const float*)d_in[8];
  const float* opw    = (const float*)d_in[9];
  const float* opb    = (const float*)d_in[10];
  const float* m1_inw = (const float*)d_in[11];
  const float* m1_cw  = (const float*)d_in[12];
  const float* m1_cb  = (const float*)d_in[13];
  const float* m1_xp  = (const float*)d_in[14];
  const float* m1_dtw = (const float*)d_in[15];
  const float* m1_dtb = (const float*)d_in[16];
  const float* m1_Al  = (const float*)d_in[17];
  const float* m1_D   = (const float*)d_in[18];
  const float* m1_ow  = (const float*)d_in[19];
  const float* m2_inw = (const float*)d_in[20];
  const float* m2_cw  = (const float*)d_in[21];
  const float* m2_cb  = (const float*)d_in[22];
  const float* m2_xp  = (const float*)d_in[23];
  const float* m2_dtw = (const float*)d_in[24];
  const float* m2_dtb = (const float*)d_in[25];
  const float* m2_Al  = (const float*)d_in[26];
  const float* m2_D   = (const float*)d_in[27];
  const float* m2_ow  = (const float*)d_in[28];
  const float* fiw    = (const float*)d_in[29];
  const float* fib    = (const float*)d_in[30];
  const float* fdw    = (const float*)d_in[31];
  const float* fdb    = (const float*)d_in[32];
  const float* fow    = (const float*)d_in[33];
  const float* fob    = (const float*)d_in[34];
  float* out = (float*)d_out;
  float* ws  = (float*)d_ws;

  const size_t M1 = 1048576;
  float* mu1   = ws + 0;  float* rstd1 = ws + 4;
  float* mu2   = ws + 8;  float* rstd2 = ws + 12;
  float* fmean = ws + 64;
  float* fsum  = ws + 320;
  float* lnpart= ws + 33792;
  float* base0 = ws + 36864;
  float* fo1raw= base0;                 // 1M [-> hstart -> res]
  float* fo2s  = base0 + M1;            // 1M
  float* fo1s  = base0 + 2*M1;          // 1M [-> Pbuf]
  float* fo1t  = base0 + 3*M1;          // 1M [-> qbuf]
  float* big0  = base0 + 4*M1;          // 8M: u_bf -> dt_bf(4M) -> g_bf(2M)
  float* big1  = base0 + 12*M1;         // 8M: xi0 -> y_bf(4M) + gm_bf(1M @ +4M)
  float* big2  = base0 + 20*M1;         // 8M: z_bf(4M) + xi_l(4M @ +4M)
  float* big3  = base0 + 28*M1;         // 8M: xi_c bf16 c-major (4M used)
  float* bcslot= base0 + 36*M1;         // 512K floats slot: bc_bf (256K used)
  float* x2    = base0 + 36*M1 + 524288;// 1M
  float* tail  = x2 + M1;
  ushort* w_bf    = (ushort*)tail;                    // 1024x256 bf16 (512KB)
  ushort* wcomb   = (ushort*)(tail + 131072);         // 576x512 bf16 (576KB)
  ushort* wf_bf   = (ushort*)(tail + 131072 + 147456);// 64x512 bf16 (64KB)

  uint*   u_bf  = (uint*)big0;
  ushort* dt_bf = (ushort*)big0;
  ushort* g_bf  = (ushort*)big0;
  float*  xi0   = big1;
  ushort* y_bf  = (ushort*)big1;
  ushort* gm_bf = (ushort*)(big1 + 4*M1);
  ushort* z_bf  = (ushort*)big2;
  ushort* xi_l  = (ushort*)(big2 + 4*M1);
  ushort* xi_c  = (ushort*)big3;
  ushort* bc_bf = (ushort*)bcslot;
  float*  Pbuf  = fo1s;
  float*  qbuf  = fo1t;
  float*  hstart= fo1raw;
  float*  res   = fo1raw;

  hipLaunchKernelGGL(ln_part, dim3(256), dim3(256), 0, stream, x, (float2*)lnpart);
  hipLaunchKernelGGL(ln_fin, dim3(4), dim3(64), 0, stream, (const float2*)lnpart, mu1, rstd1);
  hipLaunchKernelGGL(cvt_w_bf, dim3(512), dim3(256), 0, stream, m1_inw, (uint*)w_bf);
  hipLaunchKernelGGL(wdt_make, dim3(512), dim3(256), 0, stream, m1_dtw, m1_xp, wcomb);
  hipLaunchKernelGGL(cvt_bc_pad, dim3(128), dim3(256), 0, stream, m1_xp, wcomb);
  hipLaunchKernelGGL(fold_w_bf, dim3(128), dim3(256), 0, stream, m1_ow, wf_bf);
  hipLaunchKernelGGL(ln1_inproj, dim3(256), dim3(256), 0, stream,
                     x, n1w, n1b, ipw, ipb, mu1, rstd1, fo1raw, fo2s);
  hipLaunchKernelGGL(dwconv_silu_tr, dim3(256), dim3(256), 0, stream,
                     fo1raw, dww, dwb, fo1s, fo1t);
  hipLaunchKernelGGL(gather_u_t, dim3(1024), dim3(256), 0, stream, fo1s, fo1t, u_bf);
  hipLaunchKernelGGL(gemm_xz_mfma, dim3(128, 8), dim3(256), 0, stream,
                     (const ushort*)u_bf, w_bf, xi0, z_bf);
  hipLaunchKernelGGL(conv1d_silu2, dim3(2048), dim3(256), 0, stream,
                     xi0, m1_cw, m1_cb, xi_c, xi_l);
  hipLaunchKernelGGL(gemm_proj_mfma, dim3(256, 9), dim3(256), 0, stream,
                     xi_l, wcomb, m1_dtb, dt_bf, bc_bf);
  hipLaunchKernelGGL(scan3_p1, dim3(4096), dim3(64), 0, stream,
                     dt_bf, xi_c, bc_bf, m1_Al, (float4*)Pbuf, (float4*)qbuf);
  hipLaunchKernelGGL(scan3_mid, dim3(32), dim3(256), 0, stream,
                     (const float4*)Pbuf, (const float4*)qbuf, (float4*)hstart);
  hipLaunchKernelGGL(scan3_p2, dim3(4096), dim3(64), 0, stream,
                     dt_bf, xi_c, z_bf, bc_bf, m1_Al, m1_D, (const float4*)hstart, y_bf);
  hipLaunchKernelGGL(gemm_res_mfma, dim3(128), dim3(256), 0, stream,
                     y_bf, wf_bf, fo2s, res);
  hipLaunchKernelGGL(colmean, dim3(256), dim3(256), 0, stream, res, fmean);
  hipLaunchKernelGGL(mamba2_kernel, dim3(4), dim3(64), 0, stream,
                     fmean, m2_inw, m2_cw, m2_cb, m2_xp, m2_dtw, m2_dtb, m2_Al, m2_D, m2_ow, fsum);
  hipLaunchKernelGGL(outproj_kernel, dim3(256), dim3(256), 0, stream,
                     res, fsum, opw, opb, x, x2);
  hipLaunchKernelGGL(ln_part, dim3(256), dim3(256), 0, stream, x2, (float2*)lnpart);
  hipLaunchKernelGGL(ln_fin, dim3(4), dim3(64), 0, stream, (const float2*)lnpart, mu2, rstd2);
  hipLaunchKernelGGL(ffn_in_kernel, dim3(256, 4), dim3(256), 0, stream,
                     x2, n2w, n2b, fiw, fib, mu2, rstd2, g_bf);
  hipLaunchKernelGGL(ffn_dw_gate, dim3(8192), dim3(256), 0, stream, g_bf, fdw, fdb, gm_bf);
  hipLaunchKernelGGL(ffn_out_kernel, dim3(256), dim3(256), 0, stream, gm_bf, fow, fob, x2, out);
}

// Round 11
// 380.611 us; speedup vs baseline: 1.0507x; 1.0132x over previous
//
#include <hip/hip_runtime.h>
#include <math.h>

// OSS / VMamba-style block. B=4, C=64, H=W=64, L=4096, d_inner=512, D_STATE=16.
// R3: gemm_xz MFMA. R4: scan v3. R5: dt/BC/res MFMA. R6: merged gemm_proj, blocked z/y.
// R7: dt/xi bf16. R8: D folded into pl, bf16 FFN chain. R9: B/C bf16 global, f32 LDS.
// R10: scan latency/occupancy fix — dt/xi via DPP quad-broadcast (no pk LDS),
// single-buffered LDS (p2 16.4->6.9KB = ~23 blk/CU, p1 -> 2.6KB).

#define DEV static __device__ __forceinline__

DEV float silu_f(float x){ return x / (1.f + __expf(-x)); }

DEV ushort f2bf(float f){
  uint u = __float_as_uint(f);
  uint r = (u + 0x7FFF + ((u>>16)&1)) >> 16;
  return (ushort)r;
}
DEV uint f2bf2(float lo, float hi){
  return (uint)f2bf(lo) | ((uint)f2bf(hi)<<16);
}
DEV float bf2f(ushort u){ return __uint_as_float(((uint)u)<<16); }
DEV float bflo(uint u){ return __uint_as_float(u<<16); }
DEV float bfhi(uint u){ return __uint_as_float(u&0xffff0000u); }

typedef __attribute__((ext_vector_type(8))) short bf8_t;
typedef __attribute__((ext_vector_type(4))) float f4_t;

DEV float quad_sum4(float v){
  v += __int_as_float(__builtin_amdgcn_update_dpp(0, __float_as_int(v), 0xB1, 0xF, 0xF, false));
  v += __int_as_float(__builtin_amdgcn_update_dpp(0, __float_as_int(v), 0x4E, 0xF, 0xF, false));
  return v;
}
// broadcast lane O of each DPP quad to all 4 lanes
template<int O> DEV uint qb(uint v){
  return (uint)__builtin_amdgcn_update_dpp(0, (int)v, O*0x55, 0xF, 0xF, false);
}

// ---------------- LayerNorm stats, two-stage ----------------
__global__ __launch_bounds__(256) void ln_part(const float* __restrict__ x,
                                               float2* __restrict__ part){
  int blk = blockIdx.x; int b = blk>>6, pc = blk&63;
  const float* p = x + (size_t)b*262144 + (size_t)pc*4096;
  float s=0.f, s2=0.f;
  #pragma unroll
  for(int it=0; it<4; ++it){
    int i = threadIdx.x + it*256;
    float4 v = *(const float4*)(p + i*4);
    s  += v.x+v.y+v.z+v.w;
    s2 += v.x*v.x+v.y*v.y+v.z*v.z+v.w*v.w;
  }
  __shared__ float ls[256], ls2[256];
  ls[threadIdx.x]=s; ls2[threadIdx.x]=s2; __syncthreads();
  for(int st=128;st>0;st>>=1){
    if(threadIdx.x<st){ ls[threadIdx.x]+=ls[threadIdx.x+st]; ls2[threadIdx.x]+=ls2[threadIdx.x+st]; }
    __syncthreads();
  }
  if(threadIdx.x==0) part[blk]=make_float2(ls[0],ls2[0]);
}
__global__ __launch_bounds__(64) void ln_fin(const float2* __restrict__ part,
                                             float* __restrict__ mu, float* __restrict__ rstd){
  int b = blockIdx.x;
  float2 v = part[b*64+threadIdx.x];
  __shared__ double ds_[64], ds2_[64];
  ds_[threadIdx.x]=v.x; ds2_[threadIdx.x]=v.y; __syncthreads();
  for(int st=32;st>0;st>>=1){
    if(threadIdx.x<st){ ds_[threadIdx.x]+=ds_[threadIdx.x+st]; ds2_[threadIdx.x]+=ds2_[threadIdx.x+st]; }
    __syncthreads();
  }
  if(threadIdx.x==0){
    double m = ds_[0]*(1.0/262144.0);
    double var = ds2_[0]*(1.0/262144.0) - m*m;
    mu[b]=(float)m; rstd[b]=(float)(1.0/sqrt(var+1e-5));
  }
}

// ---------------- LN1 apply + inproj (64->128) + split, silu on fo2 ----------------
__global__ __launch_bounds__(256) void ln1_inproj(const float* __restrict__ x,
    const float* __restrict__ n1w, const float* __restrict__ n1b,
    const float* __restrict__ ipw, const float* __restrict__ ipb,
    const float* __restrict__ mu, const float* __restrict__ rstd,
    float* __restrict__ fo1_raw, float* __restrict__ fo2s){
  int bh = blockIdx.x; int b = bh>>6, h = bh&63;
  __shared__ float xn[64][64];
  __shared__ float wl[128*64];
  float m = mu[b], rs = rstd[b];
  for(int i=threadIdx.x;i<4096;i+=256){
    int c=i>>6, w=i&63;
    size_t sp=(size_t)c*4096 + h*64 + w;
    float v = x[(size_t)b*262144 + sp];
    xn[c][w] = (v-m)*rs*n1w[sp] + n1b[sp];
  }
  for(int i=threadIdx.x;i<8192;i+=256) wl[i]=ipw[i];
  __syncthreads();
  int px = threadIdx.x & 63, ob = (threadIdx.x>>6)*32;
  float acc[32];
  #pragma unroll
  for(int j=0;j<32;j++) acc[j]=0.f;
  for(int c=0;c<64;c++){
    float xv = xn[c][px];
    #pragma unroll
    for(int j=0;j<32;j++) acc[j] = fmaf(wl[(ob+j)*64+c], xv, acc[j]);
  }
  for(int j=0;j<32;j++){
    int o = ob+j;
    float v = acc[j] + ipb[o];
    if(o<64) fo1_raw[((size_t)(b*64+o))*4096 + h*64 + px] = v;
    else     fo2s  [((size_t)(b*64+o-64))*4096 + h*64 + px] = silu_f(v);
  }
}

// ---------------- depthwise 3x3 + silu, writes normal + transposed spatial ----------------
__global__ __launch_bounds__(256) void dwconv_silu_tr(const float* __restrict__ src_,
    const float* __restrict__ dww, const float* __restrict__ dwb,
    float* __restrict__ fo1s, float* __restrict__ fo1t){
  int bc = blockIdx.x; int c = bc & 63;
  const float* src = src_ + (size_t)bc*4096;
  float wk[9];
  #pragma unroll
  for(int k=0;k<9;k++) wk[k]=dww[c*9+k];
  float bias = dwb[c];
  __shared__ float tl[64][65];
  for(int i=threadIdx.x;i<4096;i+=256){
    int h=i>>6, w=i&63;
    float acc=bias;
    #pragma unroll
    for(int kh=0;kh<3;kh++){
      int ih=h+kh-1; if(ih<0||ih>63) continue;
      #pragma unroll
      for(int kw=0;kw<3;kw++){
        int iw=w+kw-1; if(iw<0||iw>63) continue;
        acc += wk[kh*3+kw]*src[ih*64+iw];
      }
    }
    tl[h][w] = silu_f(acc);
  }
  __syncthreads();
  float* ps = fo1s + (size_t)bc*4096;
  float* pt = fo1t + (size_t)bc*4096;
  for(int i=threadIdx.x;i<4096;i+=256){
    ps[i] = tl[i>>6][i&63];
    pt[i] = tl[i&63][i>>6];
  }
}

// ---------------- weight preps ----------------
__global__ __launch_bounds__(256) void cvt_w_bf(const float* __restrict__ w, uint* __restrict__ wb){
  int i = blockIdx.x*256 + threadIdx.x;   // 131072 pairs
  float2 v = *(const float2*)(w + 2*i);
  wb[i] = f2bf2(v.x, v.y);
}
__global__ __launch_bounds__(256) void wdt_make(const float* __restrict__ dtw,
    const float* __restrict__ xpw, ushort* __restrict__ wcomb){
  int d = blockIdx.x;
  float wr[16];
  #pragma unroll
  for(int r=0;r<16;r++) wr[r]=dtw[d*16+r];
  for(int k=threadIdx.x;k<512;k+=256){
    float acc=0.f;
    #pragma unroll
    for(int r=0;r<16;r++) acc = fmaf(wr[r], xpw[r*512+k], acc);
    wcomb[(size_t)d*512+k]=f2bf(acc);
  }
}
__global__ __launch_bounds__(256) void cvt_bc_pad(const float* __restrict__ xpw, ushort* __restrict__ wcomb){
  int i = blockIdx.x*256 + threadIdx.x;   // 32768
  int row = i>>9, k = i&511;
  float v = (row<32) ? xpw[8192 + row*512 + k] : 0.f;
  wcomb[(size_t)(512+row)*512 + k] = f2bf(v);
}
__global__ __launch_bounds__(256) void fold_w_bf(const float* __restrict__ ow, ushort* __restrict__ wf){
  int i = blockIdx.x*256 + threadIdx.x;   // 32768
  int c = i>>9, d2 = i&511;
  wf[i] = f2bf(ow[c*512+d2] + ow[(64+c)*512+d2] + ow[(128+c)*512+d2] + ow[(192+c)*512+d2]);
}

// ---------------- gather u transposed: (B, L=4096, 256) bf16 ----------------
__global__ __launch_bounds__(256) void gather_u_t(const float* __restrict__ fo1s,
    const float* __restrict__ fo1t, uint* __restrict__ u_bf){
  int blk = blockIdx.x;
  int lt = blk&63, part = (blk>>6)&3, b = blk>>8;
  int l0 = lt<<6;
  const float* s = (part<2)? fo1s : fo1t;
  bool rev = part&1;
  __shared__ float tl[64][65];
  for(int i=threadIdx.x;i<4096;i+=256){
    int c=i>>6, j=i&63;
    int l = l0 + j;
    int idx = rev ? (4095-l) : l;
    tl[c][j] = s[((size_t)(b*64+c))*4096 + idx];
  }
  __syncthreads();
  for(int i=threadIdx.x;i<2048;i+=256){
    int j = i>>5, cp = i&31;
    int l = l0 + j;
    u_bf[((size_t)(b*4096)+l)*128 + part*32 + cp] = f2bf2(tl[2*cp][j], tl[2*cp+1][j]);
  }
}

// ---------------- MFMA GEMM: xz = W(1024,256) x U^T ----------------
__global__ __launch_bounds__(256) void gemm_xz_mfma(const ushort* __restrict__ u_bf,
    const ushort* __restrict__ w_bf, float* __restrict__ xi0, ushort* __restrict__ z_bf){
  int blk = blockIdx.x; int b = blk>>5; int l0 = (blk&31)<<7;
  int o0 = blockIdx.y<<7;
  __shared__ __align__(16) ushort Al[2][5120];
  __shared__ __align__(16) ushort Bl[2][5120];
  int t = threadIdx.x, lane = t&63, wid = t>>6;
  int wr = wid>>1, wc = wid&1;
  int rl = lane&15, kseg = (lane>>4)*8;
  f4_t acc[4][4];
  #pragma unroll
  for(int m=0;m<4;m++)
    #pragma unroll
    for(int n=0;n<4;n++) acc[m][n]=(f4_t){0.f,0.f,0.f,0.f};

  int r0 = t>>2, r1 = 64+(t>>2), seg = t&3;
  uint4 rA0,rA1,rB0,rB1;
  auto issue=[&](int kc){
    rA0 = *(const uint4*)&w_bf[(size_t)(o0+r0)*256 + kc*32 + seg*8];
    rA1 = *(const uint4*)&w_bf[(size_t)(o0+r1)*256 + kc*32 + seg*8];
    rB0 = *(const uint4*)&u_bf[((size_t)(b*4096)+l0+r0)*256 + kc*32 + seg*8];
    rB1 = *(const uint4*)&u_bf[((size_t)(b*4096)+l0+r1)*256 + kc*32 + seg*8];
  };
  auto store=[&](int buf){
    *(uint4*)&Al[buf][r0*40 + seg*8] = rA0;
    *(uint4*)&Al[buf][r1*40 + seg*8] = rA1;
    *(uint4*)&Bl[buf][r0*40 + seg*8] = rB0;
    *(uint4*)&Bl[buf][r1*40 + seg*8] = rB1;
  };
  issue(0); store(0); __syncthreads();
  int buf=0;
  for(int kc=0;kc<8;kc++){
    bool more = kc<7;
    if(more) issue(kc+1);
    bf8_t af[4], bfr[4];
    #pragma unroll
    for(int m=0;m<4;m++) af[m] = *(const bf8_t*)&Al[buf][(wr*64+m*16+rl)*40 + kseg];
    #pragma unroll
    for(int n=0;n<4;n++) bfr[n] = *(const bf8_t*)&Bl[buf][(wc*64+n*16+rl)*40 + kseg];
    #pragma unroll
    for(int m=0;m<4;m++)
      #pragma unroll
      for(int n=0;n<4;n++)
        acc[m][n] = __builtin_amdgcn_mfma_f32_16x16x32_bf16(af[m], bfr[n], acc[m][n], 0,0,0);
    __syncthreads();
    if(more){ store(buf^1); __syncthreads(); }
    buf^=1;
  }
  int orow = (lane>>4)*4;
  if(o0 < 512){
    #pragma unroll
    for(int m=0;m<4;m++)
      #pragma unroll
      for(int n=0;n<4;n++){
        int l = l0 + wc*64 + n*16 + rl;
        #pragma unroll
        for(int r=0;r<4;r++){
          int o = o0 + wr*64 + m*16 + orow + r;
          xi0[((size_t)(b*512)+o)*4096 + l] = acc[m][n][r];
        }
      }
  } else {
    #pragma unroll
    for(int m=0;m<4;m++)
      #pragma unroll
      for(int n=0;n<4;n++){
        int l = l0 + wc*64 + n*16 + rl;
        int gz = (o0 - 512 + wr*64 + m*16) >> 4;
        uint2 pkz;
        pkz.x = f2bf2(acc[m][n][0], acc[m][n][1]);
        pkz.y = f2bf2(acc[m][n][2], acc[m][n][3]);
        *(uint2*)&z_bf[(((size_t)(b*32)+gz)*4096 + l)*16 + orow] = pkz;
      }
  }
}

// ---------------- conv1d (k=4 causal) + silu: xi bf16 c-major + bf16 l-major ----------------
__global__ __launch_bounds__(256) void conv1d_silu2(const float* __restrict__ xi0,
    const float* __restrict__ cw, const float* __restrict__ cb,
    ushort* __restrict__ xi_c, ushort* __restrict__ xi_l){
  int blk = blockIdx.x;          // 2048: lt(64) | dt8(8) | b(4)
  int lt = blk&63, dt8 = (blk>>6)&7, b = blk>>9;
  int d0 = dt8*64, l0 = lt*64;
  __shared__ float T[64][65];
  int t = threadIdx.x, lloc = t&63, dq = t>>6;
  #pragma unroll 4
  for(int i=0;i<16;i++){
    int dloc = dq + i*4;
    int d = d0 + dloc;
    int l = l0 + lloc;
    size_t rowb = ((size_t)(b*512)+d)*4096;
    float acc = cb[d];
    #pragma unroll
    for(int k=0;k<4;k++){
      int ls = l-3+k;
      if(ls>=0) acc += cw[d*4+k]*xi0[rowb+ls];
    }
    acc = silu_f(acc);
    xi_c[rowb + l] = f2bf(acc);
    T[lloc][dloc] = acc;
  }
  __syncthreads();
  int dl = t&63;
  #pragma unroll 4
  for(int i=0;i<16;i++){
    int lloc2 = dq + i*4;
    xi_l[((size_t)(b*4096)+l0+lloc2)*512 + d0 + dl] = f2bf(T[lloc2][dl]);
  }
}

// ---------------- merged MFMA GEMM: [dt(512); bc(32)] = Wcomb(576,512) x xi^T ----------------
__global__ __launch_bounds__(256) void gemm_proj_mfma(const ushort* __restrict__ xi_bf,
    const ushort* __restrict__ wcomb, const float* __restrict__ dtb,
    ushort* __restrict__ dt_bf, ushort* __restrict__ bc_out){
  int blk = blockIdx.x; int b = blk>>6; int l0 = (blk&63)<<6;
  int o0 = blockIdx.y<<6;
  __shared__ __align__(16) ushort Al[2][2560];
  __shared__ __align__(16) ushort Bl[2][2560];
  int t = threadIdx.x, lane = t&63, wid = t>>6;
  int wo = wid>>1, wl = wid&1;
  int rl = lane&15, kseg = (lane>>4)*8;
  f4_t acc[2][2];
  #pragma unroll
  for(int m=0;m<2;m++)
    #pragma unroll
    for(int n=0;n<2;n++) acc[m][n]=(f4_t){0.f,0.f,0.f,0.f};
  int r = t>>2, seg = t&3;
  uint4 rA,rB;
  auto issue=[&](int kc){
    rA = *(const uint4*)&wcomb[(size_t)(o0+r)*512 + kc*32 + seg*8];
    rB = *(const uint4*)&xi_bf[((size_t)(b*4096)+l0+r)*512 + kc*32 + seg*8];
  };
  auto store=[&](int buf){
    *(uint4*)&Al[buf][r*40 + seg*8] = rA;
    *(uint4*)&Bl[buf][r*40 + seg*8] = rB;
  };
  issue(0); store(0); __syncthreads();
  int buf=0;
  for(int kc=0;kc<16;kc++){
    bool more = kc<15;
    if(more) issue(kc+1);
    bf8_t af[2], bfr[2];
    #pragma unroll
    for(int m=0;m<2;m++) af[m] = *(const bf8_t*)&Al[buf][(wo*32+m*16+rl)*40 + kseg];
    #pragma unroll
    for(int n=0;n<2;n++) bfr[n] = *(const bf8_t*)&Bl[buf][(wl*32+n*16+rl)*40 + kseg];
    #pragma unroll
    for(int m=0;m<2;m++)
      #pragma unroll
      for(int n=0;n<2;n++)
        acc[m][n] = __builtin_amdgcn_mfma_f32_16x16x32_bf16(af[m], bfr[n], acc[m][n], 0,0,0);
    __syncthreads();
    if(more){ store(buf^1); __syncthreads(); }
    buf^=1;
  }
  int orow = (lane>>4)*4;
  #pragma unroll
  for(int m=0;m<2;m++)
    #pragma unroll
    for(int n=0;n<2;n++){
      int l = l0 + wl*32 + n*16 + rl;
      #pragma unroll
      for(int rr=0;rr<4;rr++){
        int o = o0 + wo*32 + m*16 + orow + rr;
        float v = acc[m][n][rr];
        if(o<512){
          v += dtb[o];
          float sp = (v>20.f)? v : 0.69314718056f*__log2f(1.f+exp2f(1.44269504089f*v));
          dt_bf[((size_t)(b*512)+o)*4096 + l] = f2bf(sp);
        } else if(o<544){
          bc_out[((size_t)(b*4096)+l)*32 + (o-512)] = f2bf(v);
        }
      }
    }
}

// ================= scan v3: 32 chunks of 128; wave = 16 ch x 4 states =================
// dt/xi bf16 c-major distributed via DPP quad-broadcast (no LDS); B/C bf16 global,
// f32 in single-buffered LDS.
__global__ __launch_bounds__(64) void scan3_p1(
    const ushort* __restrict__ dtx, const ushort* __restrict__ xix,
    const ushort* __restrict__ bc, const float* __restrict__ Alog,
    float4* __restrict__ Pbuf, float4* __restrict__ qbuf){
  int blk=blockIdx.x;
  int c=blk&31, g=(blk>>5)&31, b=blk>>10;
  int lane=threadIdx.x, ch=lane>>2, sq=lane&3;
  int d=g*16+ch;
  float4 Ar = *(const float4*)(Alog + d*16 + sq*4);
  float A2[4];
  A2[0]=-__expf(Ar.x)*1.44269504088896f;
  A2[1]=-__expf(Ar.y)*1.44269504088896f;
  A2[2]=-__expf(Ar.z)*1.44269504088896f;
  A2[3]=-__expf(Ar.w)*1.44269504088896f;
  __shared__ __align__(16) float bl[32][20];
  const int l0c = c*128;
  const size_t dtrow = ((size_t)(b*512)+d)*4096;
  const ushort* xb = bc + (size_t)b*4096*32;
  uint4 rdt, rxi; uint2 rb[2];
  uint pkc[8];
  auto issue=[&](int t){
    int l0 = l0c + t*32;
    rdt = *(const uint4*)(dtx + dtrow + l0 + sq*8);
    rxi = *(const uint4*)(xix + dtrow + l0 + sq*8);
    #pragma unroll
    for(int k=0;k<2;k++){
      int j=ch+k*16;
      rb[k]=*(const uint2*)(xb + (size_t)(l0+j)*32 + sq*4);
    }
  };
  auto pack=[&](){
    const uint* dp=(const uint*)&rdt; const uint* xp=(const uint*)&rxi;
    #pragma unroll
    for(int k=0;k<4;k++){
      uint ud=dp[k], ux=xp[k];
      pkc[2*k]   = (ud&0xffffu)|(ux<<16);
      pkc[2*k+1] = (ud>>16)|(ux&0xffff0000u);
    }
  };
  auto storeB=[&](){
    #pragma unroll
    for(int k=0;k<2;k++){
      float4 bv = make_float4(bflo(rb[k].x), bfhi(rb[k].x), bflo(rb[k].y), bfhi(rb[k].y));
      *(float4*)&bl[ch+k*16][sq*4] = bv;
    }
  };
  float P[4]={1.f,1.f,1.f,1.f}, q[4]={0.f,0.f,0.f,0.f};
  auto step2=[&](uint p0, uint p1, int j0){
    float4 B0 = *(const float4*)&bl[j0][sq*4];
    float4 B1 = *(const float4*)&bl[j0+1][sq*4];
    {
      float dtv=bflo(p0), xiv=bfhi(p0); float u=dtv*xiv;
      #pragma unroll
      for(int i=0;i<4;i++){ float dA=exp2f(dtv*A2[i]); P[i]*=dA; q[i]=fmaf(dA,q[i],u*((const float*)&B0)[i]); }
    }
    {
      float dtv=bflo(p1), xiv=bfhi(p1); float u=dtv*xiv;
      #pragma unroll
      for(int i=0;i<4;i++){ float dA=exp2f(dtv*A2[i]); P[i]*=dA; q[i]=fmaf(dA,q[i],u*((const float*)&B1)[i]); }
    }
  };
  issue(0); pack(); storeB();
  for(int t=0;t<4;t++){
    if(t<3) issue(t+1);
    step2(qb<0>(pkc[0]),qb<0>(pkc[1]), 0);
    step2(qb<0>(pkc[2]),qb<0>(pkc[3]), 2);
    step2(qb<0>(pkc[4]),qb<0>(pkc[5]), 4);
    step2(qb<0>(pkc[6]),qb<0>(pkc[7]), 6);
    step2(qb<1>(pkc[0]),qb<1>(pkc[1]), 8);
    step2(qb<1>(pkc[2]),qb<1>(pkc[3]),10);
    step2(qb<1>(pkc[4]),qb<1>(pkc[5]),12);
    step2(qb<1>(pkc[6]),qb<1>(pkc[7]),14);
    step2(qb<2>(pkc[0]),qb<2>(pkc[1]),16);
    step2(qb<2>(pkc[2]),qb<2>(pkc[3]),18);
    step2(qb<2>(pkc[4]),qb<2>(pkc[5]),20);
    step2(qb<2>(pkc[6]),qb<2>(pkc[7]),22);
    step2(qb<3>(pkc[0]),qb<3>(pkc[1]),24);
    step2(qb<3>(pkc[2]),qb<3>(pkc[3]),26);
    step2(qb<3>(pkc[4]),qb<3>(pkc[5]),28);
    step2(qb<3>(pkc[6]),qb<3>(pkc[7]),30);
    if(t<3){ pack(); storeB(); }
  }
  int idx = blk*64 + lane;
  Pbuf[idx]=make_float4(P[0],P[1],P[2],P[3]);
  qbuf[idx]=make_float4(q[0],q[1],q[2],q[3]);
}

__global__ __launch_bounds__(256) void scan3_mid(const float4* __restrict__ Pbuf,
    const float4* __restrict__ qbuf, float4* __restrict__ hstart){
  int tid = blockIdx.x*256+threadIdx.x;  // 8192
  int lane = tid&63, sg = tid>>6;
  float4 h = make_float4(0.f,0.f,0.f,0.f);
  #pragma unroll
  for(int c=0;c<32;c++){
    int idx = (sg*32+c)*64 + lane;
    hstart[idx]=h;
    float4 P=Pbuf[idx], q=qbuf[idx];
    h.x = fmaf(P.x,h.x,q.x);
    h.y = fmaf(P.y,h.y,q.y);
    h.z = fmaf(P.z,h.z,q.z);
    h.w = fmaf(P.w,h.w,q.w);
  }
}

__global__ __launch_bounds__(64) void scan3_p2(
    const ushort* __restrict__ dtx, const ushort* __restrict__ xix,
    const ushort* __restrict__ z_bf, const ushort* __restrict__ bc,
    const float* __restrict__ Alog, const float* __restrict__ Dp,
    const float4* __restrict__ hstart, ushort* __restrict__ y_bf){
  int blk=blockIdx.x;
  int c=blk&31, g=(blk>>5)&31, b=blk>>10;
  int lane=threadIdx.x, ch=lane>>2, sq=lane&3;
  int d=g*16+ch;
  float4 Ar = *(const float4*)(Alog + d*16 + sq*4);
  float A2[4];
  A2[0]=-__expf(Ar.x)*1.44269504088896f;
  A2[1]=-__expf(Ar.y)*1.44269504088896f;
  A2[2]=-__expf(Ar.z)*1.44269504088896f;
  A2[3]=-__expf(Ar.w)*1.44269504088896f;
  float Dv = Dp[d];
  int je = lane>>1, halfe = lane&1;
  __shared__ __align__(16) float bcl[32][36];
  __shared__ __align__(16) float pl[32][18];
  const int l0c = c*128;
  const size_t dtrow = ((size_t)(b*512)+d)*4096;
  const ushort* xb = bc + (size_t)b*4096*32;
  const size_t zybase = (((size_t)(b*32)+g)*4096);
  uint4 rdt, rxi; uint2 rbc[4];
  uint4 rzb[2];
  uint pkc[8];
  auto issue=[&](int t){
    int l0 = l0c + t*32;
    rdt = *(const uint4*)(dtx + dtrow + l0 + sq*8);
    rxi = *(const uint4*)(xix + dtrow + l0 + sq*8);
    #pragma unroll
    for(int k=0;k<4;k++){
      int j=(lane>>3)+k*8, seg=lane&7;
      rbc[k]=*(const uint2*)(xb + (size_t)(l0+j)*32 + seg*4);
    }
    rzb[t&1] = *(const uint4*)&z_bf[(zybase + l0 + je)*16 + halfe*8];
  };
  auto pack=[&](){
    const uint* dp=(const uint*)&rdt; const uint* xp=(const uint*)&rxi;
    #pragma unroll
    for(int k=0;k<4;k++){
      uint ud=dp[k], ux=xp[k];
      pkc[2*k]   = (ud&0xffffu)|(ux<<16);
      pkc[2*k+1] = (ud>>16)|(ux&0xffff0000u);
    }
  };
  auto storeBC=[&](){
    #pragma unroll
    for(int k=0;k<4;k++){
      float4 v = make_float4(bflo(rbc[k].x), bfhi(rbc[k].x), bflo(rbc[k].y), bfhi(rbc[k].y));
      *(float4*)&bcl[(lane>>3)+k*8][(lane&7)*4] = v;
    }
  };
  float h[4];
  {
    float4 h0 = hstart[blk*64 + lane];
    h[0]=h0.x; h[1]=h0.y; h[2]=h0.z; h[3]=h0.w;
  }
  auto step2=[&](uint p0, uint p1, int j0){
    {
      float4 B4 = *(const float4*)&bcl[j0][sq*4];
      float4 C4 = *(const float4*)&bcl[j0][16+sq*4];
      float dtv=bflo(p0), xiv=bfhi(p0); float u=dtv*xiv;
      float p;
      #pragma unroll
      for(int i=0;i<4;i++){ float dA=exp2f(dtv*A2[i]); h[i]=fmaf(dA,h[i],u*((const float*)&B4)[i]); }
      p = h[0]*C4.x; p=fmaf(h[1],C4.y,p); p=fmaf(h[2],C4.z,p); p=fmaf(h[3],C4.w,p);
      p = quad_sum4(p);
      if(sq==0) pl[j0][ch] = p + xiv*Dv;
    }
    {
      float4 B4 = *(const float4*)&bcl[j0+1][sq*4];
      float4 C4 = *(const float4*)&bcl[j0+1][16+sq*4];
      float dtv=bflo(p1), xiv=bfhi(p1); float u=dtv*xiv;
      float p;
      #pragma unroll
      for(int i=0;i<4;i++){ float dA=exp2f(dtv*A2[i]); h[i]=fmaf(dA,h[i],u*((const float*)&B4)[i]); }
      p = h[0]*C4.x; p=fmaf(h[1],C4.y,p); p=fmaf(h[2],C4.z,p); p=fmaf(h[3],C4.w,p);
      p = quad_sum4(p);
      if(sq==0) pl[j0+1][ch] = p + xiv*Dv;
    }
  };
  issue(0); pack(); storeBC();
  for(int t=0;t<4;t++){
    if(t<3) issue(t+1);
    step2(qb<0>(pkc[0]),qb<0>(pkc[1]), 0);
    step2(qb<0>(pkc[2]),qb<0>(pkc[3]), 2);
    step2(qb<0>(pkc[4]),qb<0>(pkc[5]), 4);
    step2(qb<0>(pkc[6]),qb<0>(pkc[7]), 6);
    step2(qb<1>(pkc[0]),qb<1>(pkc[1]), 8);
    step2(qb<1>(pkc[2]),qb<1>(pkc[3]),10);
    step2(qb<1>(pkc[4]),qb<1>(pkc[5]),12);
    step2(qb<1>(pkc[6]),qb<1>(pkc[7]),14);
    step2(qb<2>(pkc[0]),qb<2>(pkc[1]),16);
    step2(qb<2>(pkc[2]),qb<2>(pkc[3]),18);
    step2(qb<2>(pkc[4]),qb<2>(pkc[5]),20);
    step2(qb<2>(pkc[6]),qb<2>(pkc[7]),22);
    step2(qb<3>(pkc[0]),qb<3>(pkc[1]),24);
    step2(qb<3>(pkc[2]),qb<3>(pkc[3]),26);
    step2(qb<3>(pkc[4]),qb<3>(pkc[5]),28);
    step2(qb<3>(pkc[6]),qb<3>(pkc[7]),30);
    // emit tile t
    {
      int l = l0c + t*32 + je;
      uint4 zr = rzb[t&1];
      const ushort* zp = (const ushort*)&zr;
      float pv[8];
      #pragma unroll
      for(int k=0;k<4;k++){
        float2 v2 = *(const float2*)&pl[je][halfe*8+2*k];
        pv[2*k]=v2.x; pv[2*k+1]=v2.y;
      }
      float yv[8];
      #pragma unroll
      for(int k=0;k<8;k++) yv[k] = pv[k] * silu_f(bf2f(zp[k]));
      uint4 yo;
      uint* yp=(uint*)&yo;
      yp[0]=f2bf2(yv[0],yv[1]); yp[1]=f2bf2(yv[2],yv[3]);
      yp[2]=f2bf2(yv[4],yv[5]); yp[3]=f2bf2(yv[6],yv[7]);
      *(uint4*)&y_bf[((size_t)zybase + l)*16 + halfe*8] = yo;
    }
    if(t<3){ pack(); storeBC(); }
  }
}

// ---------------- MFMA GEMM: res = (W'(64,512) x Y^T) * fo2s, out (B,64,L) c-major ----------------
__global__ __launch_bounds__(256) void gemm_res_mfma(const ushort* __restrict__ y_bf,
    const ushort* __restrict__ wf_bf, const float* __restrict__ fo2s, float* __restrict__ res){
  int blk = blockIdx.x; int b = blk>>5; int l0 = (blk&31)<<7;
  __shared__ __align__(16) ushort Wl[2][2560];
  __shared__ __align__(16) ushort Yl[2][5120];
  int t = threadIdx.x, lane = t&63, wid = t>>6;
  int rl = lane&15, kseg = (lane>>4)*8;
  f4_t acc[4][2];
  #pragma unroll
  for(int m=0;m<4;m++)
    #pragma unroll
    for(int n=0;n<2;n++) acc[m][n]=(f4_t){0.f,0.f,0.f,0.f};
  int ry = t>>1;
  int rw = t>>2, sgw = t&3;
  uint4 rY0, rY1, rW;
  auto issue=[&](int kc){
    int gg = 2*kc + (t&1);
    const ushort* yrow = &y_bf[(((size_t)(b*32)+gg)*4096 + l0+ry)*16];
    rY0 = *(const uint4*)&yrow[0];
    rY1 = *(const uint4*)&yrow[8];
    rW  = *(const uint4*)&wf_bf[(size_t)rw*512 + kc*32 + sgw*8];
  };
  auto store=[&](int buf){
    *(uint4*)&Yl[buf][ry*40 + (t&1)*16]     = rY0;
    *(uint4*)&Yl[buf][ry*40 + (t&1)*16 + 8] = rY1;
    *(uint4*)&Wl[buf][rw*40 + sgw*8]        = rW;
  };
  issue(0); store(0); __syncthreads();
  int buf=0;
  for(int kc=0;kc<16;kc++){
    bool more = kc<15;
    if(more) issue(kc+1);
    bf8_t aw[4], by[2];
    #pragma unroll
    for(int m=0;m<4;m++) aw[m] = *(const bf8_t*)&Wl[buf][(m*16+rl)*40 + kseg];
    #pragma unroll
    for(int n=0;n<2;n++) by[n] = *(const bf8_t*)&Yl[buf][(wid*32+n*16+rl)*40 + kseg];
    #pragma unroll
    for(int m=0;m<4;m++)
      #pragma unroll
      for(int n=0;n<2;n++)
        acc[m][n] = __builtin_amdgcn_mfma_f32_16x16x32_bf16(aw[m], by[n], acc[m][n], 0,0,0);
    __syncthreads();
    if(more){ store(buf^1); __syncthreads(); }
    buf^=1;
  }
  int orow = (lane>>4)*4;
  #pragma unroll
  for(int m=0;m<4;m++)
    #pragma unroll
    for(int n=0;n<2;n++){
      int l = l0 + wid*32 + n*16 + rl;
      #pragma unroll
      for(int r=0;r<4;r++){
        int o = m*16 + orow + r;
        size_t idx = ((size_t)(b*64+o))*4096 + l;
        res[idx] = acc[m][n][r]*fo2s[idx];
      }
    }
}

// ---------------- per (b,c) spatial mean ----------------
__global__ __launch_bounds__(256) void colmean(const float* __restrict__ res, float* __restrict__ fm){
  int bc = blockIdx.x;
  const float* p = res + (size_t)bc*4096;
  float s=0;
  for(int i=threadIdx.x;i<4096;i+=256) s+=p[i];
  __shared__ float ls[256];
  ls[threadIdx.x]=s; __syncthreads();
  for(int st=128;st>0;st>>=1){ if(threadIdx.x<st) ls[threadIdx.x]+=ls[threadIdx.x+st]; __syncthreads(); }
  if(threadIdx.x==0) fm[bc]=ls[0]*(1.f/4096.f);
}

// ---------------- tiny mamba2 over channel sequence ----------------
__global__ __launch_bounds__(64) void mamba2_kernel(const float* __restrict__ fm,
    const float* __restrict__ in_w, const float* __restrict__ cw, const float* __restrict__ cb,
    const float* __restrict__ xp, const float* __restrict__ dtw, const float* __restrict__ dtb,
    const float* __restrict__ Alog, const float* __restrict__ Dp, const float* __restrict__ ow,
    float* __restrict__ fsum){
  int b = blockIdx.x; int t = threadIdx.x;
  __shared__ float xi0m[64][4], xim[64][4], dtm[64][4], xbl[64][33], ym[64][4];
  float a0 = fm[b*64+t], a1 = fm[b*64 + 63-t];
  float zreg[4];
  #pragma unroll
  for(int d2=0;d2<4;d2++){
    xi0m[t][d2] = in_w[d2*2+0]*a0 + in_w[d2*2+1]*a1;
    zreg[d2]    = in_w[(4+d2)*2+0]*a0 + in_w[(4+d2)*2+1]*a1;
  }
  __syncthreads();
  float xir[4];
  #pragma unroll
  for(int d2=0;d2<4;d2++){
    float acc=cb[d2];
    #pragma unroll
    for(int k=0;k<4;k++){
      int srow=t-3+k;
      if(srow>=0) acc += cw[d2*4+k]*xi0m[srow][d2];
    }
    xir[d2]=silu_f(acc);
    xim[t][d2]=xir[d2];
  }
  for(int j=0;j<33;j++){
    float acc=0;
    #pragma unroll
    for(int d2=0;d2<4;d2++) acc += xp[j*4+d2]*xir[d2];
    xbl[t][j]=acc;
  }
  #pragma unroll
  for(int d2=0;d2<4;d2++){
    float v = xbl[t][0]*dtw[d2] + dtb[d2];
    dtm[t][d2] = (v>20.f)? v : log1pf(__expf(v));
  }
  __syncthreads();
  int dd=t>>4, s=t&15;
  float A2 = -__expf(Alog[dd*16+s]) * 1.44269504088896f;
  float h=0.f;
  for(int c=0;c<64;c++){
    float dtv=dtm[c][dd];
    float dA=exp2f(dtv*A2);
    h = fmaf(dA, h, dtv*xim[c][dd]*xbl[c][1+s]);
    float p = h*xbl[c][17+s];
    p += __shfl_xor(p,1,16);
    p += __shfl_xor(p,2,16);
    p += __shfl_xor(p,4,16);
    p += __shfl_xor(p,8,16);
    if(s==0) ym[c][dd]=p;
  }
  __syncthreads();
  float os=0.f;
  #pragma unroll
  for(int d2=0;d2<4;d2++){
    float yv = (ym[t][d2] + xim[t][d2]*Dp[d2]) * silu_f(zreg[d2]);
    os += yv * (ow[d2] + ow[4+d2]);
  }
  fsum[b*64+t]=os;
}

// ---------------- foss = res*(1+foc) ; x2 = outproj(foss) + x ----------------
__global__ __launch_bounds__(256) void outproj_kernel(const float* __restrict__ res,
    const float* __restrict__ fsum, const float* __restrict__ opw, const float* __restrict__ opb,
    const float* __restrict__ x, float* __restrict__ x2){
  int bh=blockIdx.x; int b=bh>>6,h=bh&63;
  __shared__ float tile[64][64];
  __shared__ float wl[4096];
  for(int i=threadIdx.x;i<4096;i+=256) wl[i]=opw[i];
  for(int i=threadIdx.x;i<4096;i+=256){
    int c=i>>6,w=i&63;
    tile[c][w]=res[((size_t)(b*64+c))*4096 + h*64 + w]*(1.f+fsum[b*64+c]);
  }
  __syncthreads();
  int px=threadIdx.x&63, og=threadIdx.x>>6;
  float acc[16];
  #pragma unroll
  for(int j=0;j<16;j++) acc[j]=0.f;
  for(int c=0;c<64;c++){
    float v=tile[c][px];
    #pragma unroll
    for(int j=0;j<16;j++) acc[j]=fmaf(wl[(og*16+j)*64+c],v,acc[j]);
  }
  for(int j=0;j<16;j++){
    int o=og*16+j;
    size_t idx=((size_t)(b*64+o))*4096 + h*64 + px;
    x2[idx]=acc[j]+opb[o]+x[idx];
  }
}

// ---------------- LN2 apply + ffn_in (64->256), grid (256,4), g bf16 ----------------
__global__ __launch_bounds__(256) void ffn_in_kernel(const float* __restrict__ x2,
    const float* __restrict__ n2w, const float* __restrict__ n2b,
    const float* __restrict__ fiw, const float* __restrict__ fib,
    const float* __restrict__ mu2, const float* __restrict__ rstd2,
    ushort* __restrict__ g){
  int bh=blockIdx.x; int b=bh>>6,h=bh&63;
  int oq=blockIdx.y;             // 0..3, 64 outputs each
  __shared__ float tile[64][64];
  __shared__ float wl[64*64];
  float m=mu2[b], rs=rstd2[b];
  for(int i=threadIdx.x;i<4096;i+=256){
    int c=i>>6,w=i&63;
    size_t sp=(size_t)c*4096 + h*64 + w;
    tile[c][w]=(x2[(size_t)b*262144+sp]-m)*rs*n2w[sp]+n2b[sp];
  }
  for(int i=threadIdx.x;i<4096;i+=256) wl[i]=fiw[(size_t)(oq*64)*64 + i];
  __syncthreads();
  int px=threadIdx.x&63, og=threadIdx.x>>6;
  float acc[16];
  #pragma unroll
  for(int j=0;j<16;j++) acc[j]=0.f;
  int ob = og*16;
  for(int c=0;c<64;c++){
    float v=tile[c][px];
    #pragma unroll
    for(int j=0;j<16;j++) acc[j]=fmaf(wl[(ob+j)*64+c],v,acc[j]);
  }
  for(int j=0;j<16;j++){
    int o = oq*64 + ob + j;
    g[((size_t)(b*256+o))*4096 + h*64 + px]=f2bf(acc[j]+fib[o]);
  }
}

// ---------------- ffn depthwise 3x3 + gelu-gate (bf16 in/out) ----------------
__global__ __launch_bounds__(256) void ffn_dw_gate(const ushort* __restrict__ g,
    const float* __restrict__ dww, const float* __restrict__ dwb, ushort* __restrict__ gm){
  int e = blockIdx.x*256 + threadIdx.x;   // 4*128*4096
  int sp = e & 4095, j = (e>>12)&127, b = e>>19;
  int h = sp>>6, w = sp&63;
  float v[2];
  #pragma unroll
  for(int half=0;half<2;half++){
    int ch = j + half*128;
    const ushort* gp = g + ((size_t)(b*256+ch))*4096;
    float acc = dwb[ch];
    #pragma unroll
    for(int kh=0;kh<3;kh++){
      int ih=h+kh-1; if(ih<0||ih>63) continue;
      #pragma unroll
      for(int kw=0;kw<3;kw++){
        int iw=w+kw-1; if(iw<0||iw>63) continue;
        acc += dww[ch*9+kh*3+kw]*bf2f(gp[ih*64+iw]);
      }
    }
    v[half]=acc;
  }
  float ge = 0.5f*v[0]*(1.f+erff(v[0]*0.70710678f));
  gm[((size_t)(b*128+j))*4096 + sp] = f2bf(ge*v[1]);
}

// ---------------- ffn_out (128->64) + bias + residual add -> d_out ----------------
__global__ __launch_bounds__(256) void ffn_out_kernel(const ushort* __restrict__ gm,
    const float* __restrict__ fow, const float* __restrict__ fob,
    const float* __restrict__ x2, float* __restrict__ out){
  int bh=blockIdx.x; int b=bh>>6,h=bh&63;
  __shared__ float tile[128][64];
  __shared__ float wl[64*128];
  for(int i=threadIdx.x;i<8192;i+=256){
    int c=i>>6,w=i&63;
    tile[c][w]=bf2f(gm[((size_t)(b*128+c))*4096 + h*64 + w]);
  }
  for(int i=threadIdx.x;i<8192;i+=256) wl[i]=fow[i];
  __syncthreads();
  int px=threadIdx.x&63, og=threadIdx.x>>6;
  float acc[16];
  #pragma unroll
  for(int j=0;j<16;j++) acc[j]=0.f;
  for(int c=0;c<128;c++){
    float v=tile[c][px];
    #pragma unroll
    for(int j=0;j<16;j++) acc[j]=fmaf(wl[(og*16+j)*128+c],v,acc[j]);
  }
  for(int j=0;j<16;j++){
    int o=og*16+j;
    size_t idx=((size_t)(b*64+o))*4096 + h*64 + px;
    out[idx]=acc[j]+fob[o]+x2[idx];
  }
}

extern "C" void kernel_launch(void* const* d_in, const int* in_sizes, int n_in,
                              void* d_out, int out_size, void* d_ws, size_t ws_size,
                              hipStream_t stream){
  const float* x      = (const float*)d_in[0];
  const float* n1w    = (const float*)d_in[1];
  const float* n1b    = (const float*)d_in[2];
  const float* n2w    = (const float*)d_in[3];
  const float* n2b    = (const float*)d_in[4];
  const float* ipw    = (const float*)d_in[5];
  const float* ipb    = (const float*)d_in[6];
  const float* dww    = (const float*)d_in[7];
  const float* dwb    = (const float*)d_in[8];
  const float* opw    = (const float*)d_in[9];
  const float* opb    = (const float*)d_in[10];
  const float* m1_inw = (const float*)d_in[11];
  const float* m1_cw  = (const float*)d_in[12];
  const float* m1_cb  = (const float*)d_in[13];
  const float* m1_xp  = (const float*)d_in[14];
  const float* m1_dtw = (const float*)d_in[15];
  const float* m1_dtb = (const float*)d_in[16];
  const float* m1_Al  = (const float*)d_in[17];
  const float* m1_D   = (const float*)d_in[18];
  const float* m1_ow  = (const float*)d_in[19];
  const float* m2_inw = (const float*)d_in[20];
  const float* m2_cw  = (const float*)d_in[21];
  const float* m2_cb  = (const float*)d_in[22];
  const float* m2_xp  = (const float*)d_in[23];
  const float* m2_dtw = (const float*)d_in[24];
  const float* m2_dtb = (const float*)d_in[25];
  const float* m2_Al  = (const float*)d_in[26];
  const float* m2_D   = (const float*)d_in[27];
  const float* m2_ow  = (const float*)d_in[28];
  const float* fiw    = (const float*)d_in[29];
  const float* fib    = (const float*)d_in[30];
  const float* fdw    = (const float*)d_in[31];
  const float* fdb    = (const float*)d_in[32];
  const float* fow    = (const float*)d_in[33];
  const float* fob    = (const float*)d_in[34];
  float* out = (float*)d_out;
  float* ws  = (float*)d_ws;

  const size_t M1 = 1048576;
  float* mu1   = ws + 0;  float* rstd1 = ws + 4;
  float* mu2   = ws + 8;  float* rstd2 = ws + 12;
  float* fmean = ws + 64;
  float* fsum  = ws + 320;
  float* lnpart= ws + 33792;
  float* base0 = ws + 36864;
  float* fo1raw= base0;                 // 1M [-> hstart -> res]
  float* fo2s  = base0 + M1;            // 1M
  float* fo1s  = base0 + 2*M1;          // 1M [-> Pbuf]
  float* fo1t  = base0 + 3*M1;          // 1M [-> qbuf]
  float* big0  = base0 + 4*M1;          // 8M: u_bf -> dt_bf(4M) -> g_bf(2M)
  float* big1  = base0 + 12*M1;         // 8M: xi0 -> y_bf(4M) + gm_bf(1M @ +4M)
  float* big2  = base0 + 20*M1;         // 8M: z_bf(4M) + xi_l(4M @ +4M)
  float* big3  = base0 + 28*M1;         // 8M: xi_c bf16 c-major (4M used)
  float* bcslot= base0 + 36*M1;         // 512K floats slot: bc_bf (256K used)
  float* x2    = base0 + 36*M1 + 524288;// 1M
  float* tail  = x2 + M1;
  ushort* w_bf    = (ushort*)tail;                    // 1024x256 bf16 (512KB)
  ushort* wcomb   = (ushort*)(tail + 131072);         // 576x512 bf16 (576KB)
  ushort* wf_bf   = (ushort*)(tail + 131072 + 147456);// 64x512 bf16 (64KB)

  uint*   u_bf  = (uint*)big0;
  ushort* dt_bf = (ushort*)big0;
  ushort* g_bf  = (ushort*)big0;
  float*  xi0   = big1;
  ushort* y_bf  = (ushort*)big1;
  ushort* gm_bf = (ushort*)(big1 + 4*M1);
  ushort* z_bf  = (ushort*)big2;
  ushort* xi_l  = (ushort*)(big2 + 4*M1);
  ushort* xi_c  = (ushort*)big3;
  ushort* bc_bf = (ushort*)bcslot;
  float*  Pbuf  = fo1s;
  float*  qbuf  = fo1t;
  float*  hstart= fo1raw;
  float*  res   = fo1raw;

  hipLaunchKernelGGL(ln_part, dim3(256), dim3(256), 0, stream, x, (float2*)lnpart);
  hipLaunchKernelGGL(ln_fin, dim3(4), dim3(64), 0, stream, (const float2*)lnpart, mu1, rstd1);
  hipLaunchKernelGGL(cvt_w_bf, dim3(512), dim3(256), 0, stream, m1_inw, (uint*)w_bf);
  hipLaunchKernelGGL(wdt_make, dim3(512), dim3(256), 0, stream, m1_dtw, m1_xp, wcomb);
  hipLaunchKernelGGL(cvt_bc_pad, dim3(128), dim3(256), 0, stream, m1_xp, wcomb);
  hipLaunchKernelGGL(fold_w_bf, dim3(128), dim3(256), 0, stream, m1_ow, wf_bf);
  hipLaunchKernelGGL(ln1_inproj, dim3(256), dim3(256), 0, stream,
                     x, n1w, n1b, ipw, ipb, mu1, rstd1, fo1raw, fo2s);
  hipLaunchKernelGGL(dwconv_silu_tr, dim3(256), dim3(256), 0, stream,
                     fo1raw, dww, dwb, fo1s, fo1t);
  hipLaunchKernelGGL(gather_u_t, dim3(1024), dim3(256), 0, stream, fo1s, fo1t, u_bf);
  hipLaunchKernelGGL(gemm_xz_mfma, dim3(128, 8), dim3(256), 0, stream,
                     (const ushort*)u_bf, w_bf, xi0, z_bf);
  hipLaunchKernelGGL(conv1d_silu2, dim3(2048), dim3(256), 0, stream,
                     xi0, m1_cw, m1_cb, xi_c, xi_l);
  hipLaunchKernelGGL(gemm_proj_mfma, dim3(256, 9), dim3(256), 0, stream,
                     xi_l, wcomb, m1_dtb, dt_bf, bc_bf);
  hipLaunchKernelGGL(scan3_p1, dim3(4096), dim3(64), 0, stream,
                     dt_bf, xi_c, bc_bf, m1_Al, (float4*)Pbuf, (float4*)qbuf);
  hipLaunchKernelGGL(scan3_mid, dim3(32), dim3(256), 0, stream,
                     (const float4*)Pbuf, (const float4*)qbuf, (float4*)hstart);
  hipLaunchKernelGGL(scan3_p2, dim3(4096), dim3(64), 0, stream,
                     dt_bf, xi_c, z_bf, bc_bf, m1_Al, m1_D, (const float4*)hstart, y_bf);
  hipLaunchKernelGGL(gemm_res_mfma, dim3(128), dim3(256), 0, stream,
                     y_bf, wf_bf, fo2s, res);
  hipLaunchKernelGGL(colmean, dim3(256), dim3(256), 0, stream, res, fmean);
  hipLaunchKernelGGL(mamba2_kernel, dim3(4), dim3(64), 0, stream,
                     fmean, m2_inw, m2_cw, m2_cb, m2_xp, m2_dtw, m2_dtb, m2_Al, m2_D, m2_ow, fsum);
  hipLaunchKernelGGL(outproj_kernel, dim3(256), dim3(256), 0, stream,
                     res, fsum, opw, opb, x, x2);
  hipLaunchKernelGGL(ln_part, dim3(256), dim3(256), 0, stream, x2, (float2*)lnpart);
  hipLaunchKernelGGL(ln_fin, dim3(4), dim3(64), 0, stream, (const float2*)lnpart, mu2, rstd2);
  hipLaunchKernelGGL(ffn_in_kernel, dim3(256, 4), dim3(256), 0, stream,
                     x2, n2w, n2b, fiw, fib, mu2, rstd2, g_bf);
  hipLaunchKernelGGL(ffn_dw_gate, dim3(8192), dim3(256), 0, stream, g_bf, fdw, fdb, gm_bf);
  hipLaunchKernelGGL(ffn_out_kernel, dim3(256), dim3(256), 0, stream, gm_bf, fow, fob, x2, out);
}

// Round 12
// 369.068 us; speedup vs baseline: 1.0836x; 1.0313x over previous
//
#include <hip/hip_runtime.h>
#include <math.h>

// OSS / VMamba-style block. B=4, C=64, H=W=64, L=4096, d_inner=512, D_STATE=16.
// R3: gemm_xz MFMA. R4: scan v3. R5: dt/BC/res MFMA. R6: merged gemm_proj, blocked z/y.
// R7: dt/xi bf16. R8: D folded, bf16 FFN. R9: B/C bf16 global, f32 LDS staging.
// R10: DPP quad-broadcast dt/xi, single-buffered LDS (p2 7.2KB).
// R11: 64 chunks of 64 (8192 scan blocks = 32/CU; grid was the occupancy cap).

#define DEV static __device__ __forceinline__

DEV float silu_f(float x){ return x / (1.f + __expf(-x)); }

DEV ushort f2bf(float f){
  uint u = __float_as_uint(f);
  uint r = (u + 0x7FFF + ((u>>16)&1)) >> 16;
  return (ushort)r;
}
DEV uint f2bf2(float lo, float hi){
  return (uint)f2bf(lo) | ((uint)f2bf(hi)<<16);
}
DEV float bf2f(ushort u){ return __uint_as_float(((uint)u)<<16); }
DEV float bflo(uint u){ return __uint_as_float(u<<16); }
DEV float bfhi(uint u){ return __uint_as_float(u&0xffff0000u); }

typedef __attribute__((ext_vector_type(8))) short bf8_t;
typedef __attribute__((ext_vector_type(4))) float f4_t;

DEV float quad_sum4(float v){
  v += __int_as_float(__builtin_amdgcn_update_dpp(0, __float_as_int(v), 0xB1, 0xF, 0xF, false));
  v += __int_as_float(__builtin_amdgcn_update_dpp(0, __float_as_int(v), 0x4E, 0xF, 0xF, false));
  return v;
}
// broadcast lane O of each DPP quad to all 4 lanes
template<int O> DEV uint qb(uint v){
  return (uint)__builtin_amdgcn_update_dpp(0, (int)v, O*0x55, 0xF, 0xF, false);
}

// ---------------- LayerNorm stats, two-stage ----------------
__global__ __launch_bounds__(256) void ln_part(const float* __restrict__ x,
                                               float2* __restrict__ part){
  int blk = blockIdx.x; int b = blk>>6, pc = blk&63;
  const float* p = x + (size_t)b*262144 + (size_t)pc*4096;
  float s=0.f, s2=0.f;
  #pragma unroll
  for(int it=0; it<4; ++it){
    int i = threadIdx.x + it*256;
    float4 v = *(const float4*)(p + i*4);
    s  += v.x+v.y+v.z+v.w;
    s2 += v.x*v.x+v.y*v.y+v.z*v.z+v.w*v.w;
  }
  __shared__ float ls[256], ls2[256];
  ls[threadIdx.x]=s; ls2[threadIdx.x]=s2; __syncthreads();
  for(int st=128;st>0;st>>=1){
    if(threadIdx.x<st){ ls[threadIdx.x]+=ls[threadIdx.x+st]; ls2[threadIdx.x]+=ls2[threadIdx.x+st]; }
    __syncthreads();
  }
  if(threadIdx.x==0) part[blk]=make_float2(ls[0],ls2[0]);
}
__global__ __launch_bounds__(64) void ln_fin(const float2* __restrict__ part,
                                             float* __restrict__ mu, float* __restrict__ rstd){
  int b = blockIdx.x;
  float2 v = part[b*64+threadIdx.x];
  __shared__ double ds_[64], ds2_[64];
  ds_[threadIdx.x]=v.x; ds2_[threadIdx.x]=v.y; __syncthreads();
  for(int st=32;st>0;st>>=1){
    if(threadIdx.x<st){ ds_[threadIdx.x]+=ds_[threadIdx.x+st]; ds2_[threadIdx.x]+=ds2_[threadIdx.x+st]; }
    __syncthreads();
  }
  if(threadIdx.x==0){
    double m = ds_[0]*(1.0/262144.0);
    double var = ds2_[0]*(1.0/262144.0) - m*m;
    mu[b]=(float)m; rstd[b]=(float)(1.0/sqrt(var+1e-5));
  }
}

// ---------------- LN1 apply + inproj (64->128) + split, silu on fo2 ----------------
__global__ __launch_bounds__(256) void ln1_inproj(const float* __restrict__ x,
    const float* __restrict__ n1w, const float* __restrict__ n1b,
    const float* __restrict__ ipw, const float* __restrict__ ipb,
    const float* __restrict__ mu, const float* __restrict__ rstd,
    float* __restrict__ fo1_raw, float* __restrict__ fo2s){
  int bh = blockIdx.x; int b = bh>>6, h = bh&63;
  __shared__ float xn[64][64];
  __shared__ float wl[128*64];
  float m = mu[b], rs = rstd[b];
  for(int i=threadIdx.x;i<4096;i+=256){
    int c=i>>6, w=i&63;
    size_t sp=(size_t)c*4096 + h*64 + w;
    float v = x[(size_t)b*262144 + sp];
    xn[c][w] = (v-m)*rs*n1w[sp] + n1b[sp];
  }
  for(int i=threadIdx.x;i<8192;i+=256) wl[i]=ipw[i];
  __syncthreads();
  int px = threadIdx.x & 63, ob = (threadIdx.x>>6)*32;
  float acc[32];
  #pragma unroll
  for(int j=0;j<32;j++) acc[j]=0.f;
  for(int c=0;c<64;c++){
    float xv = xn[c][px];
    #pragma unroll
    for(int j=0;j<32;j++) acc[j] = fmaf(wl[(ob+j)*64+c], xv, acc[j]);
  }
  for(int j=0;j<32;j++){
    int o = ob+j;
    float v = acc[j] + ipb[o];
    if(o<64) fo1_raw[((size_t)(b*64+o))*4096 + h*64 + px] = v;
    else     fo2s  [((size_t)(b*64+o-64))*4096 + h*64 + px] = silu_f(v);
  }
}

// ---------------- depthwise 3x3 + silu, writes normal + transposed spatial ----------------
__global__ __launch_bounds__(256) void dwconv_silu_tr(const float* __restrict__ src_,
    const float* __restrict__ dww, const float* __restrict__ dwb,
    float* __restrict__ fo1s, float* __restrict__ fo1t){
  int bc = blockIdx.x; int c = bc & 63;
  const float* src = src_ + (size_t)bc*4096;
  float wk[9];
  #pragma unroll
  for(int k=0;k<9;k++) wk[k]=dww[c*9+k];
  float bias = dwb[c];
  __shared__ float tl[64][65];
  for(int i=threadIdx.x;i<4096;i+=256){
    int h=i>>6, w=i&63;
    float acc=bias;
    #pragma unroll
    for(int kh=0;kh<3;kh++){
      int ih=h+kh-1; if(ih<0||ih>63) continue;
      #pragma unroll
      for(int kw=0;kw<3;kw++){
        int iw=w+kw-1; if(iw<0||iw>63) continue;
        acc += wk[kh*3+kw]*src[ih*64+iw];
      }
    }
    tl[h][w] = silu_f(acc);
  }
  __syncthreads();
  float* ps = fo1s + (size_t)bc*4096;
  float* pt = fo1t + (size_t)bc*4096;
  for(int i=threadIdx.x;i<4096;i+=256){
    ps[i] = tl[i>>6][i&63];
    pt[i] = tl[i&63][i>>6];
  }
}

// ---------------- weight preps ----------------
__global__ __launch_bounds__(256) void cvt_w_bf(const float* __restrict__ w, uint* __restrict__ wb){
  int i = blockIdx.x*256 + threadIdx.x;   // 131072 pairs
  float2 v = *(const float2*)(w + 2*i);
  wb[i] = f2bf2(v.x, v.y);
}
__global__ __launch_bounds__(256) void wdt_make(const float* __restrict__ dtw,
    const float* __restrict__ xpw, ushort* __restrict__ wcomb){
  int d = blockIdx.x;
  float wr[16];
  #pragma unroll
  for(int r=0;r<16;r++) wr[r]=dtw[d*16+r];
  for(int k=threadIdx.x;k<512;k+=256){
    float acc=0.f;
    #pragma unroll
    for(int r=0;r<16;r++) acc = fmaf(wr[r], xpw[r*512+k], acc);
    wcomb[(size_t)d*512+k]=f2bf(acc);
  }
}
__global__ __launch_bounds__(256) void cvt_bc_pad(const float* __restrict__ xpw, ushort* __restrict__ wcomb){
  int i = blockIdx.x*256 + threadIdx.x;   // 32768
  int row = i>>9, k = i&511;
  float v = (row<32) ? xpw[8192 + row*512 + k] : 0.f;
  wcomb[(size_t)(512+row)*512 + k] = f2bf(v);
}
__global__ __launch_bounds__(256) void fold_w_bf(const float* __restrict__ ow, ushort* __restrict__ wf){
  int i = blockIdx.x*256 + threadIdx.x;   // 32768
  int c = i>>9, d2 = i&511;
  wf[i] = f2bf(ow[c*512+d2] + ow[(64+c)*512+d2] + ow[(128+c)*512+d2] + ow[(192+c)*512+d2]);
}

// ---------------- gather u transposed: (B, L=4096, 256) bf16 ----------------
__global__ __launch_bounds__(256) void gather_u_t(const float* __restrict__ fo1s,
    const float* __restrict__ fo1t, uint* __restrict__ u_bf){
  int blk = blockIdx.x;
  int lt = blk&63, part = (blk>>6)&3, b = blk>>8;
  int l0 = lt<<6;
  const float* s = (part<2)? fo1s : fo1t;
  bool rev = part&1;
  __shared__ float tl[64][65];
  for(int i=threadIdx.x;i<4096;i+=256){
    int c=i>>6, j=i&63;
    int l = l0 + j;
    int idx = rev ? (4095-l) : l;
    tl[c][j] = s[((size_t)(b*64+c))*4096 + idx];
  }
  __syncthreads();
  for(int i=threadIdx.x;i<2048;i+=256){
    int j = i>>5, cp = i&31;
    int l = l0 + j;
    u_bf[((size_t)(b*4096)+l)*128 + part*32 + cp] = f2bf2(tl[2*cp][j], tl[2*cp+1][j]);
  }
}

// ---------------- MFMA GEMM: xz = W(1024,256) x U^T ----------------
__global__ __launch_bounds__(256) void gemm_xz_mfma(const ushort* __restrict__ u_bf,
    const ushort* __restrict__ w_bf, float* __restrict__ xi0, ushort* __restrict__ z_bf){
  int blk = blockIdx.x; int b = blk>>5; int l0 = (blk&31)<<7;
  int o0 = blockIdx.y<<7;
  __shared__ __align__(16) ushort Al[2][5120];
  __shared__ __align__(16) ushort Bl[2][5120];
  int t = threadIdx.x, lane = t&63, wid = t>>6;
  int wr = wid>>1, wc = wid&1;
  int rl = lane&15, kseg = (lane>>4)*8;
  f4_t acc[4][4];
  #pragma unroll
  for(int m=0;m<4;m++)
    #pragma unroll
    for(int n=0;n<4;n++) acc[m][n]=(f4_t){0.f,0.f,0.f,0.f};

  int r0 = t>>2, r1 = 64+(t>>2), seg = t&3;
  uint4 rA0,rA1,rB0,rB1;
  auto issue=[&](int kc){
    rA0 = *(const uint4*)&w_bf[(size_t)(o0+r0)*256 + kc*32 + seg*8];
    rA1 = *(const uint4*)&w_bf[(size_t)(o0+r1)*256 + kc*32 + seg*8];
    rB0 = *(const uint4*)&u_bf[((size_t)(b*4096)+l0+r0)*256 + kc*32 + seg*8];
    rB1 = *(const uint4*)&u_bf[((size_t)(b*4096)+l0+r1)*256 + kc*32 + seg*8];
  };
  auto store=[&](int buf){
    *(uint4*)&Al[buf][r0*40 + seg*8] = rA0;
    *(uint4*)&Al[buf][r1*40 + seg*8] = rA1;
    *(uint4*)&Bl[buf][r0*40 + seg*8] = rB0;
    *(uint4*)&Bl[buf][r1*40 + seg*8] = rB1;
  };
  issue(0); store(0); __syncthreads();
  int buf=0;
  for(int kc=0;kc<8;kc++){
    bool more = kc<7;
    if(more) issue(kc+1);
    bf8_t af[4], bfr[4];
    #pragma unroll
    for(int m=0;m<4;m++) af[m] = *(const bf8_t*)&Al[buf][(wr*64+m*16+rl)*40 + kseg];
    #pragma unroll
    for(int n=0;n<4;n++) bfr[n] = *(const bf8_t*)&Bl[buf][(wc*64+n*16+rl)*40 + kseg];
    #pragma unroll
    for(int m=0;m<4;m++)
      #pragma unroll
      for(int n=0;n<4;n++)
        acc[m][n] = __builtin_amdgcn_mfma_f32_16x16x32_bf16(af[m], bfr[n], acc[m][n], 0,0,0);
    __syncthreads();
    if(more){ store(buf^1); __syncthreads(); }
    buf^=1;
  }
  int orow = (lane>>4)*4;
  if(o0 < 512){
    #pragma unroll
    for(int m=0;m<4;m++)
      #pragma unroll
      for(int n=0;n<4;n++){
        int l = l0 + wc*64 + n*16 + rl;
        #pragma unroll
        for(int r=0;r<4;r++){
          int o = o0 + wr*64 + m*16 + orow + r;
          xi0[((size_t)(b*512)+o)*4096 + l] = acc[m][n][r];
        }
      }
  } else {
    #pragma unroll
    for(int m=0;m<4;m++)
      #pragma unroll
      for(int n=0;n<4;n++){
        int l = l0 + wc*64 + n*16 + rl;
        int gz = (o0 - 512 + wr*64 + m*16) >> 4;
        uint2 pkz;
        pkz.x = f2bf2(acc[m][n][0], acc[m][n][1]);
        pkz.y = f2bf2(acc[m][n][2], acc[m][n][3]);
        *(uint2*)&z_bf[(((size_t)(b*32)+gz)*4096 + l)*16 + orow] = pkz;
      }
  }
}

// ---------------- conv1d (k=4 causal) + silu: xi bf16 c-major + bf16 l-major ----------------
__global__ __launch_bounds__(256) void conv1d_silu2(const float* __restrict__ xi0,
    const float* __restrict__ cw, const float* __restrict__ cb,
    ushort* __restrict__ xi_c, ushort* __restrict__ xi_l){
  int blk = blockIdx.x;          // 2048: lt(64) | dt8(8) | b(4)
  int lt = blk&63, dt8 = (blk>>6)&7, b = blk>>9;
  int d0 = dt8*64, l0 = lt*64;
  __shared__ float T[64][65];
  int t = threadIdx.x, lloc = t&63, dq = t>>6;
  #pragma unroll 4
  for(int i=0;i<16;i++){
    int dloc = dq + i*4;
    int d = d0 + dloc;
    int l = l0 + lloc;
    size_t rowb = ((size_t)(b*512)+d)*4096;
    float acc = cb[d];
    #pragma unroll
    for(int k=0;k<4;k++){
      int ls = l-3+k;
      if(ls>=0) acc += cw[d*4+k]*xi0[rowb+ls];
    }
    acc = silu_f(acc);
    xi_c[rowb + l] = f2bf(acc);
    T[lloc][dloc] = acc;
  }
  __syncthreads();
  int dl = t&63;
  #pragma unroll 4
  for(int i=0;i<16;i++){
    int lloc2 = dq + i*4;
    xi_l[((size_t)(b*4096)+l0+lloc2)*512 + d0 + dl] = f2bf(T[lloc2][dl]);
  }
}

// ---------------- merged MFMA GEMM: [dt(512); bc(32)] = Wcomb(576,512) x xi^T ----------------
__global__ __launch_bounds__(256) void gemm_proj_mfma(const ushort* __restrict__ xi_bf,
    const ushort* __restrict__ wcomb, const float* __restrict__ dtb,
    ushort* __restrict__ dt_bf, ushort* __restrict__ bc_out){
  int blk = blockIdx.x; int b = blk>>6; int l0 = (blk&63)<<6;
  int o0 = blockIdx.y<<6;
  __shared__ __align__(16) ushort Al[2][2560];
  __shared__ __align__(16) ushort Bl[2][2560];
  int t = threadIdx.x, lane = t&63, wid = t>>6;
  int wo = wid>>1, wl = wid&1;
  int rl = lane&15, kseg = (lane>>4)*8;
  f4_t acc[2][2];
  #pragma unroll
  for(int m=0;m<2;m++)
    #pragma unroll
    for(int n=0;n<2;n++) acc[m][n]=(f4_t){0.f,0.f,0.f,0.f};
  int r = t>>2, seg = t&3;
  uint4 rA,rB;
  auto issue=[&](int kc){
    rA = *(const uint4*)&wcomb[(size_t)(o0+r)*512 + kc*32 + seg*8];
    rB = *(const uint4*)&xi_bf[((size_t)(b*4096)+l0+r)*512 + kc*32 + seg*8];
  };
  auto store=[&](int buf){
    *(uint4*)&Al[buf][r*40 + seg*8] = rA;
    *(uint4*)&Bl[buf][r*40 + seg*8] = rB;
  };
  issue(0); store(0); __syncthreads();
  int buf=0;
  for(int kc=0;kc<16;kc++){
    bool more = kc<15;
    if(more) issue(kc+1);
    bf8_t af[2], bfr[2];
    #pragma unroll
    for(int m=0;m<2;m++) af[m] = *(const bf8_t*)&Al[buf][(wo*32+m*16+rl)*40 + kseg];
    #pragma unroll
    for(int n=0;n<2;n++) bfr[n] = *(const bf8_t*)&Bl[buf][(wl*32+n*16+rl)*40 + kseg];
    #pragma unroll
    for(int m=0;m<2;m++)
      #pragma unroll
      for(int n=0;n<2;n++)
        acc[m][n] = __builtin_amdgcn_mfma_f32_16x16x32_bf16(af[m], bfr[n], acc[m][n], 0,0,0);
    __syncthreads();
    if(more){ store(buf^1); __syncthreads(); }
    buf^=1;
  }
  int orow = (lane>>4)*4;
  #pragma unroll
  for(int m=0;m<2;m++)
    #pragma unroll
    for(int n=0;n<2;n++){
      int l = l0 + wl*32 + n*16 + rl;
      #pragma unroll
      for(int rr=0;rr<4;rr++){
        int o = o0 + wo*32 + m*16 + orow + rr;
        float v = acc[m][n][rr];
        if(o<512){
          v += dtb[o];
          float sp = (v>20.f)? v : 0.69314718056f*__log2f(1.f+exp2f(1.44269504089f*v));
          dt_bf[((size_t)(b*512)+o)*4096 + l] = f2bf(sp);
        } else if(o<544){
          bc_out[((size_t)(b*4096)+l)*32 + (o-512)] = f2bf(v);
        }
      }
    }
}

// ================= scan v4: 64 chunks of 64; wave = 16 ch x 4 states =================
// blk = (b<<11)|(g<<6)|c. dt/xi via DPP quad-broadcast; B/C bf16 global, f32 LDS.
__global__ __launch_bounds__(64) void scan3_p1(
    const ushort* __restrict__ dtx, const ushort* __restrict__ xix,
    const ushort* __restrict__ bc, const float* __restrict__ Alog,
    float4* __restrict__ Pbuf, float4* __restrict__ qbuf){
  int blk=blockIdx.x;
  int c=blk&63, g=(blk>>6)&31, b=blk>>11;
  int lane=threadIdx.x, ch=lane>>2, sq=lane&3;
  int d=g*16+ch;
  float4 Ar = *(const float4*)(Alog + d*16 + sq*4);
  float A2[4];
  A2[0]=-__expf(Ar.x)*1.44269504088896f;
  A2[1]=-__expf(Ar.y)*1.44269504088896f;
  A2[2]=-__expf(Ar.z)*1.44269504088896f;
  A2[3]=-__expf(Ar.w)*1.44269504088896f;
  __shared__ __align__(16) float bl[32][20];
  const int l0c = c*64;
  const size_t dtrow = ((size_t)(b*512)+d)*4096;
  const ushort* xb = bc + (size_t)b*4096*32;
  uint4 rdt, rxi; uint2 rb[2];
  uint pkc[8];
  auto issue=[&](int t){
    int l0 = l0c + t*32;
    rdt = *(const uint4*)(dtx + dtrow + l0 + sq*8);
    rxi = *(const uint4*)(xix + dtrow + l0 + sq*8);
    #pragma unroll
    for(int k=0;k<2;k++){
      int j=ch+k*16;
      rb[k]=*(const uint2*)(xb + (size_t)(l0+j)*32 + sq*4);
    }
  };
  auto pack=[&](){
    const uint* dp=(const uint*)&rdt; const uint* xp=(const uint*)&rxi;
    #pragma unroll
    for(int k=0;k<4;k++){
      uint ud=dp[k], ux=xp[k];
      pkc[2*k]   = (ud&0xffffu)|(ux<<16);
      pkc[2*k+1] = (ud>>16)|(ux&0xffff0000u);
    }
  };
  auto storeB=[&](){
    #pragma unroll
    for(int k=0;k<2;k++){
      float4 bv = make_float4(bflo(rb[k].x), bfhi(rb[k].x), bflo(rb[k].y), bfhi(rb[k].y));
      *(float4*)&bl[ch+k*16][sq*4] = bv;
    }
  };
  float P[4]={1.f,1.f,1.f,1.f}, q[4]={0.f,0.f,0.f,0.f};
  auto step2=[&](uint p0, uint p1, int j0){
    float4 B0 = *(const float4*)&bl[j0][sq*4];
    float4 B1 = *(const float4*)&bl[j0+1][sq*4];
    {
      float dtv=bflo(p0), xiv=bfhi(p0); float u=dtv*xiv;
      #pragma unroll
      for(int i=0;i<4;i++){ float dA=exp2f(dtv*A2[i]); P[i]*=dA; q[i]=fmaf(dA,q[i],u*((const float*)&B0)[i]); }
    }
    {
      float dtv=bflo(p1), xiv=bfhi(p1); float u=dtv*xiv;
      #pragma unroll
      for(int i=0;i<4;i++){ float dA=exp2f(dtv*A2[i]); P[i]*=dA; q[i]=fmaf(dA,q[i],u*((const float*)&B1)[i]); }
    }
  };
  issue(0); pack(); storeB();
  for(int t=0;t<2;t++){
    if(t<1) issue(t+1);
    step2(qb<0>(pkc[0]),qb<0>(pkc[1]), 0);
    step2(qb<0>(pkc[2]),qb<0>(pkc[3]), 2);
    step2(qb<0>(pkc[4]),qb<0>(pkc[5]), 4);
    step2(qb<0>(pkc[6]),qb<0>(pkc[7]), 6);
    step2(qb<1>(pkc[0]),qb<1>(pkc[1]), 8);
    step2(qb<1>(pkc[2]),qb<1>(pkc[3]),10);
    step2(qb<1>(pkc[4]),qb<1>(pkc[5]),12);
    step2(qb<1>(pkc[6]),qb<1>(pkc[7]),14);
    step2(qb<2>(pkc[0]),qb<2>(pkc[1]),16);
    step2(qb<2>(pkc[2]),qb<2>(pkc[3]),18);
    step2(qb<2>(pkc[4]),qb<2>(pkc[5]),20);
    step2(qb<2>(pkc[6]),qb<2>(pkc[7]),22);
    step2(qb<3>(pkc[0]),qb<3>(pkc[1]),24);
    step2(qb<3>(pkc[2]),qb<3>(pkc[3]),26);
    step2(qb<3>(pkc[4]),qb<3>(pkc[5]),28);
    step2(qb<3>(pkc[6]),qb<3>(pkc[7]),30);
    if(t<1){ pack(); storeB(); }
  }
  int idx = blk*64 + lane;
  Pbuf[idx]=make_float4(P[0],P[1],P[2],P[3]);
  qbuf[idx]=make_float4(q[0],q[1],q[2],q[3]);
}

__global__ __launch_bounds__(256) void scan3_mid(const float4* __restrict__ Pbuf,
    const float4* __restrict__ qbuf, float4* __restrict__ hstart){
  int tid = blockIdx.x*256+threadIdx.x;  // 8192 = 128 groups * 64 lanes
  int lane = tid&63, sg = tid>>6;
  float4 h = make_float4(0.f,0.f,0.f,0.f);
  #pragma unroll 8
  for(int c=0;c<64;c++){
    int idx = (sg*64+c)*64 + lane;
    hstart[idx]=h;
    float4 P=Pbuf[idx], q=qbuf[idx];
    h.x = fmaf(P.x,h.x,q.x);
    h.y = fmaf(P.y,h.y,q.y);
    h.z = fmaf(P.z,h.z,q.z);
    h.w = fmaf(P.w,h.w,q.w);
  }
}

__global__ __launch_bounds__(64) void scan3_p2(
    const ushort* __restrict__ dtx, const ushort* __restrict__ xix,
    const ushort* __restrict__ z_bf, const ushort* __restrict__ bc,
    const float* __restrict__ Alog, const float* __restrict__ Dp,
    const float4* __restrict__ hstart, ushort* __restrict__ y_bf){
  int blk=blockIdx.x;
  int c=blk&63, g=(blk>>6)&31, b=blk>>11;
  int lane=threadIdx.x, ch=lane>>2, sq=lane&3;
  int d=g*16+ch;
  float4 Ar = *(const float4*)(Alog + d*16 + sq*4);
  float A2[4];
  A2[0]=-__expf(Ar.x)*1.44269504088896f;
  A2[1]=-__expf(Ar.y)*1.44269504088896f;
  A2[2]=-__expf(Ar.z)*1.44269504088896f;
  A2[3]=-__expf(Ar.w)*1.44269504088896f;
  float Dv = Dp[d];
  int je = lane>>1, halfe = lane&1;
  __shared__ __align__(16) float bcl[32][36];
  __shared__ __align__(16) float pl[32][18];
  const int l0c = c*64;
  const size_t dtrow = ((size_t)(b*512)+d)*4096;
  const ushort* xb = bc + (size_t)b*4096*32;
  const size_t zybase = (((size_t)(b*32)+g)*4096);
  uint4 rdt, rxi; uint2 rbc[4];
  uint4 rzb[2];
  uint pkc[8];
  auto issue=[&](int t){
    int l0 = l0c + t*32;
    rdt = *(const uint4*)(dtx + dtrow + l0 + sq*8);
    rxi = *(const uint4*)(xix + dtrow + l0 + sq*8);
    #pragma unroll
    for(int k=0;k<4;k++){
      int j=(lane>>3)+k*8, seg=lane&7;
      rbc[k]=*(const uint2*)(xb + (size_t)(l0+j)*32 + seg*4);
    }
    rzb[t&1] = *(const uint4*)&z_bf[(zybase + l0 + je)*16 + halfe*8];
  };
  auto pack=[&](){
    const uint* dp=(const uint*)&rdt; const uint* xp=(const uint*)&rxi;
    #pragma unroll
    for(int k=0;k<4;k++){
      uint ud=dp[k], ux=xp[k];
      pkc[2*k]   = (ud&0xffffu)|(ux<<16);
      pkc[2*k+1] = (ud>>16)|(ux&0xffff0000u);
    }
  };
  auto storeBC=[&](){
    #pragma unroll
    for(int k=0;k<4;k++){
      float4 v = make_float4(bflo(rbc[k].x), bfhi(rbc[k].x), bflo(rbc[k].y), bfhi(rbc[k].y));
      *(float4*)&bcl[(lane>>3)+k*8][(lane&7)*4] = v;
    }
  };
  float h[4];
  {
    float4 h0 = hstart[blk*64 + lane];
    h[0]=h0.x; h[1]=h0.y; h[2]=h0.z; h[3]=h0.w;
  }
  auto step2=[&](uint p0, uint p1, int j0){
    {
      float4 B4 = *(const float4*)&bcl[j0][sq*4];
      float4 C4 = *(const float4*)&bcl[j0][16+sq*4];
      float dtv=bflo(p0), xiv=bfhi(p0); float u=dtv*xiv;
      float p;
      #pragma unroll
      for(int i=0;i<4;i++){ float dA=exp2f(dtv*A2[i]); h[i]=fmaf(dA,h[i],u*((const float*)&B4)[i]); }
      p = h[0]*C4.x; p=fmaf(h[1],C4.y,p); p=fmaf(h[2],C4.z,p); p=fmaf(h[3],C4.w,p);
      p = quad_sum4(p);
      if(sq==0) pl[j0][ch] = p + xiv*Dv;
    }
    {
      float4 B4 = *(const float4*)&bcl[j0+1][sq*4];
      float4 C4 = *(const float4*)&bcl[j0+1][16+sq*4];
      float dtv=bflo(p1), xiv=bfhi(p1); float u=dtv*xiv;
      float p;
      #pragma unroll
      for(int i=0;i<4;i++){ float dA=exp2f(dtv*A2[i]); h[i]=fmaf(dA,h[i],u*((const float*)&B4)[i]); }
      p = h[0]*C4.x; p=fmaf(h[1],C4.y,p); p=fmaf(h[2],C4.z,p); p=fmaf(h[3],C4.w,p);
      p = quad_sum4(p);
      if(sq==0) pl[j0+1][ch] = p + xiv*Dv;
    }
  };
  issue(0); pack(); storeBC();
  for(int t=0;t<2;t++){
    if(t<1) issue(t+1);
    step2(qb<0>(pkc[0]),qb<0>(pkc[1]), 0);
    step2(qb<0>(pkc[2]),qb<0>(pkc[3]), 2);
    step2(qb<0>(pkc[4]),qb<0>(pkc[5]), 4);
    step2(qb<0>(pkc[6]),qb<0>(pkc[7]), 6);
    step2(qb<1>(pkc[0]),qb<1>(pkc[1]), 8);
    step2(qb<1>(pkc[2]),qb<1>(pkc[3]),10);
    step2(qb<1>(pkc[4]),qb<1>(pkc[5]),12);
    step2(qb<1>(pkc[6]),qb<1>(pkc[7]),14);
    step2(qb<2>(pkc[0]),qb<2>(pkc[1]),16);
    step2(qb<2>(pkc[2]),qb<2>(pkc[3]),18);
    step2(qb<2>(pkc[4]),qb<2>(pkc[5]),20);
    step2(qb<2>(pkc[6]),qb<2>(pkc[7]),22);
    step2(qb<3>(pkc[0]),qb<3>(pkc[1]),24);
    step2(qb<3>(pkc[2]),qb<3>(pkc[3]),26);
    step2(qb<3>(pkc[4]),qb<3>(pkc[5]),28);
    step2(qb<3>(pkc[6]),qb<3>(pkc[7]),30);
    // emit tile t
    {
      int l = l0c + t*32 + je;
      uint4 zr = rzb[t&1];
      const ushort* zp = (const ushort*)&zr;
      float pv[8];
      #pragma unroll
      for(int k=0;k<4;k++){
        float2 v2 = *(const float2*)&pl[je][halfe*8+2*k];
        pv[2*k]=v2.x; pv[2*k+1]=v2.y;
      }
      float yv[8];
      #pragma unroll
      for(int k=0;k<8;k++) yv[k] = pv[k] * silu_f(bf2f(zp[k]));
      uint4 yo;
      uint* yp=(uint*)&yo;
      yp[0]=f2bf2(yv[0],yv[1]); yp[1]=f2bf2(yv[2],yv[3]);
      yp[2]=f2bf2(yv[4],yv[5]); yp[3]=f2bf2(yv[6],yv[7]);
      *(uint4*)&y_bf[((size_t)zybase + l)*16 + halfe*8] = yo;
    }
    if(t<1){ pack(); storeBC(); }
  }
}

// ---------------- MFMA GEMM: res = (W'(64,512) x Y^T) * fo2s, out (B,64,L) c-major ----------------
__global__ __launch_bounds__(256) void gemm_res_mfma(const ushort* __restrict__ y_bf,
    const ushort* __restrict__ wf_bf, const float* __restrict__ fo2s, float* __restrict__ res){
  int blk = blockIdx.x; int b = blk>>5; int l0 = (blk&31)<<7;
  __shared__ __align__(16) ushort Wl[2][2560];
  __shared__ __align__(16) ushort Yl[2][5120];
  int t = threadIdx.x, lane = t&63, wid = t>>6;
  int rl = lane&15, kseg = (lane>>4)*8;
  f4_t acc[4][2];
  #pragma unroll
  for(int m=0;m<4;m++)
    #pragma unroll
    for(int n=0;n<2;n++) acc[m][n]=(f4_t){0.f,0.f,0.f,0.f};
  int ry = t>>1;
  int rw = t>>2, sgw = t&3;
  uint4 rY0, rY1, rW;
  auto issue=[&](int kc){
    int gg = 2*kc + (t&1);
    const ushort* yrow = &y_bf[(((size_t)(b*32)+gg)*4096 + l0+ry)*16];
    rY0 = *(const uint4*)&yrow[0];
    rY1 = *(const uint4*)&yrow[8];
    rW  = *(const uint4*)&wf_bf[(size_t)rw*512 + kc*32 + sgw*8];
  };
  auto store=[&](int buf){
    *(uint4*)&Yl[buf][ry*40 + (t&1)*16]     = rY0;
    *(uint4*)&Yl[buf][ry*40 + (t&1)*16 + 8] = rY1;
    *(uint4*)&Wl[buf][rw*40 + sgw*8]        = rW;
  };
  issue(0); store(0); __syncthreads();
  int buf=0;
  for(int kc=0;kc<16;kc++){
    bool more = kc<15;
    if(more) issue(kc+1);
    bf8_t aw[4], by[2];
    #pragma unroll
    for(int m=0;m<4;m++) aw[m] = *(const bf8_t*)&Wl[buf][(m*16+rl)*40 + kseg];
    #pragma unroll
    for(int n=0;n<2;n++) by[n] = *(const bf8_t*)&Yl[buf][(wid*32+n*16+rl)*40 + kseg];
    #pragma unroll
    for(int m=0;m<4;m++)
      #pragma unroll
      for(int n=0;n<2;n++)
        acc[m][n] = __builtin_amdgcn_mfma_f32_16x16x32_bf16(aw[m], by[n], acc[m][n], 0,0,0);
    __syncthreads();
    if(more){ store(buf^1); __syncthreads(); }
    buf^=1;
  }
  int orow = (lane>>4)*4;
  #pragma unroll
  for(int m=0;m<4;m++)
    #pragma unroll
    for(int n=0;n<2;n++){
      int l = l0 + wid*32 + n*16 + rl;
      #pragma unroll
      for(int r=0;r<4;r++){
        int o = m*16 + orow + r;
        size_t idx = ((size_t)(b*64+o))*4096 + l;
        res[idx] = acc[m][n][r]*fo2s[idx];
      }
    }
}

// ---------------- per (b,c) spatial mean ----------------
__global__ __launch_bounds__(256) void colmean(const float* __restrict__ res, float* __restrict__ fm){
  int bc = blockIdx.x;
  const float* p = res + (size_t)bc*4096;
  float s=0;
  for(int i=threadIdx.x;i<4096;i+=256) s+=p[i];
  __shared__ float ls[256];
  ls[threadIdx.x]=s; __syncthreads();
  for(int st=128;st>0;st>>=1){ if(threadIdx.x<st) ls[threadIdx.x]+=ls[threadIdx.x+st]; __syncthreads(); }
  if(threadIdx.x==0) fm[bc]=ls[0]*(1.f/4096.f);
}

// ---------------- tiny mamba2 over channel sequence ----------------
__global__ __launch_bounds__(64) void mamba2_kernel(const float* __restrict__ fm,
    const float* __restrict__ in_w, const float* __restrict__ cw, const float* __restrict__ cb,
    const float* __restrict__ xp, const float* __restrict__ dtw, const float* __restrict__ dtb,
    const float* __restrict__ Alog, const float* __restrict__ Dp, const float* __restrict__ ow,
    float* __restrict__ fsum){
  int b = blockIdx.x; int t = threadIdx.x;
  __shared__ float xi0m[64][4], xim[64][4], dtm[64][4], xbl[64][33], ym[64][4];
  float a0 = fm[b*64+t], a1 = fm[b*64 + 63-t];
  float zreg[4];
  #pragma unroll
  for(int d2=0;d2<4;d2++){
    xi0m[t][d2] = in_w[d2*2+0]*a0 + in_w[d2*2+1]*a1;
    zreg[d2]    = in_w[(4+d2)*2+0]*a0 + in_w[(4+d2)*2+1]*a1;
  }
  __syncthreads();
  float xir[4];
  #pragma unroll
  for(int d2=0;d2<4;d2++){
    float acc=cb[d2];
    #pragma unroll
    for(int k=0;k<4;k++){
      int srow=t-3+k;
      if(srow>=0) acc += cw[d2*4+k]*xi0m[srow][d2];
    }
    xir[d2]=silu_f(acc);
    xim[t][d2]=xir[d2];
  }
  for(int j=0;j<33;j++){
    float acc=0;
    #pragma unroll
    for(int d2=0;d2<4;d2++) acc += xp[j*4+d2]*xir[d2];
    xbl[t][j]=acc;
  }
  #pragma unroll
  for(int d2=0;d2<4;d2++){
    float v = xbl[t][0]*dtw[d2] + dtb[d2];
    dtm[t][d2] = (v>20.f)? v : log1pf(__expf(v));
  }
  __syncthreads();
  int dd=t>>4, s=t&15;
  float A2 = -__expf(Alog[dd*16+s]) * 1.44269504088896f;
  float h=0.f;
  for(int c=0;c<64;c++){
    float dtv=dtm[c][dd];
    float dA=exp2f(dtv*A2);
    h = fmaf(dA, h, dtv*xim[c][dd]*xbl[c][1+s]);
    float p = h*xbl[c][17+s];
    p += __shfl_xor(p,1,16);
    p += __shfl_xor(p,2,16);
    p += __shfl_xor(p,4,16);
    p += __shfl_xor(p,8,16);
    if(s==0) ym[c][dd]=p;
  }
  __syncthreads();
  float os=0.f;
  #pragma unroll
  for(int d2=0;d2<4;d2++){
    float yv = (ym[t][d2] + xim[t][d2]*Dp[d2]) * silu_f(zreg[d2]);
    os += yv * (ow[d2] + ow[4+d2]);
  }
  fsum[b*64+t]=os;
}

// ---------------- foss = res*(1+foc) ; x2 = outproj(foss) + x ----------------
__global__ __launch_bounds__(256) void outproj_kernel(const float* __restrict__ res,
    const float* __restrict__ fsum, const float* __restrict__ opw, const float* __restrict__ opb,
    const float* __restrict__ x, float* __restrict__ x2){
  int bh=blockIdx.x; int b=bh>>6,h=bh&63;
  __shared__ float tile[64][64];
  __shared__ float wl[4096];
  for(int i=threadIdx.x;i<4096;i+=256) wl[i]=opw[i];
  for(int i=threadIdx.x;i<4096;i+=256){
    int c=i>>6,w=i&63;
    tile[c][w]=res[((size_t)(b*64+c))*4096 + h*64 + w]*(1.f+fsum[b*64+c]);
  }
  __syncthreads();
  int px=threadIdx.x&63, og=threadIdx.x>>6;
  float acc[16];
  #pragma unroll
  for(int j=0;j<16;j++) acc[j]=0.f;
  for(int c=0;c<64;c++){
    float v=tile[c][px];
    #pragma unroll
    for(int j=0;j<16;j++) acc[j]=fmaf(wl[(og*16+j)*64+c],v,acc[j]);
  }
  for(int j=0;j<16;j++){
    int o=og*16+j;
    size_t idx=((size_t)(b*64+o))*4096 + h*64 + px;
    x2[idx]=acc[j]+opb[o]+x[idx];
  }
}

// ---------------- LN2 apply + ffn_in (64->256), grid (256,4), g bf16 ----------------
__global__ __launch_bounds__(256) void ffn_in_kernel(const float* __restrict__ x2,
    const float* __restrict__ n2w, const float* __restrict__ n2b,
    const float* __restrict__ fiw, const float* __restrict__ fib,
    const float* __restrict__ mu2, const float* __restrict__ rstd2,
    ushort* __restrict__ g){
  int bh=blockIdx.x; int b=bh>>6,h=bh&63;
  int oq=blockIdx.y;             // 0..3, 64 outputs each
  __shared__ float tile[64][64];
  __shared__ float wl[64*64];
  float m=mu2[b], rs=rstd2[b];
  for(int i=threadIdx.x;i<4096;i+=256){
    int c=i>>6,w=i&63;
    size_t sp=(size_t)c*4096 + h*64 + w;
    tile[c][w]=(x2[(size_t)b*262144+sp]-m)*rs*n2w[sp]+n2b[sp];
  }
  for(int i=threadIdx.x;i<4096;i+=256) wl[i]=fiw[(size_t)(oq*64)*64 + i];
  __syncthreads();
  int px=threadIdx.x&63, og=threadIdx.x>>6;
  float acc[16];
  #pragma unroll
  for(int j=0;j<16;j++) acc[j]=0.f;
  int ob = og*16;
  for(int c=0;c<64;c++){
    float v=tile[c][px];
    #pragma unroll
    for(int j=0;j<16;j++) acc[j]=fmaf(wl[(ob+j)*64+c],v,acc[j]);
  }
  for(int j=0;j<16;j++){
    int o = oq*64 + ob + j;
    g[((size_t)(b*256+o))*4096 + h*64 + px]=f2bf(acc[j]+fib[o]);
  }
}

// ---------------- ffn depthwise 3x3 + gelu-gate (bf16 in/out) ----------------
__global__ __launch_bounds__(256) void ffn_dw_gate(const ushort* __restrict__ g,
    const float* __restrict__ dww, const float* __restrict__ dwb, ushort* __restrict__ gm){
  int e = blockIdx.x*256 + threadIdx.x;   // 4*128*4096
  int sp = e & 4095, j = (e>>12)&127, b = e>>19;
  int h = sp>>6, w = sp&63;
  float v[2];
  #pragma unroll
  for(int half=0;half<2;half++){
    int ch = j + half*128;
    const ushort* gp = g + ((size_t)(b*256+ch))*4096;
    float acc = dwb[ch];
    #pragma unroll
    for(int kh=0;kh<3;kh++){
      int ih=h+kh-1; if(ih<0||ih>63) continue;
      #pragma unroll
      for(int kw=0;kw<3;kw++){
        int iw=w+kw-1; if(iw<0||iw>63) continue;
        acc += dww[ch*9+kh*3+kw]*bf2f(gp[ih*64+iw]);
      }
    }
    v[half]=acc;
  }
  float ge = 0.5f*v[0]*(1.f+erff(v[0]*0.70710678f));
  gm[((size_t)(b*128+j))*4096 + sp] = f2bf(ge*v[1]);
}

// ---------------- ffn_out (128->64) + bias + residual add -> d_out ----------------
__global__ __launch_bounds__(256) void ffn_out_kernel(const ushort* __restrict__ gm,
    const float* __restrict__ fow, const float* __restrict__ fob,
    const float* __restrict__ x2, float* __restrict__ out){
  int bh=blockIdx.x; int b=bh>>6,h=bh&63;
  __shared__ float tile[128][64];
  __shared__ float wl[64*128];
  for(int i=threadIdx.x;i<8192;i+=256){
    int c=i>>6,w=i&63;
    tile[c][w]=bf2f(gm[((size_t)(b*128+c))*4096 + h*64 + w]);
  }
  for(int i=threadIdx.x;i<8192;i+=256) wl[i]=fow[i];
  __syncthreads();
  int px=threadIdx.x&63, og=threadIdx.x>>6;
  float acc[16];
  #pragma unroll
  for(int j=0;j<16;j++) acc[j]=0.f;
  for(int c=0;c<128;c++){
    float v=tile[c][px];
    #pragma unroll
    for(int j=0;j<16;j++) acc[j]=fmaf(wl[(og*16+j)*128+c],v,acc[j]);
  }
  for(int j=0;j<16;j++){
    int o=og*16+j;
    size_t idx=((size_t)(b*64+o))*4096 + h*64 + px;
    out[idx]=acc[j]+fob[o]+x2[idx];
  }
}

extern "C" void kernel_launch(void* const* d_in, const int* in_sizes, int n_in,
                              void* d_out, int out_size, void* d_ws, size_t ws_size,
                              hipStream_t stream){
  const float* x      = (const float*)d_in[0];
  const float* n1w    = (const float*)d_in[1];
  const float* n1b    = (const float*)d_in[2];
  const float* n2w    = (const float*)d_in[3];
  const float* n2b    = (const float*)d_in[4];
  const float* ipw    = (const float*)d_in[5];
  const float* ipb    = (const float*)d_in[6];
  const float* dww    = (const float*)d_in[7];
  const float* dwb    = (const float*)d_in[8];
  const float* opw    = (const float*)d_in[9];
  const float* opb    = (const float*)d_in[10];
  const float* m1_inw = (const float*)d_in[11];
  const float* m1_cw  = (const float*)d_in[12];
  const float* m1_cb  = (const float*)d_in[13];
  const float* m1_xp  = (const float*)d_in[14];
  const float* m1_dtw = (const float*)d_in[15];
  const float* m1_dtb = (const float*)d_in[16];
  const float* m1_Al  = (const float*)d_in[17];
  const float* m1_D   = (const float*)d_in[18];
  const float* m1_ow  = (const float*)d_in[19];
  const float* m2_inw = (const float*)d_in[20];
  const float* m2_cw  = (const float*)d_in[21];
  const float* m2_cb  = (const float*)d_in[22];
  const float* m2_xp  = (const float*)d_in[23];
  const float* m2_dtw = (const float*)d_in[24];
  const float* m2_dtb = (const float*)d_in[25];
  const float* m2_Al  = (const float*)d_in[26];
  const float* m2_D   = (const float*)d_in[27];
  const float* m2_ow  = (const float*)d_in[28];
  const float* fiw    = (const float*)d_in[29];
  const float* fib    = (const float*)d_in[30];
  const float* fdw    = (const float*)d_in[31];
  const float* fdb    = (const float*)d_in[32];
  const float* fow    = (const float*)d_in[33];
  const float* fob    = (const float*)d_in[34];
  float* out = (float*)d_out;
  float* ws  = (float*)d_ws;

  const size_t M1 = 1048576;
  float* mu1   = ws + 0;  float* rstd1 = ws + 4;
  float* mu2   = ws + 8;  float* rstd2 = ws + 12;
  float* fmean = ws + 64;
  float* fsum  = ws + 320;
  float* lnpart= ws + 33792;
  float* base0 = ws + 36864;
  float* fo1raw= base0;                 // 1M [-> res]
  float* fo2s  = base0 + M1;            // 1M
  float* fo1s  = base0 + 2*M1;          // 1M
  float* fo1t  = base0 + 3*M1;          // 1M
  float* big0  = base0 + 4*M1;          // 8M: u_bf(2M) -> dt_bf(4M) + hstart(2M @ +4M) -> g_bf(2M)
  float* big1  = base0 + 12*M1;         // 8M: xi0 -> y_bf(4M) + gm_bf(1M @ +4M)
  float* big2  = base0 + 20*M1;         // 8M: z_bf(4M) + xi_l(4M @ +4M)
  float* big3  = base0 + 28*M1;         // 8M: xi_c(4M) + Pbuf(2M @ +4M) + qbuf(2M @ +6M)
  float* bcslot= base0 + 36*M1;         // 512K floats slot: bc_bf (256K used)
  float* x2    = base0 + 36*M1 + 524288;// 1M
  float* tail  = x2 + M1;
  ushort* w_bf    = (ushort*)tail;                    // 1024x256 bf16 (512KB)
  ushort* wcomb   = (ushort*)(tail + 131072);         // 576x512 bf16 (576KB)
  ushort* wf_bf   = (ushort*)(tail + 131072 + 147456);// 64x512 bf16 (64KB)

  uint*   u_bf  = (uint*)big0;
  ushort* dt_bf = (ushort*)big0;
  ushort* g_bf  = (ushort*)big0;
  float*  hstart= big0 + 4*M1;          // 2M floats (8192 blk * 64 * float4)
  float*  xi0   = big1;
  ushort* y_bf  = (ushort*)big1;
  ushort* gm_bf = (ushort*)(big1 + 4*M1);
  ushort* z_bf  = (ushort*)big2;
  ushort* xi_l  = (ushort*)(big2 + 4*M1);
  ushort* xi_c  = (ushort*)big3;
  float*  Pbuf  = big3 + 4*M1;          // 2M floats
  float*  qbuf  = big3 + 6*M1;          // 2M floats
  ushort* bc_bf = (ushort*)bcslot;
  float*  res   = fo1raw;

  hipLaunchKernelGGL(ln_part, dim3(256), dim3(256), 0, stream, x, (float2*)lnpart);
  hipLaunchKernelGGL(ln_fin, dim3(4), dim3(64), 0, stream, (const float2*)lnpart, mu1, rstd1);
  hipLaunchKernelGGL(cvt_w_bf, dim3(512), dim3(256), 0, stream, m1_inw, (uint*)w_bf);
  hipLaunchKernelGGL(wdt_make, dim3(512), dim3(256), 0, stream, m1_dtw, m1_xp, wcomb);
  hipLaunchKernelGGL(cvt_bc_pad, dim3(128), dim3(256), 0, stream, m1_xp, wcomb);
  hipLaunchKernelGGL(fold_w_bf, dim3(128), dim3(256), 0, stream, m1_ow, wf_bf);
  hipLaunchKernelGGL(ln1_inproj, dim3(256), dim3(256), 0, stream,
                     x, n1w, n1b, ipw, ipb, mu1, rstd1, fo1raw, fo2s);
  hipLaunchKernelGGL(dwconv_silu_tr, dim3(256), dim3(256), 0, stream,
                     fo1raw, dww, dwb, fo1s, fo1t);
  hipLaunchKernelGGL(gather_u_t, dim3(1024), dim3(256), 0, stream, fo1s, fo1t, u_bf);
  hipLaunchKernelGGL(gemm_xz_mfma, dim3(128, 8), dim3(256), 0, stream,
                     (const ushort*)u_bf, w_bf, xi0, z_bf);
  hipLaunchKernelGGL(conv1d_silu2, dim3(2048), dim3(256), 0, stream,
                     xi0, m1_cw, m1_cb, xi_c, xi_l);
  hipLaunchKernelGGL(gemm_proj_mfma, dim3(256, 9), dim3(256), 0, stream,
                     xi_l, wcomb, m1_dtb, dt_bf, bc_bf);
  hipLaunchKernelGGL(scan3_p1, dim3(8192), dim3(64), 0, stream,
                     dt_bf, xi_c, bc_bf, m1_Al, (float4*)Pbuf, (float4*)qbuf);
  hipLaunchKernelGGL(scan3_mid, dim3(32), dim3(256), 0, stream,
                     (const float4*)Pbuf, (const float4*)qbuf, (float4*)hstart);
  hipLaunchKernelGGL(scan3_p2, dim3(8192), dim3(64), 0, stream,
                     dt_bf, xi_c, z_bf, bc_bf, m1_Al, m1_D, (const float4*)hstart, y_bf);
  hipLaunchKernelGGL(gemm_res_mfma, dim3(128), dim3(256), 0, stream,
                     y_bf, wf_bf, fo2s, res);
  hipLaunchKernelGGL(colmean, dim3(256), dim3(256), 0, stream, res, fmean);
  hipLaunchKernelGGL(mamba2_kernel, dim3(4), dim3(64), 0, stream,
                     fmean, m2_inw, m2_cw, m2_cb, m2_xp, m2_dtw, m2_dtb, m2_Al, m2_D, m2_ow, fsum);
  hipLaunchKernelGGL(outproj_kernel, dim3(256), dim3(256), 0, stream,
                     res, fsum, opw, opb, x, x2);
  hipLaunchKernelGGL(ln_part, dim3(256), dim3(256), 0, stream, x2, (float2*)lnpart);
  hipLaunchKernelGGL(ln_fin, dim3(4), dim3(64), 0, stream, (const float2*)lnpart, mu2, rstd2);
  hipLaunchKernelGGL(ffn_in_kernel, dim3(256, 4), dim3(256), 0, stream,
                     x2, n2w, n2b, fiw, fib, mu2, rstd2, g_bf);
  hipLaunchKernelGGL(ffn_dw_gate, dim3(8192), dim3(256), 0, stream, g_bf, fdw, fdb, gm_bf);
  hipLaunchKernelGGL(ffn_out_kernel, dim3(256), dim3(256), 0, stream, gm_bf, fow, fob, x2, out);
}

// Round 13
// 355.829 us; speedup vs baseline: 1.1239x; 1.0372x over previous
//
#include <hip/hip_runtime.h>
#include <math.h>

// OSS / VMamba-style block. B=4, C=64, H=W=64, L=4096, d_inner=512, D_STATE=16.
// R3: gemm_xz MFMA. R4: scan v3. R5: dt/BC/res MFMA. R6: merged gemm_proj, blocked z/y.
// R7: dt/xi bf16. R8: D folded, bf16 FFN. R9: B/C bf16 global, f32 LDS staging.
// R10: DPP quad-broadcast dt/xi, single-buffered LDS. R11: 64 chunks of 64.
// R12: ffn_in -> ln2_apply_bf + MFMA GEMM (g planar bf16); LN2 stats fused into outproj.

#define DEV static __device__ __forceinline__

DEV float silu_f(float x){ return x / (1.f + __expf(-x)); }

DEV ushort f2bf(float f){
  uint u = __float_as_uint(f);
  uint r = (u + 0x7FFF + ((u>>16)&1)) >> 16;
  return (ushort)r;
}
DEV uint f2bf2(float lo, float hi){
  return (uint)f2bf(lo) | ((uint)f2bf(hi)<<16);
}
DEV float bf2f(ushort u){ return __uint_as_float(((uint)u)<<16); }
DEV float bflo(uint u){ return __uint_as_float(u<<16); }
DEV float bfhi(uint u){ return __uint_as_float(u&0xffff0000u); }

typedef __attribute__((ext_vector_type(8))) short bf8_t;
typedef __attribute__((ext_vector_type(4))) float f4_t;

DEV float quad_sum4(float v){
  v += __int_as_float(__builtin_amdgcn_update_dpp(0, __float_as_int(v), 0xB1, 0xF, 0xF, false));
  v += __int_as_float(__builtin_amdgcn_update_dpp(0, __float_as_int(v), 0x4E, 0xF, 0xF, false));
  return v;
}
// broadcast lane O of each DPP quad to all 4 lanes
template<int O> DEV uint qb(uint v){
  return (uint)__builtin_amdgcn_update_dpp(0, (int)v, O*0x55, 0xF, 0xF, false);
}

// ---------------- LayerNorm stats, two-stage ----------------
__global__ __launch_bounds__(256) void ln_part(const float* __restrict__ x,
                                               float2* __restrict__ part){
  int blk = blockIdx.x; int b = blk>>6, pc = blk&63;
  const float* p = x + (size_t)b*262144 + (size_t)pc*4096;
  float s=0.f, s2=0.f;
  #pragma unroll
  for(int it=0; it<4; ++it){
    int i = threadIdx.x + it*256;
    float4 v = *(const float4*)(p + i*4);
    s  += v.x+v.y+v.z+v.w;
    s2 += v.x*v.x+v.y*v.y+v.z*v.z+v.w*v.w;
  }
  __shared__ float ls[256], ls2[256];
  ls[threadIdx.x]=s; ls2[threadIdx.x]=s2; __syncthreads();
  for(int st=128;st>0;st>>=1){
    if(threadIdx.x<st){ ls[threadIdx.x]+=ls[threadIdx.x+st]; ls2[threadIdx.x]+=ls2[threadIdx.x+st]; }
    __syncthreads();
  }
  if(threadIdx.x==0) part[blk]=make_float2(ls[0],ls2[0]);
}
__global__ __launch_bounds__(64) void ln_fin(const float2* __restrict__ part,
                                             float* __restrict__ mu, float* __restrict__ rstd){
  int b = blockIdx.x;
  float2 v = part[b*64+threadIdx.x];
  __shared__ double ds_[64], ds2_[64];
  ds_[threadIdx.x]=v.x; ds2_[threadIdx.x]=v.y; __syncthreads();
  for(int st=32;st>0;st>>=1){
    if(threadIdx.x<st){ ds_[threadIdx.x]+=ds_[threadIdx.x+st]; ds2_[threadIdx.x]+=ds2_[threadIdx.x+st]; }
    __syncthreads();
  }
  if(threadIdx.x==0){
    double m = ds_[0]*(1.0/262144.0);
    double var = ds2_[0]*(1.0/262144.0) - m*m;
    mu[b]=(float)m; rstd[b]=(float)(1.0/sqrt(var+1e-5));
  }
}

// ---------------- LN1 apply + inproj (64->128) + split, silu on fo2 ----------------
__global__ __launch_bounds__(256) void ln1_inproj(const float* __restrict__ x,
    const float* __restrict__ n1w, const float* __restrict__ n1b,
    const float* __restrict__ ipw, const float* __restrict__ ipb,
    const float* __restrict__ mu, const float* __restrict__ rstd,
    float* __restrict__ fo1_raw, float* __restrict__ fo2s){
  int bh = blockIdx.x; int b = bh>>6, h = bh&63;
  __shared__ float xn[64][64];
  __shared__ float wl[128*64];
  float m = mu[b], rs = rstd[b];
  for(int i=threadIdx.x;i<4096;i+=256){
    int c=i>>6, w=i&63;
    size_t sp=(size_t)c*4096 + h*64 + w;
    float v = x[(size_t)b*262144 + sp];
    xn[c][w] = (v-m)*rs*n1w[sp] + n1b[sp];
  }
  for(int i=threadIdx.x;i<8192;i+=256) wl[i]=ipw[i];
  __syncthreads();
  int px = threadIdx.x & 63, ob = (threadIdx.x>>6)*32;
  float acc[32];
  #pragma unroll
  for(int j=0;j<32;j++) acc[j]=0.f;
  for(int c=0;c<64;c++){
    float xv = xn[c][px];
    #pragma unroll
    for(int j=0;j<32;j++) acc[j] = fmaf(wl[(ob+j)*64+c], xv, acc[j]);
  }
  for(int j=0;j<32;j++){
    int o = ob+j;
    float v = acc[j] + ipb[o];
    if(o<64) fo1_raw[((size_t)(b*64+o))*4096 + h*64 + px] = v;
    else     fo2s  [((size_t)(b*64+o-64))*4096 + h*64 + px] = silu_f(v);
  }
}

// ---------------- depthwise 3x3 + silu, writes normal + transposed spatial ----------------
__global__ __launch_bounds__(256) void dwconv_silu_tr(const float* __restrict__ src_,
    const float* __restrict__ dww, const float* __restrict__ dwb,
    float* __restrict__ fo1s, float* __restrict__ fo1t){
  int bc = blockIdx.x; int c = bc & 63;
  const float* src = src_ + (size_t)bc*4096;
  float wk[9];
  #pragma unroll
  for(int k=0;k<9;k++) wk[k]=dww[c*9+k];
  float bias = dwb[c];
  __shared__ float tl[64][65];
  for(int i=threadIdx.x;i<4096;i+=256){
    int h=i>>6, w=i&63;
    float acc=bias;
    #pragma unroll
    for(int kh=0;kh<3;kh++){
      int ih=h+kh-1; if(ih<0||ih>63) continue;
      #pragma unroll
      for(int kw=0;kw<3;kw++){
        int iw=w+kw-1; if(iw<0||iw>63) continue;
        acc += wk[kh*3+kw]*src[ih*64+iw];
      }
    }
    tl[h][w] = silu_f(acc);
  }
  __syncthreads();
  float* ps = fo1s + (size_t)bc*4096;
  float* pt = fo1t + (size_t)bc*4096;
  for(int i=threadIdx.x;i<4096;i+=256){
    ps[i] = tl[i>>6][i&63];
    pt[i] = tl[i&63][i>>6];
  }
}

// ---------------- weight preps ----------------
__global__ __launch_bounds__(256) void cvt_w_bf(const float* __restrict__ w, uint* __restrict__ wb){
  int i = blockIdx.x*256 + threadIdx.x;   // 131072 pairs
  float2 v = *(const float2*)(w + 2*i);
  wb[i] = f2bf2(v.x, v.y);
}
__global__ __launch_bounds__(256) void wdt_make(const float* __restrict__ dtw,
    const float* __restrict__ xpw, ushort* __restrict__ wcomb){
  int d = blockIdx.x;
  float wr[16];
  #pragma unroll
  for(int r=0;r<16;r++) wr[r]=dtw[d*16+r];
  for(int k=threadIdx.x;k<512;k+=256){
    float acc=0.f;
    #pragma unroll
    for(int r=0;r<16;r++) acc = fmaf(wr[r], xpw[r*512+k], acc);
    wcomb[(size_t)d*512+k]=f2bf(acc);
  }
}
__global__ __launch_bounds__(256) void cvt_bc_pad(const float* __restrict__ xpw, ushort* __restrict__ wcomb){
  int i = blockIdx.x*256 + threadIdx.x;   // 32768
  int row = i>>9, k = i&511;
  float v = (row<32) ? xpw[8192 + row*512 + k] : 0.f;
  wcomb[(size_t)(512+row)*512 + k] = f2bf(v);
}
__global__ __launch_bounds__(256) void fold_w_bf(const float* __restrict__ ow, ushort* __restrict__ wf){
  int i = blockIdx.x*256 + threadIdx.x;   // 32768
  int c = i>>9, d2 = i&511;
  wf[i] = f2bf(ow[c*512+d2] + ow[(64+c)*512+d2] + ow[(128+c)*512+d2] + ow[(192+c)*512+d2]);
}
__global__ __launch_bounds__(256) void cvt_fiw(const float* __restrict__ w, ushort* __restrict__ wb){
  int i = blockIdx.x*256 + threadIdx.x;   // 16384
  wb[i] = f2bf(w[i]);
}

// ---------------- gather u transposed: (B, L=4096, 256) bf16 ----------------
__global__ __launch_bounds__(256) void gather_u_t(const float* __restrict__ fo1s,
    const float* __restrict__ fo1t, uint* __restrict__ u_bf){
  int blk = blockIdx.x;
  int lt = blk&63, part = (blk>>6)&3, b = blk>>8;
  int l0 = lt<<6;
  const float* s = (part<2)? fo1s : fo1t;
  bool rev = part&1;
  __shared__ float tl[64][65];
  for(int i=threadIdx.x;i<4096;i+=256){
    int c=i>>6, j=i&63;
    int l = l0 + j;
    int idx = rev ? (4095-l) : l;
    tl[c][j] = s[((size_t)(b*64+c))*4096 + idx];
  }
  __syncthreads();
  for(int i=threadIdx.x;i<2048;i+=256){
    int j = i>>5, cp = i&31;
    int l = l0 + j;
    u_bf[((size_t)(b*4096)+l)*128 + part*32 + cp] = f2bf2(tl[2*cp][j], tl[2*cp+1][j]);
  }
}

// ---------------- MFMA GEMM: xz = W(1024,256) x U^T ----------------
__global__ __launch_bounds__(256) void gemm_xz_mfma(const ushort* __restrict__ u_bf,
    const ushort* __restrict__ w_bf, float* __restrict__ xi0, ushort* __restrict__ z_bf){
  int blk = blockIdx.x; int b = blk>>5; int l0 = (blk&31)<<7;
  int o0 = blockIdx.y<<7;
  __shared__ __align__(16) ushort Al[2][5120];
  __shared__ __align__(16) ushort Bl[2][5120];
  int t = threadIdx.x, lane = t&63, wid = t>>6;
  int wr = wid>>1, wc = wid&1;
  int rl = lane&15, kseg = (lane>>4)*8;
  f4_t acc[4][4];
  #pragma unroll
  for(int m=0;m<4;m++)
    #pragma unroll
    for(int n=0;n<4;n++) acc[m][n]=(f4_t){0.f,0.f,0.f,0.f};

  int r0 = t>>2, r1 = 64+(t>>2), seg = t&3;
  uint4 rA0,rA1,rB0,rB1;
  auto issue=[&](int kc){
    rA0 = *(const uint4*)&w_bf[(size_t)(o0+r0)*256 + kc*32 + seg*8];
    rA1 = *(const uint4*)&w_bf[(size_t)(o0+r1)*256 + kc*32 + seg*8];
    rB0 = *(const uint4*)&u_bf[((size_t)(b*4096)+l0+r0)*256 + kc*32 + seg*8];
    rB1 = *(const uint4*)&u_bf[((size_t)(b*4096)+l0+r1)*256 + kc*32 + seg*8];
  };
  auto store=[&](int buf){
    *(uint4*)&Al[buf][r0*40 + seg*8] = rA0;
    *(uint4*)&Al[buf][r1*40 + seg*8] = rA1;
    *(uint4*)&Bl[buf][r0*40 + seg*8] = rB0;
    *(uint4*)&Bl[buf][r1*40 + seg*8] = rB1;
  };
  issue(0); store(0); __syncthreads();
  int buf=0;
  for(int kc=0;kc<8;kc++){
    bool more = kc<7;
    if(more) issue(kc+1);
    bf8_t af[4], bfr[4];
    #pragma unroll
    for(int m=0;m<4;m++) af[m] = *(const bf8_t*)&Al[buf][(wr*64+m*16+rl)*40 + kseg];
    #pragma unroll
    for(int n=0;n<4;n++) bfr[n] = *(const bf8_t*)&Bl[buf][(wc*64+n*16+rl)*40 + kseg];
    #pragma unroll
    for(int m=0;m<4;m++)
      #pragma unroll
      for(int n=0;n<4;n++)
        acc[m][n] = __builtin_amdgcn_mfma_f32_16x16x32_bf16(af[m], bfr[n], acc[m][n], 0,0,0);
    __syncthreads();
    if(more){ store(buf^1); __syncthreads(); }
    buf^=1;
  }
  int orow = (lane>>4)*4;
  if(o0 < 512){
    #pragma unroll
    for(int m=0;m<4;m++)
      #pragma unroll
      for(int n=0;n<4;n++){
        int l = l0 + wc*64 + n*16 + rl;
        #pragma unroll
        for(int r=0;r<4;r++){
          int o = o0 + wr*64 + m*16 + orow + r;
          xi0[((size_t)(b*512)+o)*4096 + l] = acc[m][n][r];
        }
      }
  } else {
    #pragma unroll
    for(int m=0;m<4;m++)
      #pragma unroll
      for(int n=0;n<4;n++){
        int l = l0 + wc*64 + n*16 + rl;
        int gz = (o0 - 512 + wr*64 + m*16) >> 4;
        uint2 pkz;
        pkz.x = f2bf2(acc[m][n][0], acc[m][n][1]);
        pkz.y = f2bf2(acc[m][n][2], acc[m][n][3]);
        *(uint2*)&z_bf[(((size_t)(b*32)+gz)*4096 + l)*16 + orow] = pkz;
      }
  }
}

// ---------------- conv1d (k=4 causal) + silu: xi bf16 c-major + bf16 l-major ----------------
__global__ __launch_bounds__(256) void conv1d_silu2(const float* __restrict__ xi0,
    const float* __restrict__ cw, const float* __restrict__ cb,
    ushort* __restrict__ xi_c, ushort* __restrict__ xi_l){
  int blk = blockIdx.x;          // 2048: lt(64) | dt8(8) | b(4)
  int lt = blk&63, dt8 = (blk>>6)&7, b = blk>>9;
  int d0 = dt8*64, l0 = lt*64;
  __shared__ float T[64][65];
  int t = threadIdx.x, lloc = t&63, dq = t>>6;
  #pragma unroll 4
  for(int i=0;i<16;i++){
    int dloc = dq + i*4;
    int d = d0 + dloc;
    int l = l0 + lloc;
    size_t rowb = ((size_t)(b*512)+d)*4096;
    float acc = cb[d];
    #pragma unroll
    for(int k=0;k<4;k++){
      int ls = l-3+k;
      if(ls>=0) acc += cw[d*4+k]*xi0[rowb+ls];
    }
    acc = silu_f(acc);
    xi_c[rowb + l] = f2bf(acc);
    T[lloc][dloc] = acc;
  }
  __syncthreads();
  int dl = t&63;
  #pragma unroll 4
  for(int i=0;i<16;i++){
    int lloc2 = dq + i*4;
    xi_l[((size_t)(b*4096)+l0+lloc2)*512 + d0 + dl] = f2bf(T[lloc2][dl]);
  }
}

// ---------------- merged MFMA GEMM: [dt(512); bc(32)] = Wcomb(576,512) x xi^T ----------------
__global__ __launch_bounds__(256) void gemm_proj_mfma(const ushort* __restrict__ xi_bf,
    const ushort* __restrict__ wcomb, const float* __restrict__ dtb,
    ushort* __restrict__ dt_bf, ushort* __restrict__ bc_out){
  int blk = blockIdx.x; int b = blk>>6; int l0 = (blk&63)<<6;
  int o0 = blockIdx.y<<6;
  __shared__ __align__(16) ushort Al[2][2560];
  __shared__ __align__(16) ushort Bl[2][2560];
  int t = threadIdx.x, lane = t&63, wid = t>>6;
  int wo = wid>>1, wl = wid&1;
  int rl = lane&15, kseg = (lane>>4)*8;
  f4_t acc[2][2];
  #pragma unroll
  for(int m=0;m<2;m++)
    #pragma unroll
    for(int n=0;n<2;n++) acc[m][n]=(f4_t){0.f,0.f,0.f,0.f};
  int r = t>>2, seg = t&3;
  uint4 rA,rB;
  auto issue=[&](int kc){
    rA = *(const uint4*)&wcomb[(size_t)(o0+r)*512 + kc*32 + seg*8];
    rB = *(const uint4*)&xi_bf[((size_t)(b*4096)+l0+r)*512 + kc*32 + seg*8];
  };
  auto store=[&](int buf){
    *(uint4*)&Al[buf][r*40 + seg*8] = rA;
    *(uint4*)&Bl[buf][r*40 + seg*8] = rB;
  };
  issue(0); store(0); __syncthreads();
  int buf=0;
  for(int kc=0;kc<16;kc++){
    bool more = kc<15;
    if(more) issue(kc+1);
    bf8_t af[2], bfr[2];
    #pragma unroll
    for(int m=0;m<2;m++) af[m] = *(const bf8_t*)&Al[buf][(wo*32+m*16+rl)*40 + kseg];
    #pragma unroll
    for(int n=0;n<2;n++) bfr[n] = *(const bf8_t*)&Bl[buf][(wl*32+n*16+rl)*40 + kseg];
    #pragma unroll
    for(int m=0;m<2;m++)
      #pragma unroll
      for(int n=0;n<2;n++)
        acc[m][n] = __builtin_amdgcn_mfma_f32_16x16x32_bf16(af[m], bfr[n], acc[m][n], 0,0,0);
    __syncthreads();
    if(more){ store(buf^1); __syncthreads(); }
    buf^=1;
  }
  int orow = (lane>>4)*4;
  #pragma unroll
  for(int m=0;m<2;m++)
    #pragma unroll
    for(int n=0;n<2;n++){
      int l = l0 + wl*32 + n*16 + rl;
      #pragma unroll
      for(int rr=0;rr<4;rr++){
        int o = o0 + wo*32 + m*16 + orow + rr;
        float v = acc[m][n][rr];
        if(o<512){
          v += dtb[o];
          float sp = (v>20.f)? v : 0.69314718056f*__log2f(1.f+exp2f(1.44269504089f*v));
          dt_bf[((size_t)(b*512)+o)*4096 + l] = f2bf(sp);
        } else if(o<544){
          bc_out[((size_t)(b*4096)+l)*32 + (o-512)] = f2bf(v);
        }
      }
    }
}

// ================= scan v4: 64 chunks of 64; wave = 16 ch x 4 states =================
__global__ __launch_bounds__(64) void scan3_p1(
    const ushort* __restrict__ dtx, const ushort* __restrict__ xix,
    const ushort* __restrict__ bc, const float* __restrict__ Alog,
    float4* __restrict__ Pbuf, float4* __restrict__ qbuf){
  int blk=blockIdx.x;
  int c=blk&63, g=(blk>>6)&31, b=blk>>11;
  int lane=threadIdx.x, ch=lane>>2, sq=lane&3;
  int d=g*16+ch;
  float4 Ar = *(const float4*)(Alog + d*16 + sq*4);
  float A2[4];
  A2[0]=-__expf(Ar.x)*1.44269504088896f;
  A2[1]=-__expf(Ar.y)*1.44269504088896f;
  A2[2]=-__expf(Ar.z)*1.44269504088896f;
  A2[3]=-__expf(Ar.w)*1.44269504088896f;
  __shared__ __align__(16) float bl[32][20];
  const int l0c = c*64;
  const size_t dtrow = ((size_t)(b*512)+d)*4096;
  const ushort* xb = bc + (size_t)b*4096*32;
  uint4 rdt, rxi; uint2 rb[2];
  uint pkc[8];
  auto issue=[&](int t){
    int l0 = l0c + t*32;
    rdt = *(const uint4*)(dtx + dtrow + l0 + sq*8);
    rxi = *(const uint4*)(xix + dtrow + l0 + sq*8);
    #pragma unroll
    for(int k=0;k<2;k++){
      int j=ch+k*16;
      rb[k]=*(const uint2*)(xb + (size_t)(l0+j)*32 + sq*4);
    }
  };
  auto pack=[&](){
    const uint* dp=(const uint*)&rdt; const uint* xp=(const uint*)&rxi;
    #pragma unroll
    for(int k=0;k<4;k++){
      uint ud=dp[k], ux=xp[k];
      pkc[2*k]   = (ud&0xffffu)|(ux<<16);
      pkc[2*k+1] = (ud>>16)|(ux&0xffff0000u);
    }
  };
  auto storeB=[&](){
    #pragma unroll
    for(int k=0;k<2;k++){
      float4 bv = make_float4(bflo(rb[k].x), bfhi(rb[k].x), bflo(rb[k].y), bfhi(rb[k].y));
      *(float4*)&bl[ch+k*16][sq*4] = bv;
    }
  };
  float P[4]={1.f,1.f,1.f,1.f}, q[4]={0.f,0.f,0.f,0.f};
  auto step2=[&](uint p0, uint p1, int j0){
    float4 B0 = *(const float4*)&bl[j0][sq*4];
    float4 B1 = *(const float4*)&bl[j0+1][sq*4];
    {
      float dtv=bflo(p0), xiv=bfhi(p0); float u=dtv*xiv;
      #pragma unroll
      for(int i=0;i<4;i++){ float dA=exp2f(dtv*A2[i]); P[i]*=dA; q[i]=fmaf(dA,q[i],u*((const float*)&B0)[i]); }
    }
    {
      float dtv=bflo(p1), xiv=bfhi(p1); float u=dtv*xiv;
      #pragma unroll
      for(int i=0;i<4;i++){ float dA=exp2f(dtv*A2[i]); P[i]*=dA; q[i]=fmaf(dA,q[i],u*((const float*)&B1)[i]); }
    }
  };
  issue(0); pack(); storeB();
  for(int t=0;t<2;t++){
    if(t<1) issue(t+1);
    step2(qb<0>(pkc[0]),qb<0>(pkc[1]), 0);
    step2(qb<0>(pkc[2]),qb<0>(pkc[3]), 2);
    step2(qb<0>(pkc[4]),qb<0>(pkc[5]), 4);
    step2(qb<0>(pkc[6]),qb<0>(pkc[7]), 6);
    step2(qb<1>(pkc[0]),qb<1>(pkc[1]), 8);
    step2(qb<1>(pkc[2]),qb<1>(pkc[3]),10);
    step2(qb<1>(pkc[4]),qb<1>(pkc[5]),12);
    step2(qb<1>(pkc[6]),qb<1>(pkc[7]),14);
    step2(qb<2>(pkc[0]),qb<2>(pkc[1]),16);
    step2(qb<2>(pkc[2]),qb<2>(pkc[3]),18);
    step2(qb<2>(pkc[4]),qb<2>(pkc[5]),20);
    step2(qb<2>(pkc[6]),qb<2>(pkc[7]),22);
    step2(qb<3>(pkc[0]),qb<3>(pkc[1]),24);
    step2(qb<3>(pkc[2]),qb<3>(pkc[3]),26);
    step2(qb<3>(pkc[4]),qb<3>(pkc[5]),28);
    step2(qb<3>(pkc[6]),qb<3>(pkc[7]),30);
    if(t<1){ pack(); storeB(); }
  }
  int idx = blk*64 + lane;
  Pbuf[idx]=make_float4(P[0],P[1],P[2],P[3]);
  qbuf[idx]=make_float4(q[0],q[1],q[2],q[3]);
}

__global__ __launch_bounds__(256) void scan3_mid(const float4* __restrict__ Pbuf,
    const float4* __restrict__ qbuf, float4* __restrict__ hstart){
  int tid = blockIdx.x*256+threadIdx.x;  // 8192 = 128 groups * 64 lanes
  int lane = tid&63, sg = tid>>6;
  float4 h = make_float4(0.f,0.f,0.f,0.f);
  #pragma unroll 8
  for(int c=0;c<64;c++){
    int idx = (sg*64+c)*64 + lane;
    hstart[idx]=h;
    float4 P=Pbuf[idx], q=qbuf[idx];
    h.x = fmaf(P.x,h.x,q.x);
    h.y = fmaf(P.y,h.y,q.y);
    h.z = fmaf(P.z,h.z,q.z);
    h.w = fmaf(P.w,h.w,q.w);
  }
}

__global__ __launch_bounds__(64) void scan3_p2(
    const ushort* __restrict__ dtx, const ushort* __restrict__ xix,
    const ushort* __restrict__ z_bf, const ushort* __restrict__ bc,
    const float* __restrict__ Alog, const float* __restrict__ Dp,
    const float4* __restrict__ hstart, ushort* __restrict__ y_bf){
  int blk=blockIdx.x;
  int c=blk&63, g=(blk>>6)&31, b=blk>>11;
  int lane=threadIdx.x, ch=lane>>2, sq=lane&3;
  int d=g*16+ch;
  float4 Ar = *(const float4*)(Alog + d*16 + sq*4);
  float A2[4];
  A2[0]=-__expf(Ar.x)*1.44269504088896f;
  A2[1]=-__expf(Ar.y)*1.44269504088896f;
  A2[2]=-__expf(Ar.z)*1.44269504088896f;
  A2[3]=-__expf(Ar.w)*1.44269504088896f;
  float Dv = Dp[d];
  int je = lane>>1, halfe = lane&1;
  __shared__ __align__(16) float bcl[32][36];
  __shared__ __align__(16) float pl[32][18];
  const int l0c = c*64;
  const size_t dtrow = ((size_t)(b*512)+d)*4096;
  const ushort* xb = bc + (size_t)b*4096*32;
  const size_t zybase = (((size_t)(b*32)+g)*4096);
  uint4 rdt, rxi; uint2 rbc[4];
  uint4 rzb[2];
  uint pkc[8];
  auto issue=[&](int t){
    int l0 = l0c + t*32;
    rdt = *(const uint4*)(dtx + dtrow + l0 + sq*8);
    rxi = *(const uint4*)(xix + dtrow + l0 + sq*8);
    #pragma unroll
    for(int k=0;k<4;k++){
      int j=(lane>>3)+k*8, seg=lane&7;
      rbc[k]=*(const uint2*)(xb + (size_t)(l0+j)*32 + seg*4);
    }
    rzb[t&1] = *(const uint4*)&z_bf[(zybase + l0 + je)*16 + halfe*8];
  };
  auto pack=[&](){
    const uint* dp=(const uint*)&rdt; const uint* xp=(const uint*)&rxi;
    #pragma unroll
    for(int k=0;k<4;k++){
      uint ud=dp[k], ux=xp[k];
      pkc[2*k]   = (ud&0xffffu)|(ux<<16);
      pkc[2*k+1] = (ud>>16)|(ux&0xffff0000u);
    }
  };
  auto storeBC=[&](){
    #pragma unroll
    for(int k=0;k<4;k++){
      float4 v = make_float4(bflo(rbc[k].x), bfhi(rbc[k].x), bflo(rbc[k].y), bfhi(rbc[k].y));
      *(float4*)&bcl[(lane>>3)+k*8][(lane&7)*4] = v;
    }
  };
  float h[4];
  {
    float4 h0 = hstart[blk*64 + lane];
    h[0]=h0.x; h[1]=h0.y; h[2]=h0.z; h[3]=h0.w;
  }
  auto step2=[&](uint p0, uint p1, int j0){
    {
      float4 B4 = *(const float4*)&bcl[j0][sq*4];
      float4 C4 = *(const float4*)&bcl[j0][16+sq*4];
      float dtv=bflo(p0), xiv=bfhi(p0); float u=dtv*xiv;
      float p;
      #pragma unroll
      for(int i=0;i<4;i++){ float dA=exp2f(dtv*A2[i]); h[i]=fmaf(dA,h[i],u*((const float*)&B4)[i]); }
      p = h[0]*C4.x; p=fmaf(h[1],C4.y,p); p=fmaf(h[2],C4.z,p); p=fmaf(h[3],C4.w,p);
      p = quad_sum4(p);
      if(sq==0) pl[j0][ch] = p + xiv*Dv;
    }
    {
      float4 B4 = *(const float4*)&bcl[j0+1][sq*4];
      float4 C4 = *(const float4*)&bcl[j0+1][16+sq*4];
      float dtv=bflo(p1), xiv=bfhi(p1); float u=dtv*xiv;
      float p;
      #pragma unroll
      for(int i=0;i<4;i++){ float dA=exp2f(dtv*A2[i]); h[i]=fmaf(dA,h[i],u*((const float*)&B4)[i]); }
      p = h[0]*C4.x; p=fmaf(h[1],C4.y,p); p=fmaf(h[2],C4.z,p); p=fmaf(h[3],C4.w,p);
      p = quad_sum4(p);
      if(sq==0) pl[j0+1][ch] = p + xiv*Dv;
    }
  };
  issue(0); pack(); storeBC();
  for(int t=0;t<2;t++){
    if(t<1) issue(t+1);
    step2(qb<0>(pkc[0]),qb<0>(pkc[1]), 0);
    step2(qb<0>(pkc[2]),qb<0>(pkc[3]), 2);
    step2(qb<0>(pkc[4]),qb<0>(pkc[5]), 4);
    step2(qb<0>(pkc[6]),qb<0>(pkc[7]), 6);
    step2(qb<1>(pkc[0]),qb<1>(pkc[1]), 8);
    step2(qb<1>(pkc[2]),qb<1>(pkc[3]),10);
    step2(qb<1>(pkc[4]),qb<1>(pkc[5]),12);
    step2(qb<1>(pkc[6]),qb<1>(pkc[7]),14);
    step2(qb<2>(pkc[0]),qb<2>(pkc[1]),16);
    step2(qb<2>(pkc[2]),qb<2>(pkc[3]),18);
    step2(qb<2>(pkc[4]),qb<2>(pkc[5]),20);
    step2(qb<2>(pkc[6]),qb<2>(pkc[7]),22);
    step2(qb<3>(pkc[0]),qb<3>(pkc[1]),24);
    step2(qb<3>(pkc[2]),qb<3>(pkc[3]),26);
    step2(qb<3>(pkc[4]),qb<3>(pkc[5]),28);
    step2(qb<3>(pkc[6]),qb<3>(pkc[7]),30);
    // emit tile t
    {
      int l = l0c + t*32 + je;
      uint4 zr = rzb[t&1];
      const ushort* zp = (const ushort*)&zr;
      float pv[8];
      #pragma unroll
      for(int k=0;k<4;k++){
        float2 v2 = *(const float2*)&pl[je][halfe*8+2*k];
        pv[2*k]=v2.x; pv[2*k+1]=v2.y;
      }
      float yv[8];
      #pragma unroll
      for(int k=0;k<8;k++) yv[k] = pv[k] * silu_f(bf2f(zp[k]));
      uint4 yo;
      uint* yp=(uint*)&yo;
      yp[0]=f2bf2(yv[0],yv[1]); yp[1]=f2bf2(yv[2],yv[3]);
      yp[2]=f2bf2(yv[4],yv[5]); yp[3]=f2bf2(yv[6],yv[7]);
      *(uint4*)&y_bf[((size_t)zybase + l)*16 + halfe*8] = yo;
    }
    if(t<1){ pack(); storeBC(); }
  }
}

// ---------------- MFMA GEMM: res = (W'(64,512) x Y^T) * fo2s, out (B,64,L) c-major ----------------
__global__ __launch_bounds__(256) void gemm_res_mfma(const ushort* __restrict__ y_bf,
    const ushort* __restrict__ wf_bf, const float* __restrict__ fo2s, float* __restrict__ res){
  int blk = blockIdx.x; int b = blk>>5; int l0 = (blk&31)<<7;
  __shared__ __align__(16) ushort Wl[2][2560];
  __shared__ __align__(16) ushort Yl[2][5120];
  int t = threadIdx.x, lane = t&63, wid = t>>6;
  int rl = lane&15, kseg = (lane>>4)*8;
  f4_t acc[4][2];
  #pragma unroll
  for(int m=0;m<4;m++)
    #pragma unroll
    for(int n=0;n<2;n++) acc[m][n]=(f4_t){0.f,0.f,0.f,0.f};
  int ry = t>>1;
  int rw = t>>2, sgw = t&3;
  uint4 rY0, rY1, rW;
  auto issue=[&](int kc){
    int gg = 2*kc + (t&1);
    const ushort* yrow = &y_bf[(((size_t)(b*32)+gg)*4096 + l0+ry)*16];
    rY0 = *(const uint4*)&yrow[0];
    rY1 = *(const uint4*)&yrow[8];
    rW  = *(const uint4*)&wf_bf[(size_t)rw*512 + kc*32 + sgw*8];
  };
  auto store=[&](int buf){
    *(uint4*)&Yl[buf][ry*40 + (t&1)*16]     = rY0;
    *(uint4*)&Yl[buf][ry*40 + (t&1)*16 + 8] = rY1;
    *(uint4*)&Wl[buf][rw*40 + sgw*8]        = rW;
  };
  issue(0); store(0); __syncthreads();
  int buf=0;
  for(int kc=0;kc<16;kc++){
    bool more = kc<15;
    if(more) issue(kc+1);
    bf8_t aw[4], by[2];
    #pragma unroll
    for(int m=0;m<4;m++) aw[m] = *(const bf8_t*)&Wl[buf][(m*16+rl)*40 + kseg];
    #pragma unroll
    for(int n=0;n<2;n++) by[n] = *(const bf8_t*)&Yl[buf][(wid*32+n*16+rl)*40 + kseg];
    #pragma unroll
    for(int m=0;m<4;m++)
      #pragma unroll
      for(int n=0;n<2;n++)
        acc[m][n] = __builtin_amdgcn_mfma_f32_16x16x32_bf16(aw[m], by[n], acc[m][n], 0,0,0);
    __syncthreads();
    if(more){ store(buf^1); __syncthreads(); }
    buf^=1;
  }
  int orow = (lane>>4)*4;
  #pragma unroll
  for(int m=0;m<4;m++)
    #pragma unroll
    for(int n=0;n<2;n++){
      int l = l0 + wid*32 + n*16 + rl;
      #pragma unroll
      for(int r=0;r<4;r++){
        int o = m*16 + orow + r;
        size_t idx = ((size_t)(b*64+o))*4096 + l;
        res[idx] = acc[m][n][r]*fo2s[idx];
      }
    }
}

// ---------------- per (b,c) spatial mean ----------------
__global__ __launch_bounds__(256) void colmean(const float* __restrict__ res, float* __restrict__ fm){
  int bc = blockIdx.x;
  const float* p = res + (size_t)bc*4096;
  float s=0;
  for(int i=threadIdx.x;i<4096;i+=256) s+=p[i];
  __shared__ float ls[256];
  ls[threadIdx.x]=s; __syncthreads();
  for(int st=128;st>0;st>>=1){ if(threadIdx.x<st) ls[threadIdx.x]+=ls[threadIdx.x+st]; __syncthreads(); }
  if(threadIdx.x==0) fm[bc]=ls[0]*(1.f/4096.f);
}

// ---------------- tiny mamba2 over channel sequence ----------------
__global__ __launch_bounds__(64) void mamba2_kernel(const float* __restrict__ fm,
    const float* __restrict__ in_w, const float* __restrict__ cw, const float* __restrict__ cb,
    const float* __restrict__ xp, const float* __restrict__ dtw, const float* __restrict__ dtb,
    const float* __restrict__ Alog, const float* __restrict__ Dp, const float* __restrict__ ow,
    float* __restrict__ fsum){
  int b = blockIdx.x; int t = threadIdx.x;
  __shared__ float xi0m[64][4], xim[64][4], dtm[64][4], xbl[64][33], ym[64][4];
  float a0 = fm[b*64+t], a1 = fm[b*64 + 63-t];
  float zreg[4];
  #pragma unroll
  for(int d2=0;d2<4;d2++){
    xi0m[t][d2] = in_w[d2*2+0]*a0 + in_w[d2*2+1]*a1;
    zreg[d2]    = in_w[(4+d2)*2+0]*a0 + in_w[(4+d2)*2+1]*a1;
  }
  __syncthreads();
  float xir[4];
  #pragma unroll
  for(int d2=0;d2<4;d2++){
    float acc=cb[d2];
    #pragma unroll
    for(int k=0;k<4;k++){
      int srow=t-3+k;
      if(srow>=0) acc += cw[d2*4+k]*xi0m[srow][d2];
    }
    xir[d2]=silu_f(acc);
    xim[t][d2]=xir[d2];
  }
  for(int j=0;j<33;j++){
    float acc=0;
    #pragma unroll
    for(int d2=0;d2<4;d2++) acc += xp[j*4+d2]*xir[d2];
    xbl[t][j]=acc;
  }
  #pragma unroll
  for(int d2=0;d2<4;d2++){
    float v = xbl[t][0]*dtw[d2] + dtb[d2];
    dtm[t][d2] = (v>20.f)? v : log1pf(__expf(v));
  }
  __syncthreads();
  int dd=t>>4, s=t&15;
  float A2 = -__expf(Alog[dd*16+s]) * 1.44269504088896f;
  float h=0.f;
  for(int c=0;c<64;c++){
    float dtv=dtm[c][dd];
    float dA=exp2f(dtv*A2);
    h = fmaf(dA, h, dtv*xim[c][dd]*xbl[c][1+s]);
    float p = h*xbl[c][17+s];
    p += __shfl_xor(p,1,16);
    p += __shfl_xor(p,2,16);
    p += __shfl_xor(p,4,16);
    p += __shfl_xor(p,8,16);
    if(s==0) ym[c][dd]=p;
  }
  __syncthreads();
  float os=0.f;
  #pragma unroll
  for(int d2=0;d2<4;d2++){
    float yv = (ym[t][d2] + xim[t][d2]*Dp[d2]) * silu_f(zreg[d2]);
    os += yv * (ow[d2] + ow[4+d2]);
  }
  fsum[b*64+t]=os;
}

// ---------------- foss = res*(1+foc) ; x2 = outproj(foss) + x ; emits LN2 partials ----------------
__global__ __launch_bounds__(256) void outproj_kernel(const float* __restrict__ res,
    const float* __restrict__ fsum, const float* __restrict__ opw, const float* __restrict__ opb,
    const float* __restrict__ x, float* __restrict__ x2, float2* __restrict__ part){
  int bh=blockIdx.x; int b=bh>>6,h=bh&63;
  __shared__ float tile[64][64];
  __shared__ float wl[4096];
  __shared__ float ls[256], ls2[256];
  for(int i=threadIdx.x;i<4096;i+=256) wl[i]=opw[i];
  for(int i=threadIdx.x;i<4096;i+=256){
    int c=i>>6,w=i&63;
    tile[c][w]=res[((size_t)(b*64+c))*4096 + h*64 + w]*(1.f+fsum[b*64+c]);
  }
  __syncthreads();
  int px=threadIdx.x&63, og=threadIdx.x>>6;
  float acc[16];
  #pragma unroll
  for(int j=0;j<16;j++) acc[j]=0.f;
  for(int c=0;c<64;c++){
    float v=tile[c][px];
    #pragma unroll
    for(int j=0;j<16;j++) acc[j]=fmaf(wl[(og*16+j)*64+c],v,acc[j]);
  }
  float s=0.f, s2=0.f;
  for(int j=0;j<16;j++){
    int o=og*16+j;
    size_t idx=((size_t)(b*64+o))*4096 + h*64 + px;
    float v = acc[j]+opb[o]+x[idx];
    x2[idx]=v;
    s += v; s2 = fmaf(v,v,s2);
  }
  ls[threadIdx.x]=s; ls2[threadIdx.x]=s2; __syncthreads();
  for(int st=128;st>0;st>>=1){
    if(threadIdx.x<st){ ls[threadIdx.x]+=ls[threadIdx.x+st]; ls2[threadIdx.x]+=ls2[threadIdx.x+st]; }
    __syncthreads();
  }
  if(threadIdx.x==0) part[bh]=make_float2(ls[0],ls2[0]);
}

// ---------------- LN2 apply -> xn2 bf16 l-major (B,HW,64) ----------------
__global__ __launch_bounds__(256) void ln2_apply_bf(const float* __restrict__ x2,
    const float* __restrict__ n2w, const float* __restrict__ n2b,
    const float* __restrict__ mu2, const float* __restrict__ rstd2,
    uint* __restrict__ xn_bf){
  int bh=blockIdx.x; int b=bh>>6,h=bh&63;
  __shared__ float tl[64][65];
  float m=mu2[b], rs=rstd2[b];
  for(int i=threadIdx.x;i<4096;i+=256){
    int c=i>>6,w=i&63;
    size_t sp=(size_t)c*4096 + h*64 + w;
    tl[c][w]=(x2[(size_t)b*262144+sp]-m)*rs*n2w[sp]+n2b[sp];
  }
  __syncthreads();
  for(int i=threadIdx.x;i<2048;i+=256){
    int w=i>>5, cp=i&31;
    xn_bf[((size_t)(b*4096)+h*64+w)*32 + cp] = f2bf2(tl[2*cp][w], tl[2*cp+1][w]);
  }
}

// ---------------- MFMA GEMM: g = Wfi(256,64) x xn^T + fib, planar bf16 out ----------------
__global__ __launch_bounds__(256) void gemm_ffn_mfma(const ushort* __restrict__ xn_bf,
    const ushort* __restrict__ fiw_bf, const float* __restrict__ fib,
    ushort* __restrict__ g_bf){
  int blk = blockIdx.x; int b = blk>>6; int l0 = (blk&63)<<6;
  int o0 = blockIdx.y<<6;
  __shared__ __align__(16) ushort Al[2][2560];
  __shared__ __align__(16) ushort Bl[2][2560];
  int t = threadIdx.x, lane = t&63, wid = t>>6;
  int wo = wid>>1, wl = wid&1;
  int rl = lane&15, kseg = (lane>>4)*8;
  f4_t acc[2][2];
  #pragma unroll
  for(int m=0;m<2;m++)
    #pragma unroll
    for(int n=0;n<2;n++) acc[m][n]=(f4_t){0.f,0.f,0.f,0.f};
  int r = t>>2, seg = t&3;
  uint4 rA,rB;
  auto issue=[&](int kc){
    rA = *(const uint4*)&fiw_bf[(size_t)(o0+r)*64 + kc*32 + seg*8];
    rB = *(const uint4*)&xn_bf[((size_t)(b*4096)+l0+r)*64 + kc*32 + seg*8];
  };
  auto store=[&](int buf){
    *(uint4*)&Al[buf][r*40 + seg*8] = rA;
    *(uint4*)&Bl[buf][r*40 + seg*8] = rB;
  };
  issue(0); store(0); __syncthreads();
  int buf=0;
  for(int kc=0;kc<2;kc++){
    bool more = kc<1;
    if(more) issue(kc+1);
    bf8_t af[2], bfr[2];
    #pragma unroll
    for(int m=0;m<2;m++) af[m] = *(const bf8_t*)&Al[buf][(wo*32+m*16+rl)*40 + kseg];
    #pragma unroll
    for(int n=0;n<2;n++) bfr[n] = *(const bf8_t*)&Bl[buf][(wl*32+n*16+rl)*40 + kseg];
    #pragma unroll
    for(int m=0;m<2;m++)
      #pragma unroll
      for(int n=0;n<2;n++)
        acc[m][n] = __builtin_amdgcn_mfma_f32_16x16x32_bf16(af[m], bfr[n], acc[m][n], 0,0,0);
    __syncthreads();
    if(more){ store(buf^1); __syncthreads(); }
    buf^=1;
  }
  int orow = (lane>>4)*4;
  #pragma unroll
  for(int m=0;m<2;m++)
    #pragma unroll
    for(int n=0;n<2;n++){
      int l = l0 + wl*32 + n*16 + rl;
      #pragma unroll
      for(int rr=0;rr<4;rr++){
        int og = o0 + wo*32 + m*16 + orow + rr;
        g_bf[((size_t)(b*256+og))*4096 + l] = f2bf(acc[m][n][rr] + fib[og]);
      }
    }
}

// ---------------- ffn depthwise 3x3 + gelu-gate (bf16 in/out) ----------------
__global__ __launch_bounds__(256) void ffn_dw_gate(const ushort* __restrict__ g,
    const float* __restrict__ dww, const float* __restrict__ dwb, ushort* __restrict__ gm){
  int e = blockIdx.x*256 + threadIdx.x;   // 4*128*4096
  int sp = e & 4095, j = (e>>12)&127, b = e>>19;
  int h = sp>>6, w = sp&63;
  float v[2];
  #pragma unroll
  for(int half=0;half<2;half++){
    int ch = j + half*128;
    const ushort* gp = g + ((size_t)(b*256+ch))*4096;
    float acc = dwb[ch];
    #pragma unroll
    for(int kh=0;kh<3;kh++){
      int ih=h+kh-1; if(ih<0||ih>63) continue;
      #pragma unroll
      for(int kw=0;kw<3;kw++){
        int iw=w+kw-1; if(iw<0||iw>63) continue;
        acc += dww[ch*9+kh*3+kw]*bf2f(gp[ih*64+iw]);
      }
    }
    v[half]=acc;
  }
  float ge = 0.5f*v[0]*(1.f+erff(v[0]*0.70710678f));
  gm[((size_t)(b*128+j))*4096 + sp] = f2bf(ge*v[1]);
}

// ---------------- ffn_out (128->64) + bias + residual add -> d_out ----------------
__global__ __launch_bounds__(256) void ffn_out_kernel(const ushort* __restrict__ gm,
    const float* __restrict__ fow, const float* __restrict__ fob,
    const float* __restrict__ x2, float* __restrict__ out){
  int bh=blockIdx.x; int b=bh>>6,h=bh&63;
  __shared__ float tile[128][64];
  __shared__ float wl[64*128];
  for(int i=threadIdx.x;i<8192;i+=256){
    int c=i>>6,w=i&63;
    tile[c][w]=bf2f(gm[((size_t)(b*128+c))*4096 + h*64 + w]);
  }
  for(int i=threadIdx.x;i<8192;i+=256) wl[i]=fow[i];
  __syncthreads();
  int px=threadIdx.x&63, og=threadIdx.x>>6;
  float acc[16];
  #pragma unroll
  for(int j=0;j<16;j++) acc[j]=0.f;
  for(int c=0;c<128;c++){
    float v=tile[c][px];
    #pragma unroll
    for(int j=0;j<16;j++) acc[j]=fmaf(wl[(og*16+j)*128+c],v,acc[j]);
  }
  for(int j=0;j<16;j++){
    int o=og*16+j;
    size_t idx=((size_t)(b*64+o))*4096 + h*64 + px;
    out[idx]=acc[j]+fob[o]+x2[idx];
  }
}

extern "C" void kernel_launch(void* const* d_in, const int* in_sizes, int n_in,
                              void* d_out, int out_size, void* d_ws, size_t ws_size,
                              hipStream_t stream){
  const float* x      = (const float*)d_in[0];
  const float* n1w    = (const float*)d_in[1];
  const float* n1b    = (const float*)d_in[2];
  const float* n2w    = (const float*)d_in[3];
  const float* n2b    = (const float*)d_in[4];
  const float* ipw    = (const float*)d_in[5];
  const float* ipb    = (const float*)d_in[6];
  const float* dww    = (const float*)d_in[7];
  const float* dwb    = (const float*)d_in[8];
  const float* opw    = (const float*)d_in[9];
  const float* opb    = (const float*)d_in[10];
  const float* m1_inw = (const float*)d_in[11];
  const float* m1_cw  = (const float*)d_in[12];
  const float* m1_cb  = (const float*)d_in[13];
  const float* m1_xp  = (const float*)d_in[14];
  const float* m1_dtw = (const float*)d_in[15];
  const float* m1_dtb = (const float*)d_in[16];
  const float* m1_Al  = (const float*)d_in[17];
  const float* m1_D   = (const float*)d_in[18];
  const float* m1_ow  = (const float*)d_in[19];
  const float* m2_inw = (const float*)d_in[20];
  const float* m2_cw  = (const float*)d_in[21];
  const float* m2_cb  = (const float*)d_in[22];
  const float* m2_xp  = (const float*)d_in[23];
  const float* m2_dtw = (const float*)d_in[24];
  const float* m2_dtb = (const float*)d_in[25];
  const float* m2_Al  = (const float*)d_in[26];
  const float* m2_D   = (const float*)d_in[27];
  const float* m2_ow  = (const float*)d_in[28];
  const float* fiw    = (const float*)d_in[29];
  const float* fib    = (const float*)d_in[30];
  const float* fdw    = (const float*)d_in[31];
  const float* fdb    = (const float*)d_in[32];
  const float* fow    = (const float*)d_in[33];
  const float* fob    = (const float*)d_in[34];
  float* out = (float*)d_out;
  float* ws  = (float*)d_ws;

  const size_t M1 = 1048576;
  float* mu1   = ws + 0;  float* rstd1 = ws + 4;
  float* mu2   = ws + 8;  float* rstd2 = ws + 12;
  float* fmean = ws + 64;
  float* fsum  = ws + 320;
  float* lnpart= ws + 33792;
  float* base0 = ws + 36864;
  float* fo1raw= base0;                 // 1M [-> res]
  float* fo2s  = base0 + M1;            // 1M
  float* fo1s  = base0 + 2*M1;          // 1M [-> xn2_bf]
  float* fo1t  = base0 + 3*M1;          // 1M
  float* big0  = base0 + 4*M1;          // 8M: u_bf(2M) -> dt_bf(4M) + hstart(2M @ +4M) -> g_bf(2M)
  float* big1  = base0 + 12*M1;         // 8M: xi0 -> y_bf(4M) + gm_bf(1M @ +4M)
  float* big2  = base0 + 20*M1;         // 8M: z_bf(4M) + xi_l(4M @ +4M)
  float* big3  = base0 + 28*M1;         // 8M: xi_c(4M) + Pbuf(2M @ +4M) + qbuf(2M @ +6M)
  float* bcslot= base0 + 36*M1;         // 512K floats slot: bc_bf (256K used)
  float* x2    = base0 + 36*M1 + 524288;// 1M
  float* tail  = x2 + M1;
  ushort* w_bf    = (ushort*)tail;                    // 1024x256 bf16 (512KB)
  ushort* wcomb   = (ushort*)(tail + 131072);         // 576x512 bf16 (576KB)
  ushort* wf_bf   = (ushort*)(tail + 278528);         // 64x512 bf16 (64KB)
  ushort* fiw_bf  = (ushort*)(tail + 294912);         // 256x64 bf16 (32KB)

  uint*   u_bf  = (uint*)big0;
  ushort* dt_bf = (ushort*)big0;
  ushort* g_bf  = (ushort*)big0;
  float*  hstart= big0 + 4*M1;          // 2M floats (8192 blk * 64 * float4)
  float*  xi0   = big1;
  ushort* y_bf  = (ushort*)big1;
  ushort* gm_bf = (ushort*)(big1 + 4*M1);
  ushort* z_bf  = (ushort*)big2;
  ushort* xi_l  = (ushort*)(big2 + 4*M1);
  ushort* xi_c  = (ushort*)big3;
  float*  Pbuf  = big3 + 4*M1;          // 2M floats
  float*  qbuf  = big3 + 6*M1;          // 2M floats
  ushort* bc_bf = (ushort*)bcslot;
  uint*   xn2_bf= (uint*)fo1s;          // (B,HW,64) bf16 = 1M floats
  float*  res   = fo1raw;

  hipLaunchKernelGGL(ln_part, dim3(256), dim3(256), 0, stream, x, (float2*)lnpart);
  hipLaunchKernelGGL(ln_fin, dim3(4), dim3(64), 0, stream, (const float2*)lnpart, mu1, rstd1);
  hipLaunchKernelGGL(cvt_w_bf, dim3(512), dim3(256), 0, stream, m1_inw, (uint*)w_bf);
  hipLaunchKernelGGL(wdt_make, dim3(512), dim3(256), 0, stream, m1_dtw, m1_xp, wcomb);
  hipLaunchKernelGGL(cvt_bc_pad, dim3(128), dim3(256), 0, stream, m1_xp, wcomb);
  hipLaunchKernelGGL(fold_w_bf, dim3(128), dim3(256), 0, stream, m1_ow, wf_bf);
  hipLaunchKernelGGL(cvt_fiw, dim3(64), dim3(256), 0, stream, fiw, fiw_bf);
  hipLaunchKernelGGL(ln1_inproj, dim3(256), dim3(256), 0, stream,
                     x, n1w, n1b, ipw, ipb, mu1, rstd1, fo1raw, fo2s);
  hipLaunchKernelGGL(dwconv_silu_tr, dim3(256), dim3(256), 0, stream,
                     fo1raw, dww, dwb, fo1s, fo1t);
  hipLaunchKernelGGL(gather_u_t, dim3(1024), dim3(256), 0, stream, fo1s, fo1t, u_bf);
  hipLaunchKernelGGL(gemm_xz_mfma, dim3(128, 8), dim3(256), 0, stream,
                     (const ushort*)u_bf, w_bf, xi0, z_bf);
  hipLaunchKernelGGL(conv1d_silu2, dim3(2048), dim3(256), 0, stream,
                     xi0, m1_cw, m1_cb, xi_c, xi_l);
  hipLaunchKernelGGL(gemm_proj_mfma, dim3(256, 9), dim3(256), 0, stream,
                     xi_l, wcomb, m1_dtb, dt_bf, bc_bf);
  hipLaunchKernelGGL(scan3_p1, dim3(8192), dim3(64), 0, stream,
                     dt_bf, xi_c, bc_bf, m1_Al, (float4*)Pbuf, (float4*)qbuf);
  hipLaunchKernelGGL(scan3_mid, dim3(32), dim3(256), 0, stream,
                     (const float4*)Pbuf, (const float4*)qbuf, (float4*)hstart);
  hipLaunchKernelGGL(scan3_p2, dim3(8192), dim3(64), 0, stream,
                     dt_bf, xi_c, z_bf, bc_bf, m1_Al, m1_D, (const float4*)hstart, y_bf);
  hipLaunchKernelGGL(gemm_res_mfma, dim3(128), dim3(256), 0, stream,
                     y_bf, wf_bf, fo2s, res);
  hipLaunchKernelGGL(colmean, dim3(256), dim3(256), 0, stream, res, fmean);
  hipLaunchKernelGGL(mamba2_kernel, dim3(4), dim3(64), 0, stream,
                     fmean, m2_inw, m2_cw, m2_cb, m2_xp, m2_dtw, m2_dtb, m2_Al, m2_D, m2_ow, fsum);
  hipLaunchKernelGGL(outproj_kernel, dim3(256), dim3(256), 0, stream,
                     res, fsum, opw, opb, x, x2, (float2*)lnpart);
  hipLaunchKernelGGL(ln_fin, dim3(4), dim3(64), 0, stream, (const float2*)lnpart, mu2, rstd2);
  hipLaunchKernelGGL(ln2_apply_bf, dim3(256), dim3(256), 0, stream,
                     x2, n2w, n2b, mu2, rstd2, xn2_bf);
  hipLaunchKernelGGL(gemm_ffn_mfma, dim3(256, 4), dim3(256), 0, stream,
                     (const ushort*)xn2_bf, fiw_bf, fib, g_bf);
  hipLaunchKernelGGL(ffn_dw_gate, dim3(8192), dim3(256), 0, stream, g_bf, fdw, fdb, gm_bf);
  hipLaunchKernelGGL(ffn_out_kernel, dim3(256), dim3(256), 0, stream, gm_bf, fow, fob, x2, out);
}